// Round 3
// baseline (321.856 us; speedup 1.0000x reference)
//
#include <hip/hip_runtime.h>
#include <hip/hip_bf16.h>
#include <float.h>

#define N_ORB 1024
#define KSEL 32
#define LEAK 0.01f
#define LOG2E 1.4426950408889634f

__device__ __forceinline__ float leaky(float x) { return x >= 0.0f ? x : LEAK * x; }

// ---- DPP helpers ----
template <int CTRL, int RM>
__device__ __forceinline__ int dpp0_i(int v) {  // masked-off rows contribute 0
  return __builtin_amdgcn_update_dpp(0, v, CTRL, RM, 0xF, true);
}
template <int CTRL>
__device__ __forceinline__ float dpp_zero(float v) {
  return __int_as_float(
      __builtin_amdgcn_update_dpp(0, __float_as_int(v), CTRL, 0xF, 0xF, true));
}
__device__ __forceinline__ float rdlane(float v, int l) {
  return __int_as_float(__builtin_amdgcn_readlane(__float_as_int(v), l));
}

// full 64-lane float sum, uniform result
__device__ __forceinline__ float wave_sum64_dpp(float v) {
  v += dpp_zero<0x111>(v);
  v += dpp_zero<0x112>(v);
  v += dpp_zero<0x114>(v);
  v += dpp_zero<0x118>(v);
  v += dpp_zero<0x142>(v);
  v += dpp_zero<0x143>(v);
  return rdlane(v, 63);
}
// full 64-lane int sum, uniform result
__device__ __forceinline__ int wave_isum64(int v) {
  v += dpp0_i<0x111, 0xF>(v);
  v += dpp0_i<0x112, 0xF>(v);
  v += dpp0_i<0x114, 0xF>(v);
  v += dpp0_i<0x118, 0xF>(v);
  v += dpp0_i<0x142, 0xF>(v);
  v += dpp0_i<0x143, 0xF>(v);
  return __builtin_amdgcn_readlane(v, 63);
}
// 64-lane inclusive prefix sum (int), per-lane result
__device__ __forceinline__ int wave_iscan64(int v) {
  v += dpp0_i<0x111, 0xF>(v);
  v += dpp0_i<0x112, 0xF>(v);
  v += dpp0_i<0x114, 0xF>(v);
  v += dpp0_i<0x118, 0xF>(v);
  v += dpp0_i<0x142, 0xA>(v);
  v += dpp0_i<0x143, 0xC>(v);
  return v;
}

// Successive-softmax chain, ONE row per wave (scalar f32; component-wise
// identical arithmetic to the previous packed version -> bit-exact output).
// Element j of the row = lane*16 + j. om clamp folds to the VOP3 clamp
// modifier; equivalent to ref's 1e-20 floor at fp32.
// State = w[16]+kh[16] = 32 VGPRs -> fits the 64-VGPR / 8-waves-per-EU tier
// with no AGPR shuttling (the 2-row packed version needed 64 regs of state
// alone and paid per-iteration copy traffic).
__device__ void run_chain1(float w[16], float kh[16]) {
#pragma unroll
  for (int i = 0; i < 16; ++i) kh[i] = 0.0f;
#pragma unroll 2
  for (int it = 0; it < KSEL; ++it) {
    float t0 = w[0] + w[1], t1 = w[2] + w[3], t2 = w[4] + w[5], t3 = w[6] + w[7];
    float t4 = w[8] + w[9], t5 = w[10] + w[11], t6 = w[12] + w[13], t7 = w[14] + w[15];
    t0 += t1; t2 += t3; t4 += t5; t6 += t7;
    t0 += t2; t4 += t6;
    t0 += t4;
    float Z = wave_sum64_dpp(t0);
    Z = fmaxf(Z, 1e-30f);
    float r = __builtin_amdgcn_rcpf(Z);
    float rZ = __builtin_fmaf(__builtin_fmaf(-Z, r, 1.0f), r, r);
#pragma unroll
    for (int i = 0; i < 16; ++i) {
      kh[i] = __builtin_fmaf(w[i], rZ, kh[i]);
      float om = __builtin_fmaf(-w[i], rZ, 1.0f);
      om = fminf(fmaxf(om, 0.0f), 1.0f);
      w[i] = w[i] * om;
    }
  }
}

// Tie path (cold). jax stable tie semantics: all >T, then ==T in ascending
// global index ((lane<<4)|slot).
__device__ unsigned tie_mask1(const float kh[16], unsigned T, int lane) {
  unsigned gt = 0, eq = 0;
#pragma unroll
  for (int i = 0; i < 16; ++i) {
    const unsigned u = __float_as_uint(kh[i]);
    gt |= (u > T ? 1u : 0u) << i;
    eq |= (u == T ? 1u : 0u) << i;
  }
  const int n_gt = wave_isum64(__popc(gt));
  const int m = 32 - n_gt;  // uniform, >= 1 by search invariant
  const int pe = __popc(eq);
  const int be = wave_iscan64(pe) - pe;
  int need = m - be;
  need = need < 0 ? 0 : (need > pe ? pe : need);
  unsigned tk = 0;
  unsigned em = eq;
  for (int guard = 0; guard < 16; ++guard) {
    if (!__any(need > 0)) break;
    if (need > 0) {
      const int bpos = __ffs(em) - 1;
      tk |= 1u << bpos;
      em &= em - 1;
      --need;
    }
  }
  return gt | tk;
}

// Top-32 via binary search on the uint view (khot >= 0 -> order-isomorphic),
// ballot+popcll counting, early exit when exact. Invariant (field-validated):
// tie path always completes exactly 32.
__device__ unsigned top32_mask1(const float kh[16], int lane) {
  unsigned lo = 0;
  bool ex = false;
  for (int b = 30; b >= 0; --b) {
    const unsigned cv = lo | (1u << b);
    int c = 0;
#pragma unroll
    for (int i = 0; i < 16; ++i)
      c += __popcll(__ballot(__float_as_uint(kh[i]) >= cv));
    if (c >= 32) {
      lo = cv;
      if (c == 32) { ex = true; break; }
    }
  }
  if (ex) {
    unsigned mk = 0;
#pragma unroll
    for (int i = 0; i < 16; ++i)
      mk |= (__float_as_uint(kh[i]) >= lo ? 1u : 0u) << i;
    return mk;
  }
  return tie_mask1(kh, lo, lane);
}

// Compact the 32 selected global indices into dst[0..31], ascending order.
__device__ __forceinline__ void compact_idx(unsigned mask, int lane,
                                            int* __restrict__ dst) {
  const int pe = __popc(mask);
  int base = wave_iscan64(pe) - pe;
  unsigned m = mask;
  while (m) {
    const int s = __ffs(m) - 1;
    m &= m - 1;
    dst[base++] = (lane << 4) | s;
  }
}

__device__ __forceinline__ void write_half(float* __restrict__ dst,
                                           unsigned mask, int lane) {
  float4* o4 = (float4*)dst;
#pragma unroll
  for (int q = 0; q < 4; ++q) {
    float4 o;
    o.x = ((mask >> (4 * q + 0)) & 1) ? 1.0f : 0.0f;
    o.y = ((mask >> (4 * q + 1)) & 1) ? 1.0f : 0.0f;
    o.z = ((mask >> (4 * q + 2)) & 1) ? 1.0f : 0.0f;
    o.w = ((mask >> (4 * q + 3)) & 1) ? 1.0f : 0.0f;
    o4[lane * 4 + q] = o;
  }
}

// ---- precompute, stage 1 (grid 256): the two length-1024 dot layers ----
extern "C" __global__ void pcfs_pre1(const float* __restrict__ ba,
                                     const float* __restrict__ W1a,
                                     const float* __restrict__ b1a,
                                     const float* __restrict__ bb,
                                     const float* __restrict__ W1b,
                                     float* __restrict__ ws) {
  const int b = blockIdx.x;
  const int t = threadIdx.x;
  float acc = 0.0f;
  if (b < 128) {
#pragma unroll
    for (int j = t; j < N_ORB; j += 256) acc += ba[j] * W1a[j * 128 + b];
  } else {
    const int n = b - 128;
#pragma unroll
    for (int j = t; j < N_ORB; j += 256) acc += bb[j] * W1b[j * 128 + n];
  }
  __shared__ float red[4];
  float wsum = wave_sum64_dpp(acc);
  if ((t & 63) == 0) red[t >> 6] = wsum;
  __syncthreads();
  if (t == 0) {
    float tot = red[0] + red[1] + red[2] + red[3];
    if (b < 128)
      ws[1152 + b] = leaky(tot + b1a[b]);
    else
      ws[N_ORB + (b - 128)] = tot;
  }
}

// ---- precompute, stage 2 (1 block x 1024): h2 + alpha const logits ----
extern "C" __global__ void pcfs_pre2(const float* __restrict__ ba,
                                     const float* __restrict__ W2a,
                                     const float* __restrict__ b2a,
                                     const float* __restrict__ W3a,
                                     const float* __restrict__ b3a,
                                     float* __restrict__ ws) {
  __shared__ float h1[128];
  __shared__ float h2[64];
  const int t = threadIdx.x;
  if (t < 128) h1[t] = ws[1152 + t];
  __syncthreads();
  if (t < 64) {
    float acc = b2a[t];
#pragma unroll 8
    for (int n = 0; n < 128; ++n) acc += h1[n] * W2a[n * 64 + t];
    h2[t] = leaky(acc);
  }
  __syncthreads();
  float acc = b3a[t];
#pragma unroll 8
  for (int m = 0; m < 64; ++m) acc += h2[m] * W3a[m * N_ORB + t];
  ws[t] = acc + ba[t];  // + base_a
}

// ONE wave per batch row. 2048 blocks x 4 waves -> 32 waves/CU grid-side;
// launch_bounds(256, 8) targets the 8-waves-per-EU tier (needs <=64 VGPRs;
// scalar state peaks ~46) so the serial DPP reduce + beta-stage loads are
// hidden by TLP instead of register prefetch.
extern "C" __global__ void __launch_bounds__(256, 8) pcfs_sampler(
    const float* __restrict__ ws, const float* __restrict__ Wc,
    const float* __restrict__ bc, const float* __restrict__ W1b,
    const float* __restrict__ b1b, const float* __restrict__ W2b,
    const float* __restrict__ b2b, const float* __restrict__ W3b,
    const float* __restrict__ b3b, const float* __restrict__ bb,
    const float* __restrict__ g_alpha, const float* __restrict__ g_beta,
    float* __restrict__ out, int B) {
  __shared__ int sidx[4][32];  // per-wave: 32 selected alpha indices
  const int wave = threadIdx.x >> 6;
  const int lane = threadIdx.x & 63;
  const int row = blockIdx.x * 4 + wave;
  if (row >= B) return;

  float w[16], kh[16];

  // ---- alpha chain: w = exp2((const_logits + gumbel) * log2e) ----
  {
    const float4* c4 = (const float4*)ws;
    const float4* g4 = (const float4*)(g_alpha + (size_t)row * N_ORB);
#pragma unroll
    for (int q = 0; q < 4; ++q) {
      float4 c = c4[lane * 4 + q];
      float4 g = g4[lane * 4 + q];
      w[4 * q + 0] = __builtin_amdgcn_exp2f((c.x + g.x) * LOG2E);
      w[4 * q + 1] = __builtin_amdgcn_exp2f((c.y + g.y) * LOG2E);
      w[4 * q + 2] = __builtin_amdgcn_exp2f((c.z + g.z) * LOG2E);
      w[4 * q + 3] = __builtin_amdgcn_exp2f((c.w + g.w) * LOG2E);
    }
  }
  run_chain1(w, kh);
  const unsigned am = top32_mask1(kh, lane);

  // write alpha half (hard config: exact 0/1)
  write_half(out + (size_t)row * (2 * N_ORB), am, lane);

  // ---- ctx = alpha_config @ Wc + bc (LDS compact + fixed 32-trip) ----
  compact_idx(am, lane, sidx[wave]);
  const int vi = sidx[wave][lane & 31];
  float ctx = bc[lane & 31];
#pragma unroll
  for (int r = 0; r < 32; ++r) {
    const int i0 = __builtin_amdgcn_readlane(vi, r);  // uniform
    ctx += Wc[i0 * 32 + (lane & 31)];
  }

  // ---- h1 = leaky(base_b@W1b[0:1024] + ctx@W1b[1024:1056] + b1b) ----
  float h1a = b1b[lane] + ws[N_ORB + lane];
  float h1b = b1b[lane + 64] + ws[N_ORB + lane + 64];
#pragma unroll 4
  for (int c = 0; c < 32; ++c) {
    const float cv = rdlane(ctx, c);
    const float* wr = W1b + (size_t)(N_ORB + c) * 128;
    h1a = __builtin_fmaf(wr[lane], cv, h1a);
    h1b = __builtin_fmaf(wr[lane + 64], cv, h1b);
  }
  h1a = leaky(h1a);
  h1b = leaky(h1b);

  // ---- h2 = leaky(h1 @ W2b + b2b): 4 partial accumulators (32-deep
  // chains instead of 128-deep) ----
  float p0 = b2b[lane], p1 = 0.0f, p2 = 0.0f, p3 = 0.0f;
#pragma unroll 4
  for (int n = 0; n < 64; n += 4) {
    p0 = __builtin_fmaf(W2b[(n + 0) * 64 + lane], rdlane(h1a, n + 0), p0);
    p1 = __builtin_fmaf(W2b[(n + 1) * 64 + lane], rdlane(h1a, n + 1), p1);
    p2 = __builtin_fmaf(W2b[(n + 2) * 64 + lane], rdlane(h1a, n + 2), p2);
    p3 = __builtin_fmaf(W2b[(n + 3) * 64 + lane], rdlane(h1a, n + 3), p3);
  }
#pragma unroll 4
  for (int n = 0; n < 64; n += 4) {
    p0 = __builtin_fmaf(W2b[(n + 64 + 0) * 64 + lane], rdlane(h1b, n + 0), p0);
    p1 = __builtin_fmaf(W2b[(n + 64 + 1) * 64 + lane], rdlane(h1b, n + 1), p1);
    p2 = __builtin_fmaf(W2b[(n + 64 + 2) * 64 + lane], rdlane(h1b, n + 2), p2);
    p3 = __builtin_fmaf(W2b[(n + 64 + 3) * 64 + lane], rdlane(h1b, n + 3), p3);
  }
  float h2v = (p0 + p1) + (p2 + p3);
  h2v = leaky(h2v);

  // ---- beta logits: w[] = h2 @ W3b + b3b; float4 W3b loads, x4 unroll ----
  {
    const float4* b4 = (const float4*)b3b;
#pragma unroll
    for (int q = 0; q < 4; ++q) {
      float4 b = b4[lane * 4 + q];
      w[4 * q + 0] = b.x;
      w[4 * q + 1] = b.y;
      w[4 * q + 2] = b.z;
      w[4 * q + 3] = b.w;
    }
  }
#pragma unroll 4
  for (int m = 0; m < 64; ++m) {
    const float hm = rdlane(h2v, m);
    const float4* w4 = (const float4*)(W3b + m * N_ORB);
#pragma unroll
    for (int q = 0; q < 4; ++q) {
      float4 wv = w4[lane * 4 + q];
      w[4 * q + 0] = __builtin_fmaf(wv.x, hm, w[4 * q + 0]);
      w[4 * q + 1] = __builtin_fmaf(wv.y, hm, w[4 * q + 1]);
      w[4 * q + 2] = __builtin_fmaf(wv.z, hm, w[4 * q + 2]);
      w[4 * q + 3] = __builtin_fmaf(wv.w, hm, w[4 * q + 3]);
    }
  }
  // + base_b + gumbel -> w = exp2(logits * log2e). No register prefetch:
  // at 8 waves/EU these loads are hidden by the other waves' alpha phases.
  {
    const float4* bb4 = (const float4*)bb;
    const float4* g4 = (const float4*)(g_beta + (size_t)row * N_ORB);
#pragma unroll
    for (int q = 0; q < 4; ++q) {
      float4 b = bb4[lane * 4 + q];
      float4 g = g4[lane * 4 + q];
      w[4 * q + 0] = __builtin_amdgcn_exp2f((w[4 * q + 0] + b.x + g.x) * LOG2E);
      w[4 * q + 1] = __builtin_amdgcn_exp2f((w[4 * q + 1] + b.y + g.y) * LOG2E);
      w[4 * q + 2] = __builtin_amdgcn_exp2f((w[4 * q + 2] + b.z + g.z) * LOG2E);
      w[4 * q + 3] = __builtin_amdgcn_exp2f((w[4 * q + 3] + b.w + g.w) * LOG2E);
    }
  }
  run_chain1(w, kh);
  const unsigned bm = top32_mask1(kh, lane);

  write_half(out + (size_t)row * (2 * N_ORB) + N_ORB, bm, lane);
}

extern "C" void kernel_launch(void* const* d_in, const int* in_sizes, int n_in,
                              void* d_out, int out_size, void* d_ws, size_t ws_size,
                              hipStream_t stream) {
  const float* ba  = (const float*)d_in[0];
  const float* W1a = (const float*)d_in[1];
  const float* b1a = (const float*)d_in[2];
  const float* W2a = (const float*)d_in[3];
  const float* b2a = (const float*)d_in[4];
  const float* W3a = (const float*)d_in[5];
  const float* b3a = (const float*)d_in[6];
  const float* bb  = (const float*)d_in[7];
  const float* Wc  = (const float*)d_in[8];
  const float* bc  = (const float*)d_in[9];
  const float* W1b = (const float*)d_in[10];
  const float* b1b = (const float*)d_in[11];
  const float* W2b = (const float*)d_in[12];
  const float* b2b = (const float*)d_in[13];
  const float* W3b = (const float*)d_in[14];
  const float* b3b = (const float*)d_in[15];
  const float* ga  = (const float*)d_in[16];
  const float* gbt = (const float*)d_in[17];
  const int B = in_sizes[16] / N_ORB;
  float* ws = (float*)d_ws;

  hipLaunchKernelGGL(pcfs_pre1, dim3(256), dim3(256), 0, stream,
                     ba, W1a, b1a, bb, W1b, ws);
  hipLaunchKernelGGL(pcfs_pre2, dim3(1), dim3(1024), 0, stream,
                     ba, W2a, b2a, W3a, b3a, ws);
  hipLaunchKernelGGL(pcfs_sampler, dim3((B + 3) / 4), dim3(256), 0, stream,
                     ws, Wc, bc, W1b, b1b, W2b, b2b, W3b, b3b, bb,
                     ga, gbt, (float*)d_out, B);
}

// Round 4
// 281.775 us; speedup vs baseline: 1.1422x; 1.1422x over previous
//
#include <hip/hip_runtime.h>
#include <hip/hip_bf16.h>
#include <float.h>

#define N_ORB 1024
#define KSEL 32
#define LEAK 0.01f
#define LOG2E 1.4426950408889634f

typedef float f32x2 __attribute__((ext_vector_type(2)));
// NOTE: never write (f32x2)(a, b) — in C++ that's a comma-expr cast that
// SPLATS b. Use f32x2{a, b}.

__device__ __forceinline__ float leaky(float x) { return x >= 0.0f ? x : LEAK * x; }

// ---- DPP helpers ----
template <int CTRL, int RM>
__device__ __forceinline__ int dpp0_i(int v) {  // masked-off rows contribute 0
  return __builtin_amdgcn_update_dpp(0, v, CTRL, RM, 0xF, true);
}
template <int CTRL>
__device__ __forceinline__ float dpp_zero(float v) {
  return __int_as_float(
      __builtin_amdgcn_update_dpp(0, __float_as_int(v), CTRL, 0xF, 0xF, true));
}
__device__ __forceinline__ float rdlane(float v, int l) {
  return __int_as_float(__builtin_amdgcn_readlane(__float_as_int(v), l));
}

// full 64-lane float sum, uniform result
__device__ __forceinline__ float wave_sum64_dpp(float v) {
  v += dpp_zero<0x111>(v);
  v += dpp_zero<0x112>(v);
  v += dpp_zero<0x114>(v);
  v += dpp_zero<0x118>(v);
  v += dpp_zero<0x142>(v);
  v += dpp_zero<0x143>(v);
  return rdlane(v, 63);
}
// full 64-lane int sum, uniform result
__device__ __forceinline__ int wave_isum64(int v) {
  v += dpp0_i<0x111, 0xF>(v);
  v += dpp0_i<0x112, 0xF>(v);
  v += dpp0_i<0x114, 0xF>(v);
  v += dpp0_i<0x118, 0xF>(v);
  v += dpp0_i<0x142, 0xF>(v);
  v += dpp0_i<0x143, 0xF>(v);
  return __builtin_amdgcn_readlane(v, 63);
}
// 64-lane inclusive prefix sum (int), per-lane result
__device__ __forceinline__ int wave_iscan64(int v) {
  v += dpp0_i<0x111, 0xF>(v);
  v += dpp0_i<0x112, 0xF>(v);
  v += dpp0_i<0x114, 0xF>(v);
  v += dpp0_i<0x118, 0xF>(v);
  v += dpp0_i<0x142, 0xA>(v);
  v += dpp0_i<0x143, 0xC>(v);
  return v;
}

// Successive-softmax chain for TWO rows packed in f32x2 (.x=row0,.y=row1),
// multiplicative form (w tracks exp(s)). Element j of a row = lane*16 + j.
// om clamp folds to the VOP3 clamp modifier; equivalent to ref's 1e-20 floor
// at fp32 (khot deltas <= 1e-20, far below any top-32 boundary).
__device__ void run_chain2(f32x2 w[16], f32x2 kh[16]) {
#pragma unroll
  for (int i = 0; i < 16; ++i) kh[i] = f32x2{0.0f, 0.0f};
  const f32x2 onev = f32x2{1.0f, 1.0f};
  const f32x2 zerov = f32x2{0.0f, 0.0f};
  for (int it = 0; it < KSEL; ++it) {
    f32x2 t0 = w[0] + w[1], t1 = w[2] + w[3], t2 = w[4] + w[5], t3 = w[6] + w[7];
    f32x2 t4 = w[8] + w[9], t5 = w[10] + w[11], t6 = w[12] + w[13], t7 = w[14] + w[15];
    t0 += t1; t2 += t3; t4 += t5; t6 += t7;
    t0 += t2; t4 += t6;
    t0 += t4;
    float Z0 = wave_sum64_dpp(t0.x);  // independent of Z1 -> interleaved issue
    float Z1 = wave_sum64_dpp(t0.y);
    Z0 = fmaxf(Z0, 1e-30f);
    Z1 = fmaxf(Z1, 1e-30f);
    float r0 = __builtin_amdgcn_rcpf(Z0);
    float r1 = __builtin_amdgcn_rcpf(Z1);
    float rZ0 = __builtin_fmaf(__builtin_fmaf(-Z0, r0, 1.0f), r0, r0);
    float rZ1 = __builtin_fmaf(__builtin_fmaf(-Z1, r1, 1.0f), r1, r1);
    const f32x2 rZ = f32x2{rZ0, rZ1};
#pragma unroll
    for (int i = 0; i < 16; ++i) {
      kh[i] = __builtin_elementwise_fma(w[i], rZ, kh[i]);
      f32x2 om = __builtin_elementwise_fma(-w[i], rZ, onev);
      om = __builtin_elementwise_min(__builtin_elementwise_max(om, zerov), onev);
      w[i] = w[i] * om;
    }
  }
}

// Tie path for one row (cold). jax stable tie semantics: all >T, then ==T
// in ascending global index ((lane<<4)|slot).
__device__ unsigned tie_mask16(const f32x2 kh[16], bool comp_y, unsigned T,
                               int lane) {
  unsigned gt = 0, eq = 0;
#pragma unroll
  for (int i = 0; i < 16; ++i) {
    const unsigned u = __float_as_uint(comp_y ? kh[i].y : kh[i].x);
    gt |= (u > T ? 1u : 0u) << i;
    eq |= (u == T ? 1u : 0u) << i;
  }
  const int n_gt = wave_isum64(__popc(gt));
  const int m = 32 - n_gt;  // uniform, >= 1 by search invariant
  const int pe = __popc(eq);
  const int be = wave_iscan64(pe) - pe;
  int need = m - be;
  need = need < 0 ? 0 : (need > pe ? pe : need);
  unsigned tk = 0;
  unsigned em = eq;
  for (int guard = 0; guard < 16; ++guard) {
    if (!__any(need > 0)) break;
    if (need > 0) {
      const int bpos = __ffs(em) - 1;
      tk |= 1u << bpos;
      em &= em - 1;
      --need;
    }
  }
  return gt | tk;
}

// Top-32 for both packed rows: joint binary search on the uint views
// (khot >= 0 -> order-isomorphic), ballot+popcll counting, early exit when
// both rows exact. Invariant (r6/r7, field-validated): tie path always
// completes exactly 32.
__device__ void top32_mask2(const f32x2 kh[16], int lane, unsigned& m0,
                            unsigned& m1) {
  unsigned lo0 = 0, lo1 = 0;
  bool ex0 = false, ex1 = false;
  for (int b = 30; b >= 0; --b) {
    const unsigned c0v = lo0 | (1u << b);
    const unsigned c1v = lo1 | (1u << b);
    int c0 = 0, c1 = 0;
#pragma unroll
    for (int i = 0; i < 16; ++i) {
      c0 += __popcll(__ballot(__float_as_uint(kh[i].x) >= c0v));
      c1 += __popcll(__ballot(__float_as_uint(kh[i].y) >= c1v));
    }
    if (!ex0 && c0 >= 32) { lo0 = c0v; ex0 = (c0 == 32); }
    if (!ex1 && c1 >= 32) { lo1 = c1v; ex1 = (c1 == 32); }
    if (ex0 && ex1) break;
  }

  if (ex0) {
    unsigned mk = 0;
#pragma unroll
    for (int i = 0; i < 16; ++i)
      mk |= (__float_as_uint(kh[i].x) >= lo0 ? 1u : 0u) << i;
    m0 = mk;
  } else {
    m0 = tie_mask16(kh, false, lo0, lane);
  }
  if (ex1) {
    unsigned mk = 0;
#pragma unroll
    for (int i = 0; i < 16; ++i)
      mk |= (__float_as_uint(kh[i].y) >= lo1 ? 1u : 0u) << i;
    m1 = mk;
  } else {
    m1 = tie_mask16(kh, true, lo1, lane);
  }
}

// Compact the 32 selected global indices into dst[0..31], ascending order.
__device__ __forceinline__ void compact_idx(unsigned mask, int lane,
                                            int* __restrict__ dst) {
  const int pe = __popc(mask);
  int base = wave_iscan64(pe) - pe;
  unsigned m = mask;
  while (m) {
    const int s = __ffs(m) - 1;
    m &= m - 1;
    dst[base++] = (lane << 4) | s;
  }
}

__device__ __forceinline__ void write_half(float* __restrict__ dst,
                                           unsigned mask, int lane) {
  float4* o4 = (float4*)dst;
#pragma unroll
  for (int q = 0; q < 4; ++q) {
    float4 o;
    o.x = ((mask >> (4 * q + 0)) & 1) ? 1.0f : 0.0f;
    o.y = ((mask >> (4 * q + 1)) & 1) ? 1.0f : 0.0f;
    o.z = ((mask >> (4 * q + 2)) & 1) ? 1.0f : 0.0f;
    o.w = ((mask >> (4 * q + 3)) & 1) ? 1.0f : 0.0f;
    o4[lane * 4 + q] = o;
  }
}

// ws layout (floats): [0,1024) alpha const logits; [1024,1152) beta base
// dots; [1152,1280) h1a; [1280,1344) h2a.

// ---- precompute, stage 1 (grid 256): the two length-1024 dot layers ----
extern "C" __global__ void pcfs_pre1(const float* __restrict__ ba,
                                     const float* __restrict__ W1a,
                                     const float* __restrict__ b1a,
                                     const float* __restrict__ bb,
                                     const float* __restrict__ W1b,
                                     float* __restrict__ ws) {
  const int b = blockIdx.x;
  const int t = threadIdx.x;
  float acc = 0.0f;
  if (b < 128) {
#pragma unroll
    for (int j = t; j < N_ORB; j += 256) acc += ba[j] * W1a[j * 128 + b];
  } else {
    const int n = b - 128;
#pragma unroll
    for (int j = t; j < N_ORB; j += 256) acc += bb[j] * W1b[j * 128 + n];
  }
  __shared__ float red[4];
  float wsum = wave_sum64_dpp(acc);
  if ((t & 63) == 0) red[t >> 6] = wsum;
  __syncthreads();
  if (t == 0) {
    float tot = red[0] + red[1] + red[2] + red[3];
    if (b < 128)
      ws[1152 + b] = leaky(tot + b1a[b]);
    else
      ws[N_ORB + (b - 128)] = tot;
  }
}

// ---- precompute, stage 2a (1 block x 64): h2 = leaky(h1 @ W2a + b2a) ----
// Tiny working set (32 KB of W2a) — single block is fine.
extern "C" __global__ void pcfs_pre2a(const float* __restrict__ W2a,
                                      const float* __restrict__ b2a,
                                      float* __restrict__ ws) {
  const int t = threadIdx.x;  // 64
  float acc = b2a[t];
#pragma unroll 8
  for (int n = 0; n < 128; ++n) acc = __builtin_fmaf(ws[1152 + n], W2a[n * 64 + t], acc);
  ws[1280 + t] = leaky(acc);
}

// ---- precompute, stage 2b (grid 4 x 256): alpha logits = h2 @ W3a + b3a
// + base_a. Previously a single-block kernel streamed W3a's 256 KB from HBM
// alone (~100 us latency-bound); 4 blocks with coalesced row-major reads and
// x8 unroll pipeline the fetches. ----
extern "C" __global__ void pcfs_pre2b(const float* __restrict__ ba,
                                      const float* __restrict__ W3a,
                                      const float* __restrict__ b3a,
                                      float* __restrict__ ws) {
  __shared__ float h2s[64];
  const int t = threadIdx.x;
  const int o = blockIdx.x * 256 + t;
  if (t < 64) h2s[t] = ws[1280 + t];
  __syncthreads();
  float acc = b3a[o] + ba[o];
#pragma unroll 8
  for (int m = 0; m < 64; ++m) acc = __builtin_fmaf(h2s[m], W3a[m * N_ORB + o], acc);
  ws[o] = acc;
}

// One wave per PAIR of batch rows (.x=row0, .y=row1 in every f32x2).
// (R1-verified config: 152 us, absmax 0 — do not touch while attributing
// the pre-kernel fix.)
extern "C" __global__ void __launch_bounds__(256, 4) pcfs_sampler(
    const float* __restrict__ ws, const float* __restrict__ Wc,
    const float* __restrict__ bc, const float* __restrict__ W1b,
    const float* __restrict__ b1b, const float* __restrict__ W2b,
    const float* __restrict__ b2b, const float* __restrict__ W3b,
    const float* __restrict__ b3b, const float* __restrict__ bb,
    const float* __restrict__ g_alpha, const float* __restrict__ g_beta,
    float* __restrict__ out, int B) {
  __shared__ int sidx[4][64];  // per-wave: [0..31]=row0 idxs, [32..63]=row1
  const int wave = threadIdx.x >> 6;
  const int lane = threadIdx.x & 63;
  const int pair = blockIdx.x * 4 + wave;
  const int row0 = pair * 2;
  if (row0 >= B) return;
  const bool have1 = (row0 + 1 < B);
  const int row1 = have1 ? row0 + 1 : row0;

  // ---- prefetch g_beta into registers NOW: these HBM loads drain ~10k
  // cycles later (beta exp2 stage), fully hidden behind the alpha phase ----
  float4 gb0[4], gb1[4];
  {
    const float4* g40 = (const float4*)(g_beta + (size_t)row0 * N_ORB);
    const float4* g41 = (const float4*)(g_beta + (size_t)row1 * N_ORB);
#pragma unroll
    for (int q = 0; q < 4; ++q) {
      gb0[q] = g40[lane * 4 + q];
      gb1[q] = g41[lane * 4 + q];
    }
  }

  f32x2 w[16], kh[16];

  // ---- alpha chains: w = exp2((const_logits + gumbel) * log2e), 2 rows ----
  {
    const float4* c4 = (const float4*)ws;
    const float4* g40 = (const float4*)(g_alpha + (size_t)row0 * N_ORB);
    const float4* g41 = (const float4*)(g_alpha + (size_t)row1 * N_ORB);
#pragma unroll
    for (int q = 0; q < 4; ++q) {
      float4 c = c4[lane * 4 + q];
      float4 g0 = g40[lane * 4 + q];
      float4 g1 = g41[lane * 4 + q];
      w[4 * q + 0] = f32x2{__builtin_amdgcn_exp2f((c.x + g0.x) * LOG2E),
                           __builtin_amdgcn_exp2f((c.x + g1.x) * LOG2E)};
      w[4 * q + 1] = f32x2{__builtin_amdgcn_exp2f((c.y + g0.y) * LOG2E),
                           __builtin_amdgcn_exp2f((c.y + g1.y) * LOG2E)};
      w[4 * q + 2] = f32x2{__builtin_amdgcn_exp2f((c.z + g0.z) * LOG2E),
                           __builtin_amdgcn_exp2f((c.z + g1.z) * LOG2E)};
      w[4 * q + 3] = f32x2{__builtin_amdgcn_exp2f((c.w + g0.w) * LOG2E),
                           __builtin_amdgcn_exp2f((c.w + g1.w) * LOG2E)};
    }
  }
  run_chain2(w, kh);
  unsigned am0, am1;
  top32_mask2(kh, lane, am0, am1);

  // write alpha halves (hard config: exact 0/1)
  write_half(out + (size_t)row0 * (2 * N_ORB), am0, lane);
  if (have1) write_half(out + (size_t)row1 * (2 * N_ORB), am1, lane);

  // ---- ctx = alpha_config @ Wc + bc, per row (LDS compact + fixed trip) ----
  compact_idx(am0, lane, &sidx[wave][0]);
  compact_idx(am1, lane, &sidx[wave][32]);
  const int vi0 = sidx[wave][lane & 31];
  const int vi1 = sidx[wave][32 + (lane & 31)];
  const float bcv = bc[lane & 31];
  float ctx0 = bcv, ctx1 = bcv;
#pragma unroll
  for (int r = 0; r < 32; ++r) {
    const int i0 = __builtin_amdgcn_readlane(vi0, r);  // uniform
    const int i1 = __builtin_amdgcn_readlane(vi1, r);
    ctx0 += Wc[i0 * 32 + (lane & 31)];
    ctx1 += Wc[i1 * 32 + (lane & 31)];
  }

  // ---- h1 = leaky(base_b@W1b[0:1024] + ctx@W1b[1024:1056] + b1b) ----
  f32x2 h1a, h1b_;
  {
    const float ia = b1b[lane] + ws[N_ORB + lane];
    const float ib = b1b[lane + 64] + ws[N_ORB + lane + 64];
    h1a = f32x2{ia, ia};
    h1b_ = f32x2{ib, ib};
  }
#pragma unroll 4
  for (int c = 0; c < 32; ++c) {
    const f32x2 cv = f32x2{rdlane(ctx0, c), rdlane(ctx1, c)};
    const float* wr = W1b + (size_t)(N_ORB + c) * 128;
    const float wa = wr[lane], wb = wr[lane + 64];
    h1a = __builtin_elementwise_fma(f32x2{wa, wa}, cv, h1a);
    h1b_ = __builtin_elementwise_fma(f32x2{wb, wb}, cv, h1b_);
  }
  h1a = f32x2{leaky(h1a.x), leaky(h1a.y)};
  h1b_ = f32x2{leaky(h1b_.x), leaky(h1b_.y)};

  // ---- h2 = leaky(h1 @ W2b + b2b): 4 partial accumulators (32-deep
  // chains instead of 128-deep) ----
  f32x2 h2p0, h2p1, h2p2, h2p3;
  {
    const float i2 = b2b[lane];
    h2p0 = f32x2{i2, i2};
    h2p1 = f32x2{0.0f, 0.0f};
    h2p2 = f32x2{0.0f, 0.0f};
    h2p3 = f32x2{0.0f, 0.0f};
  }
#pragma unroll 4
  for (int n = 0; n < 64; n += 4) {
    const f32x2 v0 = f32x2{rdlane(h1a.x, n + 0), rdlane(h1a.y, n + 0)};
    const f32x2 v1 = f32x2{rdlane(h1a.x, n + 1), rdlane(h1a.y, n + 1)};
    const f32x2 v2 = f32x2{rdlane(h1a.x, n + 2), rdlane(h1a.y, n + 2)};
    const f32x2 v3 = f32x2{rdlane(h1a.x, n + 3), rdlane(h1a.y, n + 3)};
    const float w0 = W2b[(n + 0) * 64 + lane];
    const float w1 = W2b[(n + 1) * 64 + lane];
    const float w2 = W2b[(n + 2) * 64 + lane];
    const float w3 = W2b[(n + 3) * 64 + lane];
    h2p0 = __builtin_elementwise_fma(f32x2{w0, w0}, v0, h2p0);
    h2p1 = __builtin_elementwise_fma(f32x2{w1, w1}, v1, h2p1);
    h2p2 = __builtin_elementwise_fma(f32x2{w2, w2}, v2, h2p2);
    h2p3 = __builtin_elementwise_fma(f32x2{w3, w3}, v3, h2p3);
  }
#pragma unroll 4
  for (int n = 0; n < 64; n += 4) {
    const f32x2 v0 = f32x2{rdlane(h1b_.x, n + 0), rdlane(h1b_.y, n + 0)};
    const f32x2 v1 = f32x2{rdlane(h1b_.x, n + 1), rdlane(h1b_.y, n + 1)};
    const f32x2 v2 = f32x2{rdlane(h1b_.x, n + 2), rdlane(h1b_.y, n + 2)};
    const f32x2 v3 = f32x2{rdlane(h1b_.x, n + 3), rdlane(h1b_.y, n + 3)};
    const float w0 = W2b[(n + 64 + 0) * 64 + lane];
    const float w1 = W2b[(n + 64 + 1) * 64 + lane];
    const float w2 = W2b[(n + 64 + 2) * 64 + lane];
    const float w3 = W2b[(n + 64 + 3) * 64 + lane];
    h2p0 = __builtin_elementwise_fma(f32x2{w0, w0}, v0, h2p0);
    h2p1 = __builtin_elementwise_fma(f32x2{w1, w1}, v1, h2p1);
    h2p2 = __builtin_elementwise_fma(f32x2{w2, w2}, v2, h2p2);
    h2p3 = __builtin_elementwise_fma(f32x2{w3, w3}, v3, h2p3);
  }
  f32x2 h2v = (h2p0 + h2p1) + (h2p2 + h2p3);
  h2v = f32x2{leaky(h2v.x), leaky(h2v.y)};

  // ---- beta logits: acc (in w[]) = h2 @ W3b + b3b; shared W3b loads,
  // unrolled x4 so 16 float4 loads pipeline per group ----
  {
    const float4* b4 = (const float4*)b3b;
#pragma unroll
    for (int q = 0; q < 4; ++q) {
      float4 b = b4[lane * 4 + q];
      w[4 * q + 0] = f32x2{b.x, b.x};
      w[4 * q + 1] = f32x2{b.y, b.y};
      w[4 * q + 2] = f32x2{b.z, b.z};
      w[4 * q + 3] = f32x2{b.w, b.w};
    }
  }
#pragma unroll 4
  for (int m = 0; m < 64; ++m) {
    const f32x2 hm = f32x2{rdlane(h2v.x, m), rdlane(h2v.y, m)};
    const float4* w4 = (const float4*)(W3b + m * N_ORB);
#pragma unroll
    for (int q = 0; q < 4; ++q) {
      float4 wv = w4[lane * 4 + q];
      w[4 * q + 0] = __builtin_elementwise_fma(f32x2{wv.x, wv.x}, hm, w[4 * q + 0]);
      w[4 * q + 1] = __builtin_elementwise_fma(f32x2{wv.y, wv.y}, hm, w[4 * q + 1]);
      w[4 * q + 2] = __builtin_elementwise_fma(f32x2{wv.z, wv.z}, hm, w[4 * q + 2]);
      w[4 * q + 3] = __builtin_elementwise_fma(f32x2{wv.w, wv.w}, hm, w[4 * q + 3]);
    }
  }
  // + base_b + gumbel (prefetched) -> w = exp2(logits * log2e)
  {
    const float4* bb4 = (const float4*)bb;
#pragma unroll
    for (int q = 0; q < 4; ++q) {
      float4 b = bb4[lane * 4 + q];
      const float4 g0 = gb0[q];
      const float4 g1 = gb1[q];
      w[4 * q + 0] = f32x2{
          __builtin_amdgcn_exp2f((w[4 * q + 0].x + b.x + g0.x) * LOG2E),
          __builtin_amdgcn_exp2f((w[4 * q + 0].y + b.x + g1.x) * LOG2E)};
      w[4 * q + 1] = f32x2{
          __builtin_amdgcn_exp2f((w[4 * q + 1].x + b.y + g0.y) * LOG2E),
          __builtin_amdgcn_exp2f((w[4 * q + 1].y + b.y + g1.y) * LOG2E)};
      w[4 * q + 2] = f32x2{
          __builtin_amdgcn_exp2f((w[4 * q + 2].x + b.z + g0.z) * LOG2E),
          __builtin_amdgcn_exp2f((w[4 * q + 2].y + b.z + g1.z) * LOG2E)};
      w[4 * q + 3] = f32x2{
          __builtin_amdgcn_exp2f((w[4 * q + 3].x + b.w + g0.w) * LOG2E),
          __builtin_amdgcn_exp2f((w[4 * q + 3].y + b.w + g1.w) * LOG2E)};
    }
  }
  run_chain2(w, kh);
  unsigned bm0, bm1;
  top32_mask2(kh, lane, bm0, bm1);

  write_half(out + (size_t)row0 * (2 * N_ORB) + N_ORB, bm0, lane);
  if (have1) write_half(out + (size_t)row1 * (2 * N_ORB) + N_ORB, bm1, lane);
}

extern "C" void kernel_launch(void* const* d_in, const int* in_sizes, int n_in,
                              void* d_out, int out_size, void* d_ws, size_t ws_size,
                              hipStream_t stream) {
  const float* ba  = (const float*)d_in[0];
  const float* W1a = (const float*)d_in[1];
  const float* b1a = (const float*)d_in[2];
  const float* W2a = (const float*)d_in[3];
  const float* b2a = (const float*)d_in[4];
  const float* W3a = (const float*)d_in[5];
  const float* b3a = (const float*)d_in[6];
  const float* bb  = (const float*)d_in[7];
  const float* Wc  = (const float*)d_in[8];
  const float* bc  = (const float*)d_in[9];
  const float* W1b = (const float*)d_in[10];
  const float* b1b = (const float*)d_in[11];
  const float* W2b = (const float*)d_in[12];
  const float* b2b = (const float*)d_in[13];
  const float* W3b = (const float*)d_in[14];
  const float* b3b = (const float*)d_in[15];
  const float* ga  = (const float*)d_in[16];
  const float* gbt = (const float*)d_in[17];
  const int B = in_sizes[16] / N_ORB;
  float* ws = (float*)d_ws;

  hipLaunchKernelGGL(pcfs_pre1, dim3(256), dim3(256), 0, stream,
                     ba, W1a, b1a, bb, W1b, ws);
  hipLaunchKernelGGL(pcfs_pre2a, dim3(1), dim3(64), 0, stream,
                     W2a, b2a, ws);
  hipLaunchKernelGGL(pcfs_pre2b, dim3(4), dim3(256), 0, stream,
                     ba, W3a, b3a, ws);
  const int pairs = (B + 1) / 2;
  hipLaunchKernelGGL(pcfs_sampler, dim3((pairs + 3) / 4), dim3(256), 0, stream,
                     ws, Wc, bc, W1b, b1b, W2b, b2b, W3b, b3b, bb,
                     ga, gbt, (float*)d_out, B);
}

// Round 6
// 278.601 us; speedup vs baseline: 1.1553x; 1.0114x over previous
//
#include <hip/hip_runtime.h>
#include <hip/hip_bf16.h>
#include <float.h>

#define N_ORB 1024
#define KSEL 32
#define LEAK 0.01f
#define LOG2E 1.4426950408889634f

typedef float f32x2 __attribute__((ext_vector_type(2)));
// NOTE: never write (f32x2)(a, b) — in C++ that's a comma-expr cast that
// SPLATS b. Use f32x2{a, b}.

__device__ __forceinline__ float leaky(float x) { return x >= 0.0f ? x : LEAK * x; }

// ---- packed-FP32 helpers (gfx90a+/gfx950 VOP3P). Counter arithmetic (R4):
// VALUBusy*dur implies ~22k VALU instr/wave == fully scalarized f32x2 chain.
// The compiler scalarizes (DPP .x/.y extracts + min/max break SLP), so force
// v_pk_* with inline asm. Per-half arithmetic is the identical IEEE op ->
// bit-exact vs the verified scalar version. ----
__device__ __forceinline__ f32x2 pk_add(f32x2 a, f32x2 b) {
  f32x2 d;
  asm("v_pk_add_f32 %0, %1, %2" : "=v"(d) : "v"(a), "v"(b));
  return d;
}
__device__ __forceinline__ f32x2 pk_mul(f32x2 a, f32x2 b) {
  f32x2 d;
  asm("v_pk_mul_f32 %0, %1, %2" : "=v"(d) : "v"(a), "v"(b));
  return d;
}
__device__ __forceinline__ f32x2 pk_fma(f32x2 a, f32x2 b, f32x2 c) {
  f32x2 d;
  asm("v_pk_fma_f32 %0, %1, %2, %3" : "=v"(d) : "v"(a), "v"(b), "v"(c));
  return d;
}
// VOP3P clamp bit == clamp result to [0,1] per half — exactly the verified
// min(max(om,0),1) semantics, in one instruction.
__device__ __forceinline__ f32x2 pk_fma_clamp(f32x2 a, f32x2 b, f32x2 c) {
  f32x2 d;
  asm("v_pk_fma_f32 %0, %1, %2, %3 clamp" : "=v"(d) : "v"(a), "v"(b), "v"(c));
  return d;
}

// ---- DPP helpers ----
template <int CTRL, int RM>
__device__ __forceinline__ int dpp0_i(int v) {  // masked-off rows contribute 0
  return __builtin_amdgcn_update_dpp(0, v, CTRL, RM, 0xF, true);
}
template <int CTRL>
__device__ __forceinline__ float dpp_zero(float v) {
  return __int_as_float(
      __builtin_amdgcn_update_dpp(0, __float_as_int(v), CTRL, 0xF, 0xF, true));
}
__device__ __forceinline__ float rdlane(float v, int l) {
  return __int_as_float(__builtin_amdgcn_readlane(__float_as_int(v), l));
}

// full 64-lane float sum, uniform result
__device__ __forceinline__ float wave_sum64_dpp(float v) {
  v += dpp_zero<0x111>(v);
  v += dpp_zero<0x112>(v);
  v += dpp_zero<0x114>(v);
  v += dpp_zero<0x118>(v);
  v += dpp_zero<0x142>(v);
  v += dpp_zero<0x143>(v);
  return rdlane(v, 63);
}
// full 64-lane int sum, uniform result
__device__ __forceinline__ int wave_isum64(int v) {
  v += dpp0_i<0x111, 0xF>(v);
  v += dpp0_i<0x112, 0xF>(v);
  v += dpp0_i<0x114, 0xF>(v);
  v += dpp0_i<0x118, 0xF>(v);
  v += dpp0_i<0x142, 0xF>(v);
  v += dpp0_i<0x143, 0xF>(v);
  return __builtin_amdgcn_readlane(v, 63);
}
// 64-lane inclusive prefix sum (int), per-lane result
__device__ __forceinline__ int wave_iscan64(int v) {
  v += dpp0_i<0x111, 0xF>(v);
  v += dpp0_i<0x112, 0xF>(v);
  v += dpp0_i<0x114, 0xF>(v);
  v += dpp0_i<0x118, 0xF>(v);
  v += dpp0_i<0x142, 0xA>(v);
  v += dpp0_i<0x143, 0xC>(v);
  return v;
}

// Successive-softmax chain for TWO rows packed in f32x2 (.x=row0,.y=row1),
// multiplicative form (w tracks exp(s)). Element j of a row = lane*16 + j.
// pk_fma_clamp == ref's 1e-20 floor at fp32 (khot deltas <= 1e-20, far below
// any top-32 boundary). fma(w, -rZ, 1) == fma(-w, rZ, 1) exactly (product is
// exact inside fma), so building rZn once per iteration is bit-identical.
__device__ void run_chain2(f32x2 w[16], f32x2 kh[16]) {
#pragma unroll
  for (int i = 0; i < 16; ++i) kh[i] = f32x2{0.0f, 0.0f};
  const f32x2 onev = f32x2{1.0f, 1.0f};
  for (int it = 0; it < KSEL; ++it) {
    f32x2 t0 = pk_add(w[0], w[1]), t1 = pk_add(w[2], w[3]);
    f32x2 t2 = pk_add(w[4], w[5]), t3 = pk_add(w[6], w[7]);
    f32x2 t4 = pk_add(w[8], w[9]), t5 = pk_add(w[10], w[11]);
    f32x2 t6 = pk_add(w[12], w[13]), t7 = pk_add(w[14], w[15]);
    t0 = pk_add(t0, t1); t2 = pk_add(t2, t3);
    t4 = pk_add(t4, t5); t6 = pk_add(t6, t7);
    t0 = pk_add(t0, t2); t4 = pk_add(t4, t6);
    t0 = pk_add(t0, t4);
    float Z0 = wave_sum64_dpp(t0.x);  // independent of Z1 -> interleaved issue
    float Z1 = wave_sum64_dpp(t0.y);
    Z0 = fmaxf(Z0, 1e-30f);
    Z1 = fmaxf(Z1, 1e-30f);
    float r0 = __builtin_amdgcn_rcpf(Z0);
    float r1 = __builtin_amdgcn_rcpf(Z1);
    float rZ0 = __builtin_fmaf(__builtin_fmaf(-Z0, r0, 1.0f), r0, r0);
    float rZ1 = __builtin_fmaf(__builtin_fmaf(-Z1, r1, 1.0f), r1, r1);
    const f32x2 rZ = f32x2{rZ0, rZ1};
    const f32x2 rZn = f32x2{-rZ0, -rZ1};
#pragma unroll
    for (int i = 0; i < 16; ++i) {
      kh[i] = pk_fma(w[i], rZ, kh[i]);
      f32x2 om = pk_fma_clamp(w[i], rZn, onev);  // clamp [0,1]
      w[i] = pk_mul(w[i], om);
    }
  }
}

// Tie path for one row (cold). jax stable tie semantics: all >T, then ==T
// in ascending global index ((lane<<4)|slot).
__device__ unsigned tie_mask16(const f32x2 kh[16], bool comp_y, unsigned T,
                               int lane) {
  unsigned gt = 0, eq = 0;
#pragma unroll
  for (int i = 0; i < 16; ++i) {
    const unsigned u = __float_as_uint(comp_y ? kh[i].y : kh[i].x);
    gt |= (u > T ? 1u : 0u) << i;
    eq |= (u == T ? 1u : 0u) << i;
  }
  const int n_gt = wave_isum64(__popc(gt));
  const int m = 32 - n_gt;  // uniform, >= 1 by search invariant
  const int pe = __popc(eq);
  const int be = wave_iscan64(pe) - pe;
  int need = m - be;
  need = need < 0 ? 0 : (need > pe ? pe : need);
  unsigned tk = 0;
  unsigned em = eq;
  for (int guard = 0; guard < 16; ++guard) {
    if (!__any(need > 0)) break;
    if (need > 0) {
      const int bpos = __ffs(em) - 1;
      tk |= 1u << bpos;
      em &= em - 1;
      --need;
    }
  }
  return gt | tk;
}

// Top-32 for both packed rows: joint binary search on the uint views
// (khot >= 0 -> order-isomorphic), ballot+popcll counting, early exit when
// both rows exact. Invariant (r6/r7, field-validated): tie path always
// completes exactly 32.
__device__ void top32_mask2(const f32x2 kh[16], int lane, unsigned& m0,
                            unsigned& m1) {
  unsigned lo0 = 0, lo1 = 0;
  bool ex0 = false, ex1 = false;
  for (int b = 30; b >= 0; --b) {
    const unsigned c0v = lo0 | (1u << b);
    const unsigned c1v = lo1 | (1u << b);
    int c0 = 0, c1 = 0;
#pragma unroll
    for (int i = 0; i < 16; ++i) {
      c0 += __popcll(__ballot(__float_as_uint(kh[i].x) >= c0v));
      c1 += __popcll(__ballot(__float_as_uint(kh[i].y) >= c1v));
    }
    if (!ex0 && c0 >= 32) { lo0 = c0v; ex0 = (c0 == 32); }
    if (!ex1 && c1 >= 32) { lo1 = c1v; ex1 = (c1 == 32); }
    if (ex0 && ex1) break;
  }

  if (ex0) {
    unsigned mk = 0;
#pragma unroll
    for (int i = 0; i < 16; ++i)
      mk |= (__float_as_uint(kh[i].x) >= lo0 ? 1u : 0u) << i;
    m0 = mk;
  } else {
    m0 = tie_mask16(kh, false, lo0, lane);
  }
  if (ex1) {
    unsigned mk = 0;
#pragma unroll
    for (int i = 0; i < 16; ++i)
      mk |= (__float_as_uint(kh[i].y) >= lo1 ? 1u : 0u) << i;
    m1 = mk;
  } else {
    m1 = tie_mask16(kh, true, lo1, lane);
  }
}

// Compact the 32 selected global indices into dst[0..31], ascending order.
__device__ __forceinline__ void compact_idx(unsigned mask, int lane,
                                            int* __restrict__ dst) {
  const int pe = __popc(mask);
  int base = wave_iscan64(pe) - pe;
  unsigned m = mask;
  while (m) {
    const int s = __ffs(m) - 1;
    m &= m - 1;
    dst[base++] = (lane << 4) | s;
  }
}

__device__ __forceinline__ void write_half(float* __restrict__ dst,
                                           unsigned mask, int lane) {
  float4* o4 = (float4*)dst;
#pragma unroll
  for (int q = 0; q < 4; ++q) {
    float4 o;
    o.x = ((mask >> (4 * q + 0)) & 1) ? 1.0f : 0.0f;
    o.y = ((mask >> (4 * q + 1)) & 1) ? 1.0f : 0.0f;
    o.z = ((mask >> (4 * q + 2)) & 1) ? 1.0f : 0.0f;
    o.w = ((mask >> (4 * q + 3)) & 1) ? 1.0f : 0.0f;
    o4[lane * 4 + q] = o;
  }
}

// ws layout (floats): [0,1024) alpha const logits; [1024,1152) beta base
// dots; [1152,1280) h1a; [1280,1344) h2a.

// ---- precompute, stage 1 (grid 256): the two length-1024 dot layers ----
extern "C" __global__ void pcfs_pre1(const float* __restrict__ ba,
                                     const float* __restrict__ W1a,
                                     const float* __restrict__ b1a,
                                     const float* __restrict__ bb,
                                     const float* __restrict__ W1b,
                                     float* __restrict__ ws) {
  const int b = blockIdx.x;
  const int t = threadIdx.x;
  float acc = 0.0f;
  if (b < 128) {
#pragma unroll
    for (int j = t; j < N_ORB; j += 256) acc += ba[j] * W1a[j * 128 + b];
  } else {
    const int n = b - 128;
#pragma unroll
    for (int j = t; j < N_ORB; j += 256) acc += bb[j] * W1b[j * 128 + n];
  }
  __shared__ float red[4];
  float wsum = wave_sum64_dpp(acc);
  if ((t & 63) == 0) red[t >> 6] = wsum;
  __syncthreads();
  if (t == 0) {
    float tot = red[0] + red[1] + red[2] + red[3];
    if (b < 128)
      ws[1152 + b] = leaky(tot + b1a[b]);
    else
      ws[N_ORB + (b - 128)] = tot;
  }
}

// ---- precompute, stage 2a (1 block x 64): h2 = leaky(h1 @ W2a + b2a) ----
extern "C" __global__ void pcfs_pre2a(const float* __restrict__ W2a,
                                      const float* __restrict__ b2a,
                                      float* __restrict__ ws) {
  const int t = threadIdx.x;  // 64
  float acc = b2a[t];
#pragma unroll 8
  for (int n = 0; n < 128; ++n) acc = __builtin_fmaf(ws[1152 + n], W2a[n * 64 + t], acc);
  ws[1280 + t] = leaky(acc);
}

// ---- precompute, stage 2b (grid 4 x 256): alpha logits = h2 @ W3a + b3a
// + base_a, coalesced row-major W3a reads ----
extern "C" __global__ void pcfs_pre2b(const float* __restrict__ ba,
                                      const float* __restrict__ W3a,
                                      const float* __restrict__ b3a,
                                      float* __restrict__ ws) {
  __shared__ float h2s[64];
  const int t = threadIdx.x;
  const int o = blockIdx.x * 256 + t;
  if (t < 64) h2s[t] = ws[1280 + t];
  __syncthreads();
  float acc = b3a[o] + ba[o];
#pragma unroll 8
  for (int m = 0; m < 64; ++m) acc = __builtin_fmaf(h2s[m], W3a[m * N_ORB + o], acc);
  ws[o] = acc;
}

// One wave per PAIR of batch rows (.x=row0, .y=row1 in every f32x2).
extern "C" __global__ void __launch_bounds__(256, 4) pcfs_sampler(
    const float* __restrict__ ws, const float* __restrict__ Wc,
    const float* __restrict__ bc, const float* __restrict__ W1b,
    const float* __restrict__ b1b, const float* __restrict__ W2b,
    const float* __restrict__ b2b, const float* __restrict__ W3b,
    const float* __restrict__ b3b, const float* __restrict__ bb,
    const float* __restrict__ g_alpha, const float* __restrict__ g_beta,
    float* __restrict__ out, int B) {
  __shared__ int sidx[4][64];  // per-wave: [0..31]=row0 idxs, [32..63]=row1
  const int wave = threadIdx.x >> 6;
  const int lane = threadIdx.x & 63;
  const int pair = blockIdx.x * 4 + wave;
  const int row0 = pair * 2;
  if (row0 >= B) return;
  const bool have1 = (row0 + 1 < B);
  const int row1 = have1 ? row0 + 1 : row0;

  // ---- prefetch g_beta into registers NOW: these HBM loads drain ~10k
  // cycles later (beta exp2 stage), fully hidden behind the alpha phase ----
  float4 gb0[4], gb1[4];
  {
    const float4* g40 = (const float4*)(g_beta + (size_t)row0 * N_ORB);
    const float4* g41 = (const float4*)(g_beta + (size_t)row1 * N_ORB);
#pragma unroll
    for (int q = 0; q < 4; ++q) {
      gb0[q] = g40[lane * 4 + q];
      gb1[q] = g41[lane * 4 + q];
    }
  }

  f32x2 w[16], kh[16];

  // ---- alpha chains: w = exp2((const_logits + gumbel) * log2e), 2 rows ----
  {
    const float4* c4 = (const float4*)ws;
    const float4* g40 = (const float4*)(g_alpha + (size_t)row0 * N_ORB);
    const float4* g41 = (const float4*)(g_alpha + (size_t)row1 * N_ORB);
#pragma unroll
    for (int q = 0; q < 4; ++q) {
      float4 c = c4[lane * 4 + q];
      float4 g0 = g40[lane * 4 + q];
      float4 g1 = g41[lane * 4 + q];
      w[4 * q + 0] = f32x2{__builtin_amdgcn_exp2f((c.x + g0.x) * LOG2E),
                           __builtin_amdgcn_exp2f((c.x + g1.x) * LOG2E)};
      w[4 * q + 1] = f32x2{__builtin_amdgcn_exp2f((c.y + g0.y) * LOG2E),
                           __builtin_amdgcn_exp2f((c.y + g1.y) * LOG2E)};
      w[4 * q + 2] = f32x2{__builtin_amdgcn_exp2f((c.z + g0.z) * LOG2E),
                           __builtin_amdgcn_exp2f((c.z + g1.z) * LOG2E)};
      w[4 * q + 3] = f32x2{__builtin_amdgcn_exp2f((c.w + g0.w) * LOG2E),
                           __builtin_amdgcn_exp2f((c.w + g1.w) * LOG2E)};
    }
  }
  run_chain2(w, kh);
  unsigned am0, am1;
  top32_mask2(kh, lane, am0, am1);

  // write alpha halves (hard config: exact 0/1)
  write_half(out + (size_t)row0 * (2 * N_ORB), am0, lane);
  if (have1) write_half(out + (size_t)row1 * (2 * N_ORB), am1, lane);

  // ---- ctx = alpha_config @ Wc + bc, per row (LDS compact + fixed trip) ----
  compact_idx(am0, lane, &sidx[wave][0]);
  compact_idx(am1, lane, &sidx[wave][32]);
  const int vi0 = sidx[wave][lane & 31];
  const int vi1 = sidx[wave][32 + (lane & 31)];
  const float bcv = bc[lane & 31];
  float ctx0 = bcv, ctx1 = bcv;
#pragma unroll
  for (int r = 0; r < 32; ++r) {
    const int i0 = __builtin_amdgcn_readlane(vi0, r);  // uniform
    const int i1 = __builtin_amdgcn_readlane(vi1, r);
    ctx0 += Wc[i0 * 32 + (lane & 31)];
    ctx1 += Wc[i1 * 32 + (lane & 31)];
  }

  // ---- h1 = leaky(base_b@W1b[0:1024] + ctx@W1b[1024:1056] + b1b) ----
  f32x2 h1a, h1b_;
  {
    const float ia = b1b[lane] + ws[N_ORB + lane];
    const float ib = b1b[lane + 64] + ws[N_ORB + lane + 64];
    h1a = f32x2{ia, ia};
    h1b_ = f32x2{ib, ib};
  }
#pragma unroll 4
  for (int c = 0; c < 32; ++c) {
    const f32x2 cv = f32x2{rdlane(ctx0, c), rdlane(ctx1, c)};
    const float* wr = W1b + (size_t)(N_ORB + c) * 128;
    const float wa = wr[lane], wb = wr[lane + 64];
    h1a = __builtin_elementwise_fma(f32x2{wa, wa}, cv, h1a);
    h1b_ = __builtin_elementwise_fma(f32x2{wb, wb}, cv, h1b_);
  }
  h1a = f32x2{leaky(h1a.x), leaky(h1a.y)};
  h1b_ = f32x2{leaky(h1b_.x), leaky(h1b_.y)};

  // ---- h2 = leaky(h1 @ W2b + b2b): 4 partial accumulators (32-deep
  // chains instead of 128-deep) ----
  f32x2 h2p0, h2p1, h2p2, h2p3;
  {
    const float i2 = b2b[lane];
    h2p0 = f32x2{i2, i2};
    h2p1 = f32x2{0.0f, 0.0f};
    h2p2 = f32x2{0.0f, 0.0f};
    h2p3 = f32x2{0.0f, 0.0f};
  }
#pragma unroll 4
  for (int n = 0; n < 64; n += 4) {
    const f32x2 v0 = f32x2{rdlane(h1a.x, n + 0), rdlane(h1a.y, n + 0)};
    const f32x2 v1 = f32x2{rdlane(h1a.x, n + 1), rdlane(h1a.y, n + 1)};
    const f32x2 v2 = f32x2{rdlane(h1a.x, n + 2), rdlane(h1a.y, n + 2)};
    const f32x2 v3 = f32x2{rdlane(h1a.x, n + 3), rdlane(h1a.y, n + 3)};
    const float w0 = W2b[(n + 0) * 64 + lane];
    const float w1 = W2b[(n + 1) * 64 + lane];
    const float w2 = W2b[(n + 2) * 64 + lane];
    const float w3 = W2b[(n + 3) * 64 + lane];
    h2p0 = __builtin_elementwise_fma(f32x2{w0, w0}, v0, h2p0);
    h2p1 = __builtin_elementwise_fma(f32x2{w1, w1}, v1, h2p1);
    h2p2 = __builtin_elementwise_fma(f32x2{w2, w2}, v2, h2p2);
    h2p3 = __builtin_elementwise_fma(f32x2{w3, w3}, v3, h2p3);
  }
#pragma unroll 4
  for (int n = 0; n < 64; n += 4) {
    const f32x2 v0 = f32x2{rdlane(h1b_.x, n + 0), rdlane(h1b_.y, n + 0)};
    const f32x2 v1 = f32x2{rdlane(h1b_.x, n + 1), rdlane(h1b_.y, n + 1)};
    const f32x2 v2 = f32x2{rdlane(h1b_.x, n + 2), rdlane(h1b_.y, n + 2)};
    const f32x2 v3 = f32x2{rdlane(h1b_.x, n + 3), rdlane(h1b_.y, n + 3)};
    const float w0 = W2b[(n + 64 + 0) * 64 + lane];
    const float w1 = W2b[(n + 64 + 1) * 64 + lane];
    const float w2 = W2b[(n + 64 + 2) * 64 + lane];
    const float w3 = W2b[(n + 64 + 3) * 64 + lane];
    h2p0 = __builtin_elementwise_fma(f32x2{w0, w0}, v0, h2p0);
    h2p1 = __builtin_elementwise_fma(f32x2{w1, w1}, v1, h2p1);
    h2p2 = __builtin_elementwise_fma(f32x2{w2, w2}, v2, h2p2);
    h2p3 = __builtin_elementwise_fma(f32x2{w3, w3}, v3, h2p3);
  }
  f32x2 h2v = (h2p0 + h2p1) + (h2p2 + h2p3);
  h2v = f32x2{leaky(h2v.x), leaky(h2v.y)};

  // ---- beta logits: acc (in w[]) = h2 @ W3b + b3b; shared W3b loads,
  // unrolled x4 so 16 float4 loads pipeline per group ----
  {
    const float4* b4 = (const float4*)b3b;
#pragma unroll
    for (int q = 0; q < 4; ++q) {
      float4 b = b4[lane * 4 + q];
      w[4 * q + 0] = f32x2{b.x, b.x};
      w[4 * q + 1] = f32x2{b.y, b.y};
      w[4 * q + 2] = f32x2{b.z, b.z};
      w[4 * q + 3] = f32x2{b.w, b.w};
    }
  }
#pragma unroll 4
  for (int m = 0; m < 64; ++m) {
    const f32x2 hm = f32x2{rdlane(h2v.x, m), rdlane(h2v.y, m)};
    const float4* w4 = (const float4*)(W3b + m * N_ORB);
#pragma unroll
    for (int q = 0; q < 4; ++q) {
      float4 wv = w4[lane * 4 + q];
      w[4 * q + 0] = __builtin_elementwise_fma(f32x2{wv.x, wv.x}, hm, w[4 * q + 0]);
      w[4 * q + 1] = __builtin_elementwise_fma(f32x2{wv.y, wv.y}, hm, w[4 * q + 1]);
      w[4 * q + 2] = __builtin_elementwise_fma(f32x2{wv.z, wv.z}, hm, w[4 * q + 2]);
      w[4 * q + 3] = __builtin_elementwise_fma(f32x2{wv.w, wv.w}, hm, w[4 * q + 3]);
    }
  }
  // + base_b + gumbel (prefetched) -> w = exp2(logits * log2e)
  {
    const float4* bb4 = (const float4*)bb;
#pragma unroll
    for (int q = 0; q < 4; ++q) {
      float4 b = bb4[lane * 4 + q];
      const float4 g0 = gb0[q];
      const float4 g1 = gb1[q];
      w[4 * q + 0] = f32x2{
          __builtin_amdgcn_exp2f((w[4 * q + 0].x + b.x + g0.x) * LOG2E),
          __builtin_amdgcn_exp2f((w[4 * q + 0].y + b.x + g1.x) * LOG2E)};
      w[4 * q + 1] = f32x2{
          __builtin_amdgcn_exp2f((w[4 * q + 1].x + b.y + g0.y) * LOG2E),
          __builtin_amdgcn_exp2f((w[4 * q + 1].y + b.y + g1.y) * LOG2E)};
      w[4 * q + 2] = f32x2{
          __builtin_amdgcn_exp2f((w[4 * q + 2].x + b.z + g0.z) * LOG2E),
          __builtin_amdgcn_exp2f((w[4 * q + 2].y + b.z + g1.z) * LOG2E)};
      w[4 * q + 3] = f32x2{
          __builtin_amdgcn_exp2f((w[4 * q + 3].x + b.w + g0.w) * LOG2E),
          __builtin_amdgcn_exp2f((w[4 * q + 3].y + b.w + g1.w) * LOG2E)};
    }
  }
  run_chain2(w, kh);
  unsigned bm0, bm1;
  top32_mask2(kh, lane, bm0, bm1);

  write_half(out + (size_t)row0 * (2 * N_ORB) + N_ORB, bm0, lane);
  if (have1) write_half(out + (size_t)row1 * (2 * N_ORB) + N_ORB, bm1, lane);
}

extern "C" void kernel_launch(void* const* d_in, const int* in_sizes, int n_in,
                              void* d_out, int out_size, void* d_ws, size_t ws_size,
                              hipStream_t stream) {
  const float* ba  = (const float*)d_in[0];
  const float* W1a = (const float*)d_in[1];
  const float* b1a = (const float*)d_in[2];
  const float* W2a = (const float*)d_in[3];
  const float* b2a = (const float*)d_in[4];
  const float* W3a = (const float*)d_in[5];
  const float* b3a = (const float*)d_in[6];
  const float* bb  = (const float*)d_in[7];
  const float* Wc  = (const float*)d_in[8];
  const float* bc  = (const float*)d_in[9];
  const float* W1b = (const float*)d_in[10];
  const float* b1b = (const float*)d_in[11];
  const float* W2b = (const float*)d_in[12];
  const float* b2b = (const float*)d_in[13];
  const float* W3b = (const float*)d_in[14];
  const float* b3b = (const float*)d_in[15];
  const float* ga  = (const float*)d_in[16];
  const float* gbt = (const float*)d_in[17];
  const int B = in_sizes[16] / N_ORB;
  float* ws = (float*)d_ws;

  hipLaunchKernelGGL(pcfs_pre1, dim3(256), dim3(256), 0, stream,
                     ba, W1a, b1a, bb, W1b, ws);
  hipLaunchKernelGGL(pcfs_pre2a, dim3(1), dim3(64), 0, stream,
                     W2a, b2a, ws);
  hipLaunchKernelGGL(pcfs_pre2b, dim3(4), dim3(256), 0, stream,
                     ba, W3a, b3a, ws);
  const int pairs = (B + 1) / 2;
  hipLaunchKernelGGL(pcfs_sampler, dim3((pairs + 3) / 4), dim3(256), 0, stream,
                     ws, Wc, bc, W1b, b1b, W2b, b2b, W3b, b3b, bb,
                     ga, gbt, (float*)d_out, B);
}

// Round 7
// 278.307 us; speedup vs baseline: 1.1565x; 1.0011x over previous
//
#include <hip/hip_runtime.h>
#include <hip/hip_bf16.h>
#include <float.h>

#define N_ORB 1024
#define KSEL 32
#define LEAK 0.01f
#define LOG2E 1.4426950408889634f

typedef float f32x2 __attribute__((ext_vector_type(2)));
// NOTE: never write (f32x2)(a, b) — in C++ that's a comma-expr cast that
// SPLATS b. Use f32x2{a, b}.

__device__ __forceinline__ float leaky(float x) { return x >= 0.0f ? x : LEAK * x; }

// ---- packed-FP32 helpers (gfx90a+/gfx950 VOP3P). R6-verified: bit-exact
// (absmax 0) and -3.5k VALU instr/wave vs the scalarized f32x2 chain. ----
__device__ __forceinline__ f32x2 pk_add(f32x2 a, f32x2 b) {
  f32x2 d;
  asm("v_pk_add_f32 %0, %1, %2" : "=v"(d) : "v"(a), "v"(b));
  return d;
}
__device__ __forceinline__ f32x2 pk_mul(f32x2 a, f32x2 b) {
  f32x2 d;
  asm("v_pk_mul_f32 %0, %1, %2" : "=v"(d) : "v"(a), "v"(b));
  return d;
}
__device__ __forceinline__ f32x2 pk_fma(f32x2 a, f32x2 b, f32x2 c) {
  f32x2 d;
  asm("v_pk_fma_f32 %0, %1, %2, %3" : "=v"(d) : "v"(a), "v"(b), "v"(c));
  return d;
}
// VOP3P clamp bit == clamp result to [0,1] per half — exactly the verified
// min(max(om,0),1) semantics, in one instruction.
__device__ __forceinline__ f32x2 pk_fma_clamp(f32x2 a, f32x2 b, f32x2 c) {
  f32x2 d;
  asm("v_pk_fma_f32 %0, %1, %2, %3 clamp" : "=v"(d) : "v"(a), "v"(b), "v"(c));
  return d;
}

// ---- DPP helpers ----
template <int CTRL, int RM>
__device__ __forceinline__ int dpp0_i(int v) {  // masked-off rows contribute 0
  return __builtin_amdgcn_update_dpp(0, v, CTRL, RM, 0xF, true);
}
template <int CTRL>
__device__ __forceinline__ float dpp_zero(float v) {
  return __int_as_float(
      __builtin_amdgcn_update_dpp(0, __float_as_int(v), CTRL, 0xF, 0xF, true));
}
__device__ __forceinline__ float rdlane(float v, int l) {
  return __int_as_float(__builtin_amdgcn_readlane(__float_as_int(v), l));
}

// full 64-lane float sum, uniform result
__device__ __forceinline__ float wave_sum64_dpp(float v) {
  v += dpp_zero<0x111>(v);
  v += dpp_zero<0x112>(v);
  v += dpp_zero<0x114>(v);
  v += dpp_zero<0x118>(v);
  v += dpp_zero<0x142>(v);
  v += dpp_zero<0x143>(v);
  return rdlane(v, 63);
}
// full 64-lane int sum, uniform result
__device__ __forceinline__ int wave_isum64(int v) {
  v += dpp0_i<0x111, 0xF>(v);
  v += dpp0_i<0x112, 0xF>(v);
  v += dpp0_i<0x114, 0xF>(v);
  v += dpp0_i<0x118, 0xF>(v);
  v += dpp0_i<0x142, 0xF>(v);
  v += dpp0_i<0x143, 0xF>(v);
  return __builtin_amdgcn_readlane(v, 63);
}
// 64-lane inclusive prefix sum (int), per-lane result
__device__ __forceinline__ int wave_iscan64(int v) {
  v += dpp0_i<0x111, 0xF>(v);
  v += dpp0_i<0x112, 0xF>(v);
  v += dpp0_i<0x114, 0xF>(v);
  v += dpp0_i<0x118, 0xF>(v);
  v += dpp0_i<0x142, 0xA>(v);
  v += dpp0_i<0x143, 0xC>(v);
  return v;
}

// Successive-softmax chain for TWO rows packed in f32x2 (.x=row0,.y=row1),
// multiplicative form (w tracks exp(s)). Element j of a row = lane*16 + j.
// pk_fma_clamp == ref's 1e-20 floor at fp32 (khot deltas <= 1e-20, far below
// any top-32 boundary). fma(w, -rZ, 1) == fma(-w, rZ, 1) exactly (product is
// exact inside fma), so building rZn once per iteration is bit-identical.
__device__ void run_chain2(f32x2 w[16], f32x2 kh[16]) {
#pragma unroll
  for (int i = 0; i < 16; ++i) kh[i] = f32x2{0.0f, 0.0f};
  const f32x2 onev = f32x2{1.0f, 1.0f};
  for (int it = 0; it < KSEL; ++it) {
    f32x2 t0 = pk_add(w[0], w[1]), t1 = pk_add(w[2], w[3]);
    f32x2 t2 = pk_add(w[4], w[5]), t3 = pk_add(w[6], w[7]);
    f32x2 t4 = pk_add(w[8], w[9]), t5 = pk_add(w[10], w[11]);
    f32x2 t6 = pk_add(w[12], w[13]), t7 = pk_add(w[14], w[15]);
    t0 = pk_add(t0, t1); t2 = pk_add(t2, t3);
    t4 = pk_add(t4, t5); t6 = pk_add(t6, t7);
    t0 = pk_add(t0, t2); t4 = pk_add(t4, t6);
    t0 = pk_add(t0, t4);
    float Z0 = wave_sum64_dpp(t0.x);  // independent of Z1 -> interleaved issue
    float Z1 = wave_sum64_dpp(t0.y);
    Z0 = fmaxf(Z0, 1e-30f);
    Z1 = fmaxf(Z1, 1e-30f);
    float r0 = __builtin_amdgcn_rcpf(Z0);
    float r1 = __builtin_amdgcn_rcpf(Z1);
    float rZ0 = __builtin_fmaf(__builtin_fmaf(-Z0, r0, 1.0f), r0, r0);
    float rZ1 = __builtin_fmaf(__builtin_fmaf(-Z1, r1, 1.0f), r1, r1);
    const f32x2 rZ = f32x2{rZ0, rZ1};
    const f32x2 rZn = f32x2{-rZ0, -rZ1};
#pragma unroll
    for (int i = 0; i < 16; ++i) {
      kh[i] = pk_fma(w[i], rZ, kh[i]);
      f32x2 om = pk_fma_clamp(w[i], rZn, onev);  // clamp [0,1]
      w[i] = pk_mul(w[i], om);
    }
  }
}

// Tie path for one row (cold). jax stable tie semantics: all >T, then ==T
// in ascending global index ((lane<<4)|slot).
__device__ unsigned tie_mask16(const f32x2 kh[16], bool comp_y, unsigned T,
                               int lane) {
  unsigned gt = 0, eq = 0;
#pragma unroll
  for (int i = 0; i < 16; ++i) {
    const unsigned u = __float_as_uint(comp_y ? kh[i].y : kh[i].x);
    gt |= (u > T ? 1u : 0u) << i;
    eq |= (u == T ? 1u : 0u) << i;
  }
  const int n_gt = wave_isum64(__popc(gt));
  const int m = 32 - n_gt;  // uniform, >= 1 by search invariant
  const int pe = __popc(eq);
  const int be = wave_iscan64(pe) - pe;
  int need = m - be;
  need = need < 0 ? 0 : (need > pe ? pe : need);
  unsigned tk = 0;
  unsigned em = eq;
  for (int guard = 0; guard < 16; ++guard) {
    if (!__any(need > 0)) break;
    if (need > 0) {
      const int bpos = __ffs(em) - 1;
      tk |= 1u << bpos;
      em &= em - 1;
      --need;
    }
  }
  return gt | tk;
}

// Top-32 for both packed rows: joint binary search on the uint views
// (khot >= 0 -> order-isomorphic), ballot+popcll counting, early exit when
// both rows exact. Invariant (r6/r7, field-validated): tie path always
// completes exactly 32.
__device__ void top32_mask2(const f32x2 kh[16], int lane, unsigned& m0,
                            unsigned& m1) {
  unsigned lo0 = 0, lo1 = 0;
  bool ex0 = false, ex1 = false;
  for (int b = 30; b >= 0; --b) {
    const unsigned c0v = lo0 | (1u << b);
    const unsigned c1v = lo1 | (1u << b);
    int c0 = 0, c1 = 0;
#pragma unroll
    for (int i = 0; i < 16; ++i) {
      c0 += __popcll(__ballot(__float_as_uint(kh[i].x) >= c0v));
      c1 += __popcll(__ballot(__float_as_uint(kh[i].y) >= c1v));
    }
    if (!ex0 && c0 >= 32) { lo0 = c0v; ex0 = (c0 == 32); }
    if (!ex1 && c1 >= 32) { lo1 = c1v; ex1 = (c1 == 32); }
    if (ex0 && ex1) break;
  }

  if (ex0) {
    unsigned mk = 0;
#pragma unroll
    for (int i = 0; i < 16; ++i)
      mk |= (__float_as_uint(kh[i].x) >= lo0 ? 1u : 0u) << i;
    m0 = mk;
  } else {
    m0 = tie_mask16(kh, false, lo0, lane);
  }
  if (ex1) {
    unsigned mk = 0;
#pragma unroll
    for (int i = 0; i < 16; ++i)
      mk |= (__float_as_uint(kh[i].y) >= lo1 ? 1u : 0u) << i;
    m1 = mk;
  } else {
    m1 = tie_mask16(kh, true, lo1, lane);
  }
}

// Compact the 32 selected global indices into dst[0..31], ascending order.
__device__ __forceinline__ void compact_idx(unsigned mask, int lane,
                                            int* __restrict__ dst) {
  const int pe = __popc(mask);
  int base = wave_iscan64(pe) - pe;
  unsigned m = mask;
  while (m) {
    const int s = __ffs(m) - 1;
    m &= m - 1;
    dst[base++] = (lane << 4) | s;
  }
}

__device__ __forceinline__ void write_half(float* __restrict__ dst,
                                           unsigned mask, int lane) {
  float4* o4 = (float4*)dst;
#pragma unroll
  for (int q = 0; q < 4; ++q) {
    float4 o;
    o.x = ((mask >> (4 * q + 0)) & 1) ? 1.0f : 0.0f;
    o.y = ((mask >> (4 * q + 1)) & 1) ? 1.0f : 0.0f;
    o.z = ((mask >> (4 * q + 2)) & 1) ? 1.0f : 0.0f;
    o.w = ((mask >> (4 * q + 3)) & 1) ? 1.0f : 0.0f;
    o4[lane * 4 + q] = o;
  }
}

// ws layout (floats): [0,1024) alpha const logits; [1024,1152) beta base
// dots; [1152,1280) h1a; [1280,1344) h2a.

// ---- precompute, stage 1 (grid 256): the two length-1024 dot layers ----
extern "C" __global__ void pcfs_pre1(const float* __restrict__ ba,
                                     const float* __restrict__ W1a,
                                     const float* __restrict__ b1a,
                                     const float* __restrict__ bb,
                                     const float* __restrict__ W1b,
                                     float* __restrict__ ws) {
  const int b = blockIdx.x;
  const int t = threadIdx.x;
  float acc = 0.0f;
  if (b < 128) {
#pragma unroll
    for (int j = t; j < N_ORB; j += 256) acc += ba[j] * W1a[j * 128 + b];
  } else {
    const int n = b - 128;
#pragma unroll
    for (int j = t; j < N_ORB; j += 256) acc += bb[j] * W1b[j * 128 + n];
  }
  __shared__ float red[4];
  float wsum = wave_sum64_dpp(acc);
  if ((t & 63) == 0) red[t >> 6] = wsum;
  __syncthreads();
  if (t == 0) {
    float tot = red[0] + red[1] + red[2] + red[3];
    if (b < 128)
      ws[1152 + b] = leaky(tot + b1a[b]);
    else
      ws[N_ORB + (b - 128)] = tot;
  }
}

// ---- precompute, stage 2a (1 block x 64): h2 = leaky(h1 @ W2a + b2a) ----
extern "C" __global__ void pcfs_pre2a(const float* __restrict__ W2a,
                                      const float* __restrict__ b2a,
                                      float* __restrict__ ws) {
  const int t = threadIdx.x;  // 64
  float acc = b2a[t];
#pragma unroll 8
  for (int n = 0; n < 128; ++n) acc = __builtin_fmaf(ws[1152 + n], W2a[n * 64 + t], acc);
  ws[1280 + t] = leaky(acc);
}

// ---- precompute, stage 2b (grid 4 x 256): alpha logits = h2 @ W3a + b3a
// + base_a, coalesced row-major W3a reads ----
extern "C" __global__ void pcfs_pre2b(const float* __restrict__ ba,
                                      const float* __restrict__ W3a,
                                      const float* __restrict__ b3a,
                                      float* __restrict__ ws) {
  __shared__ float h2s[64];
  const int t = threadIdx.x;
  const int o = blockIdx.x * 256 + t;
  if (t < 64) h2s[t] = ws[1280 + t];
  __syncthreads();
  float acc = b3a[o] + ba[o];
#pragma unroll 8
  for (int m = 0; m < 64; ++m) acc = __builtin_fmaf(h2s[m], W3a[m * N_ORB + o], acc);
  ws[o] = acc;
}

// One wave per PAIR of batch rows (.x=row0, .y=row1 in every f32x2).
extern "C" __global__ void __launch_bounds__(256, 4) pcfs_sampler(
    const float* __restrict__ ws, const float* __restrict__ Wc,
    const float* __restrict__ bc, const float* __restrict__ W1b,
    const float* __restrict__ b1b, const float* __restrict__ W2b,
    const float* __restrict__ b2b, const float* __restrict__ W3b,
    const float* __restrict__ b3b, const float* __restrict__ bb,
    const float* __restrict__ g_alpha, const float* __restrict__ g_beta,
    float* __restrict__ out, int B) {
  __shared__ int sidx[4][64];  // per-wave: [0..31]=row0 idxs, [32..63]=row1
  const int wave = threadIdx.x >> 6;
  const int lane = threadIdx.x & 63;
  const int pair = blockIdx.x * 4 + wave;
  const int row0 = pair * 2;
  if (row0 >= B) return;
  const bool have1 = (row0 + 1 < B);
  const int row1 = have1 ? row0 + 1 : row0;

  // ---- de-phase the 16 waves/CU (R6 theory: phase-locked stalls ->
  // VALUBusy 50% despite 4 waves/SIMD; independent phases would give ~94%).
  // sid in 0..15, 64 cy per s_sleep unit -> 0..960 cy spread, ~2-6 chain
  // iterations. Pure delay: zero correctness impact, <=1 us ramp cost. ----
  {
    const int sid = wave + ((blockIdx.x & 3) << 2);  // wave-uniform
    for (int k = 0; k < sid; ++k) __builtin_amdgcn_s_sleep(1);
  }

  // ---- prefetch g_beta into registers NOW: these HBM loads drain ~10k
  // cycles later (beta exp2 stage), fully hidden behind the alpha phase ----
  float4 gb0[4], gb1[4];
  {
    const float4* g40 = (const float4*)(g_beta + (size_t)row0 * N_ORB);
    const float4* g41 = (const float4*)(g_beta + (size_t)row1 * N_ORB);
#pragma unroll
    for (int q = 0; q < 4; ++q) {
      gb0[q] = g40[lane * 4 + q];
      gb1[q] = g41[lane * 4 + q];
    }
  }

  f32x2 w[16], kh[16];

  // ---- alpha chains: w = exp2((const_logits + gumbel) * log2e), 2 rows ----
  {
    const float4* c4 = (const float4*)ws;
    const float4* g40 = (const float4*)(g_alpha + (size_t)row0 * N_ORB);
    const float4* g41 = (const float4*)(g_alpha + (size_t)row1 * N_ORB);
#pragma unroll
    for (int q = 0; q < 4; ++q) {
      float4 c = c4[lane * 4 + q];
      float4 g0 = g40[lane * 4 + q];
      float4 g1 = g41[lane * 4 + q];
      w[4 * q + 0] = f32x2{__builtin_amdgcn_exp2f((c.x + g0.x) * LOG2E),
                           __builtin_amdgcn_exp2f((c.x + g1.x) * LOG2E)};
      w[4 * q + 1] = f32x2{__builtin_amdgcn_exp2f((c.y + g0.y) * LOG2E),
                           __builtin_amdgcn_exp2f((c.y + g1.y) * LOG2E)};
      w[4 * q + 2] = f32x2{__builtin_amdgcn_exp2f((c.z + g0.z) * LOG2E),
                           __builtin_amdgcn_exp2f((c.z + g1.z) * LOG2E)};
      w[4 * q + 3] = f32x2{__builtin_amdgcn_exp2f((c.w + g0.w) * LOG2E),
                           __builtin_amdgcn_exp2f((c.w + g1.w) * LOG2E)};
    }
  }
  run_chain2(w, kh);
  unsigned am0, am1;
  top32_mask2(kh, lane, am0, am1);

  // write alpha halves (hard config: exact 0/1)
  write_half(out + (size_t)row0 * (2 * N_ORB), am0, lane);
  if (have1) write_half(out + (size_t)row1 * (2 * N_ORB), am1, lane);

  // ---- ctx = alpha_config @ Wc + bc, per row (LDS compact + fixed trip) ----
  compact_idx(am0, lane, &sidx[wave][0]);
  compact_idx(am1, lane, &sidx[wave][32]);
  const int vi0 = sidx[wave][lane & 31];
  const int vi1 = sidx[wave][32 + (lane & 31)];
  const float bcv = bc[lane & 31];
  float ctx0 = bcv, ctx1 = bcv;
#pragma unroll
  for (int r = 0; r < 32; ++r) {
    const int i0 = __builtin_amdgcn_readlane(vi0, r);  // uniform
    const int i1 = __builtin_amdgcn_readlane(vi1, r);
    ctx0 += Wc[i0 * 32 + (lane & 31)];
    ctx1 += Wc[i1 * 32 + (lane & 31)];
  }

  // ---- h1 = leaky(base_b@W1b[0:1024] + ctx@W1b[1024:1056] + b1b) ----
  f32x2 h1a, h1b_;
  {
    const float ia = b1b[lane] + ws[N_ORB + lane];
    const float ib = b1b[lane + 64] + ws[N_ORB + lane + 64];
    h1a = f32x2{ia, ia};
    h1b_ = f32x2{ib, ib};
  }
#pragma unroll 4
  for (int c = 0; c < 32; ++c) {
    const f32x2 cv = f32x2{rdlane(ctx0, c), rdlane(ctx1, c)};
    const float* wr = W1b + (size_t)(N_ORB + c) * 128;
    const float wa = wr[lane], wb = wr[lane + 64];
    h1a = __builtin_elementwise_fma(f32x2{wa, wa}, cv, h1a);
    h1b_ = __builtin_elementwise_fma(f32x2{wb, wb}, cv, h1b_);
  }
  h1a = f32x2{leaky(h1a.x), leaky(h1a.y)};
  h1b_ = f32x2{leaky(h1b_.x), leaky(h1b_.y)};

  // ---- h2 = leaky(h1 @ W2b + b2b): 4 partial accumulators (32-deep
  // chains instead of 128-deep) ----
  f32x2 h2p0, h2p1, h2p2, h2p3;
  {
    const float i2 = b2b[lane];
    h2p0 = f32x2{i2, i2};
    h2p1 = f32x2{0.0f, 0.0f};
    h2p2 = f32x2{0.0f, 0.0f};
    h2p3 = f32x2{0.0f, 0.0f};
  }
#pragma unroll 4
  for (int n = 0; n < 64; n += 4) {
    const f32x2 v0 = f32x2{rdlane(h1a.x, n + 0), rdlane(h1a.y, n + 0)};
    const f32x2 v1 = f32x2{rdlane(h1a.x, n + 1), rdlane(h1a.y, n + 1)};
    const f32x2 v2 = f32x2{rdlane(h1a.x, n + 2), rdlane(h1a.y, n + 2)};
    const f32x2 v3 = f32x2{rdlane(h1a.x, n + 3), rdlane(h1a.y, n + 3)};
    const float w0 = W2b[(n + 0) * 64 + lane];
    const float w1 = W2b[(n + 1) * 64 + lane];
    const float w2 = W2b[(n + 2) * 64 + lane];
    const float w3 = W2b[(n + 3) * 64 + lane];
    h2p0 = __builtin_elementwise_fma(f32x2{w0, w0}, v0, h2p0);
    h2p1 = __builtin_elementwise_fma(f32x2{w1, w1}, v1, h2p1);
    h2p2 = __builtin_elementwise_fma(f32x2{w2, w2}, v2, h2p2);
    h2p3 = __builtin_elementwise_fma(f32x2{w3, w3}, v3, h2p3);
  }
#pragma unroll 4
  for (int n = 0; n < 64; n += 4) {
    const f32x2 v0 = f32x2{rdlane(h1b_.x, n + 0), rdlane(h1b_.y, n + 0)};
    const f32x2 v1 = f32x2{rdlane(h1b_.x, n + 1), rdlane(h1b_.y, n + 1)};
    const f32x2 v2 = f32x2{rdlane(h1b_.x, n + 2), rdlane(h1b_.y, n + 2)};
    const f32x2 v3 = f32x2{rdlane(h1b_.x, n + 3), rdlane(h1b_.y, n + 3)};
    const float w0 = W2b[(n + 64 + 0) * 64 + lane];
    const float w1 = W2b[(n + 64 + 1) * 64 + lane];
    const float w2 = W2b[(n + 64 + 2) * 64 + lane];
    const float w3 = W2b[(n + 64 + 3) * 64 + lane];
    h2p0 = __builtin_elementwise_fma(f32x2{w0, w0}, v0, h2p0);
    h2p1 = __builtin_elementwise_fma(f32x2{w1, w1}, v1, h2p1);
    h2p2 = __builtin_elementwise_fma(f32x2{w2, w2}, v2, h2p2);
    h2p3 = __builtin_elementwise_fma(f32x2{w3, w3}, v3, h2p3);
  }
  f32x2 h2v = (h2p0 + h2p1) + (h2p2 + h2p3);
  h2v = f32x2{leaky(h2v.x), leaky(h2v.y)};

  // ---- beta logits: acc (in w[]) = h2 @ W3b + b3b; shared W3b loads,
  // unrolled x4 so 16 float4 loads pipeline per group ----
  {
    const float4* b4 = (const float4*)b3b;
#pragma unroll
    for (int q = 0; q < 4; ++q) {
      float4 b = b4[lane * 4 + q];
      w[4 * q + 0] = f32x2{b.x, b.x};
      w[4 * q + 1] = f32x2{b.y, b.y};
      w[4 * q + 2] = f32x2{b.z, b.z};
      w[4 * q + 3] = f32x2{b.w, b.w};
    }
  }
#pragma unroll 4
  for (int m = 0; m < 64; ++m) {
    const f32x2 hm = f32x2{rdlane(h2v.x, m), rdlane(h2v.y, m)};
    const float4* w4 = (const float4*)(W3b + m * N_ORB);
#pragma unroll
    for (int q = 0; q < 4; ++q) {
      float4 wv = w4[lane * 4 + q];
      w[4 * q + 0] = __builtin_elementwise_fma(f32x2{wv.x, wv.x}, hm, w[4 * q + 0]);
      w[4 * q + 1] = __builtin_elementwise_fma(f32x2{wv.y, wv.y}, hm, w[4 * q + 1]);
      w[4 * q + 2] = __builtin_elementwise_fma(f32x2{wv.z, wv.z}, hm, w[4 * q + 2]);
      w[4 * q + 3] = __builtin_elementwise_fma(f32x2{wv.w, wv.w}, hm, w[4 * q + 3]);
    }
  }
  // + base_b + gumbel (prefetched) -> w = exp2(logits * log2e)
  {
    const float4* bb4 = (const float4*)bb;
#pragma unroll
    for (int q = 0; q < 4; ++q) {
      float4 b = bb4[lane * 4 + q];
      const float4 g0 = gb0[q];
      const float4 g1 = gb1[q];
      w[4 * q + 0] = f32x2{
          __builtin_amdgcn_exp2f((w[4 * q + 0].x + b.x + g0.x) * LOG2E),
          __builtin_amdgcn_exp2f((w[4 * q + 0].y + b.x + g1.x) * LOG2E)};
      w[4 * q + 1] = f32x2{
          __builtin_amdgcn_exp2f((w[4 * q + 1].x + b.y + g0.y) * LOG2E),
          __builtin_amdgcn_exp2f((w[4 * q + 1].y + b.y + g1.y) * LOG2E)};
      w[4 * q + 2] = f32x2{
          __builtin_amdgcn_exp2f((w[4 * q + 2].x + b.z + g0.z) * LOG2E),
          __builtin_amdgcn_exp2f((w[4 * q + 2].y + b.z + g1.z) * LOG2E)};
      w[4 * q + 3] = f32x2{
          __builtin_amdgcn_exp2f((w[4 * q + 3].x + b.w + g0.w) * LOG2E),
          __builtin_amdgcn_exp2f((w[4 * q + 3].y + b.w + g1.w) * LOG2E)};
    }
  }
  run_chain2(w, kh);
  unsigned bm0, bm1;
  top32_mask2(kh, lane, bm0, bm1);

  write_half(out + (size_t)row0 * (2 * N_ORB) + N_ORB, bm0, lane);
  if (have1) write_half(out + (size_t)row1 * (2 * N_ORB) + N_ORB, bm1, lane);
}

extern "C" void kernel_launch(void* const* d_in, const int* in_sizes, int n_in,
                              void* d_out, int out_size, void* d_ws, size_t ws_size,
                              hipStream_t stream) {
  const float* ba  = (const float*)d_in[0];
  const float* W1a = (const float*)d_in[1];
  const float* b1a = (const float*)d_in[2];
  const float* W2a = (const float*)d_in[3];
  const float* b2a = (const float*)d_in[4];
  const float* W3a = (const float*)d_in[5];
  const float* b3a = (const float*)d_in[6];
  const float* bb  = (const float*)d_in[7];
  const float* Wc  = (const float*)d_in[8];
  const float* bc  = (const float*)d_in[9];
  const float* W1b = (const float*)d_in[10];
  const float* b1b = (const float*)d_in[11];
  const float* W2b = (const float*)d_in[12];
  const float* b2b = (const float*)d_in[13];
  const float* W3b = (const float*)d_in[14];
  const float* b3b = (const float*)d_in[15];
  const float* ga  = (const float*)d_in[16];
  const float* gbt = (const float*)d_in[17];
  const int B = in_sizes[16] / N_ORB;
  float* ws = (float*)d_ws;

  hipLaunchKernelGGL(pcfs_pre1, dim3(256), dim3(256), 0, stream,
                     ba, W1a, b1a, bb, W1b, ws);
  hipLaunchKernelGGL(pcfs_pre2a, dim3(1), dim3(64), 0, stream,
                     W2a, b2a, ws);
  hipLaunchKernelGGL(pcfs_pre2b, dim3(4), dim3(256), 0, stream,
                     ba, W3a, b3a, ws);
  const int pairs = (B + 1) / 2;
  hipLaunchKernelGGL(pcfs_sampler, dim3((pairs + 3) / 4), dim3(256), 0, stream,
                     ws, Wc, bc, W1b, b1b, W2b, b2b, W3b, b3b, bb,
                     ga, gbt, (float*)d_out, B);
}

// Round 8
// 268.838 us; speedup vs baseline: 1.1972x; 1.0352x over previous
//
#include <hip/hip_runtime.h>
#include <hip/hip_bf16.h>
#include <float.h>

#define N_ORB 1024
#define KSEL 32
#define LEAK 0.01f
#define LOG2E 1.4426950408889634f

typedef float f32x2 __attribute__((ext_vector_type(2)));
// NOTE: never write (f32x2)(a, b) — in C++ that's a comma-expr cast that
// SPLATS b. Use f32x2{a, b}.

__device__ __forceinline__ float leaky(float x) { return x >= 0.0f ? x : LEAK * x; }

// ---- packed-FP32 helpers (gfx90a+/gfx950 VOP3P, full-rate packed fp32).
// R6-verified: bit-exact (absmax 0), -3.5k VALU instr/wave, -20 us. ----
__device__ __forceinline__ f32x2 pk_add(f32x2 a, f32x2 b) {
  f32x2 d;
  asm("v_pk_add_f32 %0, %1, %2" : "=v"(d) : "v"(a), "v"(b));
  return d;
}
__device__ __forceinline__ f32x2 pk_mul(f32x2 a, f32x2 b) {
  f32x2 d;
  asm("v_pk_mul_f32 %0, %1, %2" : "=v"(d) : "v"(a), "v"(b));
  return d;
}
__device__ __forceinline__ f32x2 pk_fma(f32x2 a, f32x2 b, f32x2 c) {
  f32x2 d;
  asm("v_pk_fma_f32 %0, %1, %2, %3" : "=v"(d) : "v"(a), "v"(b), "v"(c));
  return d;
}
// VOP3P clamp bit == clamp result to [0,1] per half — exactly the verified
// min(max(om,0),1) semantics, in one instruction.
__device__ __forceinline__ f32x2 pk_fma_clamp(f32x2 a, f32x2 b, f32x2 c) {
  f32x2 d;
  asm("v_pk_fma_f32 %0, %1, %2, %3 clamp" : "=v"(d) : "v"(a), "v"(b), "v"(c));
  return d;
}

// ---- DPP helpers ----
template <int CTRL, int RM>
__device__ __forceinline__ int dpp0_i(int v) {  // masked-off rows contribute 0
  return __builtin_amdgcn_update_dpp(0, v, CTRL, RM, 0xF, true);
}
template <int CTRL>
__device__ __forceinline__ float dpp_zero(float v) {
  return __int_as_float(
      __builtin_amdgcn_update_dpp(0, __float_as_int(v), CTRL, 0xF, 0xF, true));
}
__device__ __forceinline__ float rdlane(float v, int l) {
  return __int_as_float(__builtin_amdgcn_readlane(__float_as_int(v), l));
}

// full 64-lane float sum, uniform result
__device__ __forceinline__ float wave_sum64_dpp(float v) {
  v += dpp_zero<0x111>(v);
  v += dpp_zero<0x112>(v);
  v += dpp_zero<0x114>(v);
  v += dpp_zero<0x118>(v);
  v += dpp_zero<0x142>(v);
  v += dpp_zero<0x143>(v);
  return rdlane(v, 63);
}
// full 64-lane int sum, uniform result
__device__ __forceinline__ int wave_isum64(int v) {
  v += dpp0_i<0x111, 0xF>(v);
  v += dpp0_i<0x112, 0xF>(v);
  v += dpp0_i<0x114, 0xF>(v);
  v += dpp0_i<0x118, 0xF>(v);
  v += dpp0_i<0x142, 0xF>(v);
  v += dpp0_i<0x143, 0xF>(v);
  return __builtin_amdgcn_readlane(v, 63);
}
// 64-lane inclusive prefix sum (int), per-lane result
__device__ __forceinline__ int wave_iscan64(int v) {
  v += dpp0_i<0x111, 0xF>(v);
  v += dpp0_i<0x112, 0xF>(v);
  v += dpp0_i<0x114, 0xF>(v);
  v += dpp0_i<0x118, 0xF>(v);
  v += dpp0_i<0x142, 0xA>(v);
  v += dpp0_i<0x143, 0xC>(v);
  return v;
}

// Successive-softmax chain for TWO rows packed in f32x2 (.x=row0,.y=row1),
// multiplicative form (w tracks exp(s)). Element j of a row = lane*16 + j.
// pk_fma_clamp == ref's 1e-20 floor at fp32 (khot deltas <= 1e-20, far below
// any top-32 boundary). fma(w, -rZ, 1) == fma(-w, rZ, 1) exactly (product is
// exact inside fma), so building rZn once per iteration is bit-identical.
__device__ void run_chain2(f32x2 w[16], f32x2 kh[16]) {
#pragma unroll
  for (int i = 0; i < 16; ++i) kh[i] = f32x2{0.0f, 0.0f};
  const f32x2 onev = f32x2{1.0f, 1.0f};
  for (int it = 0; it < KSEL; ++it) {
    f32x2 t0 = pk_add(w[0], w[1]), t1 = pk_add(w[2], w[3]);
    f32x2 t2 = pk_add(w[4], w[5]), t3 = pk_add(w[6], w[7]);
    f32x2 t4 = pk_add(w[8], w[9]), t5 = pk_add(w[10], w[11]);
    f32x2 t6 = pk_add(w[12], w[13]), t7 = pk_add(w[14], w[15]);
    t0 = pk_add(t0, t1); t2 = pk_add(t2, t3);
    t4 = pk_add(t4, t5); t6 = pk_add(t6, t7);
    t0 = pk_add(t0, t2); t4 = pk_add(t4, t6);
    t0 = pk_add(t0, t4);
    float Z0 = wave_sum64_dpp(t0.x);  // independent of Z1 -> interleaved issue
    float Z1 = wave_sum64_dpp(t0.y);
    Z0 = fmaxf(Z0, 1e-30f);
    Z1 = fmaxf(Z1, 1e-30f);
    float r0 = __builtin_amdgcn_rcpf(Z0);
    float r1 = __builtin_amdgcn_rcpf(Z1);
    float rZ0 = __builtin_fmaf(__builtin_fmaf(-Z0, r0, 1.0f), r0, r0);
    float rZ1 = __builtin_fmaf(__builtin_fmaf(-Z1, r1, 1.0f), r1, r1);
    const f32x2 rZ = f32x2{rZ0, rZ1};
    const f32x2 rZn = f32x2{-rZ0, -rZ1};
#pragma unroll
    for (int i = 0; i < 16; ++i) {
      kh[i] = pk_fma(w[i], rZ, kh[i]);
      f32x2 om = pk_fma_clamp(w[i], rZn, onev);  // clamp [0,1]
      w[i] = pk_mul(w[i], om);
    }
  }
}

// Tie path for one row (cold). jax stable tie semantics: all >T, then ==T
// in ascending global index ((lane<<4)|slot).
__device__ unsigned tie_mask16(const f32x2 kh[16], bool comp_y, unsigned T,
                               int lane) {
  unsigned gt = 0, eq = 0;
#pragma unroll
  for (int i = 0; i < 16; ++i) {
    const unsigned u = __float_as_uint(comp_y ? kh[i].y : kh[i].x);
    gt |= (u > T ? 1u : 0u) << i;
    eq |= (u == T ? 1u : 0u) << i;
  }
  const int n_gt = wave_isum64(__popc(gt));
  const int m = 32 - n_gt;  // uniform, >= 1 by search invariant
  const int pe = __popc(eq);
  const int be = wave_iscan64(pe) - pe;
  int need = m - be;
  need = need < 0 ? 0 : (need > pe ? pe : need);
  unsigned tk = 0;
  unsigned em = eq;
  for (int guard = 0; guard < 16; ++guard) {
    if (!__any(need > 0)) break;
    if (need > 0) {
      const int bpos = __ffs(em) - 1;
      tk |= 1u << bpos;
      em &= em - 1;
      --need;
    }
  }
  return gt | tk;
}

// Top-32 for both packed rows: joint binary search on the uint views
// (khot >= 0 -> order-isomorphic), ballot+popcll counting, early exit when
// both rows exact. Invariant (r6/r7, field-validated): tie path always
// completes exactly 32.
__device__ void top32_mask2(const f32x2 kh[16], int lane, unsigned& m0,
                            unsigned& m1) {
  unsigned lo0 = 0, lo1 = 0;
  bool ex0 = false, ex1 = false;
  for (int b = 30; b >= 0; --b) {
    const unsigned c0v = lo0 | (1u << b);
    const unsigned c1v = lo1 | (1u << b);
    int c0 = 0, c1 = 0;
#pragma unroll
    for (int i = 0; i < 16; ++i) {
      c0 += __popcll(__ballot(__float_as_uint(kh[i].x) >= c0v));
      c1 += __popcll(__ballot(__float_as_uint(kh[i].y) >= c1v));
    }
    if (!ex0 && c0 >= 32) { lo0 = c0v; ex0 = (c0 == 32); }
    if (!ex1 && c1 >= 32) { lo1 = c1v; ex1 = (c1 == 32); }
    if (ex0 && ex1) break;
  }

  if (ex0) {
    unsigned mk = 0;
#pragma unroll
    for (int i = 0; i < 16; ++i)
      mk |= (__float_as_uint(kh[i].x) >= lo0 ? 1u : 0u) << i;
    m0 = mk;
  } else {
    m0 = tie_mask16(kh, false, lo0, lane);
  }
  if (ex1) {
    unsigned mk = 0;
#pragma unroll
    for (int i = 0; i < 16; ++i)
      mk |= (__float_as_uint(kh[i].y) >= lo1 ? 1u : 0u) << i;
    m1 = mk;
  } else {
    m1 = tie_mask16(kh, true, lo1, lane);
  }
}

// Compact the 32 selected global indices into dst[0..31], ascending order.
__device__ __forceinline__ void compact_idx(unsigned mask, int lane,
                                            int* __restrict__ dst) {
  const int pe = __popc(mask);
  int base = wave_iscan64(pe) - pe;
  unsigned m = mask;
  while (m) {
    const int s = __ffs(m) - 1;
    m &= m - 1;
    dst[base++] = (lane << 4) | s;
  }
}

__device__ __forceinline__ void write_half(float* __restrict__ dst,
                                           unsigned mask, int lane) {
  float4* o4 = (float4*)dst;
#pragma unroll
  for (int q = 0; q < 4; ++q) {
    float4 o;
    o.x = ((mask >> (4 * q + 0)) & 1) ? 1.0f : 0.0f;
    o.y = ((mask >> (4 * q + 1)) & 1) ? 1.0f : 0.0f;
    o.z = ((mask >> (4 * q + 2)) & 1) ? 1.0f : 0.0f;
    o.w = ((mask >> (4 * q + 3)) & 1) ? 1.0f : 0.0f;
    o4[lane * 4 + q] = o;
  }
}

// ws layout (floats): [0,1024) alpha const logits; [1024,1152) beta base
// dots; [1152,1280) h1a; [1280,1344) h2a.

// ---- precompute, stage 1 (grid 256): the two length-1024 dot layers ----
extern "C" __global__ void pcfs_pre1(const float* __restrict__ ba,
                                     const float* __restrict__ W1a,
                                     const float* __restrict__ b1a,
                                     const float* __restrict__ bb,
                                     const float* __restrict__ W1b,
                                     float* __restrict__ ws) {
  const int b = blockIdx.x;
  const int t = threadIdx.x;
  float acc = 0.0f;
  if (b < 128) {
#pragma unroll
    for (int j = t; j < N_ORB; j += 256) acc += ba[j] * W1a[j * 128 + b];
  } else {
    const int n = b - 128;
#pragma unroll
    for (int j = t; j < N_ORB; j += 256) acc += bb[j] * W1b[j * 128 + n];
  }
  __shared__ float red[4];
  float wsum = wave_sum64_dpp(acc);
  if ((t & 63) == 0) red[t >> 6] = wsum;
  __syncthreads();
  if (t == 0) {
    float tot = red[0] + red[1] + red[2] + red[3];
    if (b < 128)
      ws[1152 + b] = leaky(tot + b1a[b]);
    else
      ws[N_ORB + (b - 128)] = tot;
  }
}

// ---- precompute, stage 2a (1 block x 64): h2 = leaky(h1 @ W2a + b2a) ----
extern "C" __global__ void pcfs_pre2a(const float* __restrict__ W2a,
                                      const float* __restrict__ b2a,
                                      float* __restrict__ ws) {
  const int t = threadIdx.x;  // 64
  float acc = b2a[t];
#pragma unroll 8
  for (int n = 0; n < 128; ++n) acc = __builtin_fmaf(ws[1152 + n], W2a[n * 64 + t], acc);
  ws[1280 + t] = leaky(acc);
}

// ---- precompute, stage 2b (grid 4 x 256): alpha logits = h2 @ W3a + b3a
// + base_a, coalesced row-major W3a reads ----
extern "C" __global__ void pcfs_pre2b(const float* __restrict__ ba,
                                      const float* __restrict__ W3a,
                                      const float* __restrict__ b3a,
                                      float* __restrict__ ws) {
  __shared__ float h2s[64];
  const int t = threadIdx.x;
  const int o = blockIdx.x * 256 + t;
  if (t < 64) h2s[t] = ws[1280 + t];
  __syncthreads();
  float acc = b3a[o] + ba[o];
#pragma unroll 8
  for (int m = 0; m < 64; ++m) acc = __builtin_fmaf(h2s[m], W3a[m * N_ORB + o], acc);
  ws[o] = acc;
}

// One wave per PAIR of batch rows (.x=row0, .y=row1 in every f32x2).
// R8: W3b (256 KB) is LDS-staged in 8x 32KB tiles shared by the block's 4
// waves. Theory: the W3b phase's 256 dependent-batched L2 loads/wave (L1
// thrashes at 16 waves/CU x 256KB; L2 latency under contention, ~4-6 loads
// in flight at 64 VGPR) is the dominant per-wave stall (duty 12.5%, busy 50%
// invariant across wave counts -> latency not TLP). LDS read ~40cy hides
// under the 64 fma issue-cycles per m. fma order unchanged -> bit-exact.
extern "C" __global__ void __launch_bounds__(256, 4) pcfs_sampler(
    const float* __restrict__ ws, const float* __restrict__ Wc,
    const float* __restrict__ bc, const float* __restrict__ W1b,
    const float* __restrict__ b1b, const float* __restrict__ W2b,
    const float* __restrict__ b2b, const float* __restrict__ W3b,
    const float* __restrict__ b3b, const float* __restrict__ bb,
    const float* __restrict__ g_alpha, const float* __restrict__ g_beta,
    float* __restrict__ out, int B) {
  __shared__ int sidx[4][64];        // per-wave: [0..31]=row0, [32..63]=row1
  __shared__ float w3s[8 * N_ORB];   // 32 KB: one 8-row tile of W3b
  const int tid = threadIdx.x;
  const int wave = tid >> 6;
  const int lane = tid & 63;
  const int pair = blockIdx.x * 4 + wave;
  const int row0 = pair * 2;
  // No early return: all threads must reach the tile barriers. Inactive
  // waves compute on clamped rows and skip the output writes.
  const bool active = (row0 < B);
  const bool have1 = active && (row0 + 1 < B);
  const int r0 = active ? row0 : 0;
  const int r1 = have1 ? row0 + 1 : r0;

  // ---- prefetch g_beta into registers NOW: these HBM loads drain ~10k
  // cycles later (beta exp2 stage), fully hidden behind the alpha phase ----
  float4 gb0[4], gb1[4];
  {
    const float4* g40 = (const float4*)(g_beta + (size_t)r0 * N_ORB);
    const float4* g41 = (const float4*)(g_beta + (size_t)r1 * N_ORB);
#pragma unroll
    for (int q = 0; q < 4; ++q) {
      gb0[q] = g40[lane * 4 + q];
      gb1[q] = g41[lane * 4 + q];
    }
  }

  f32x2 w[16], kh[16];

  // ---- alpha chains: w = exp2((const_logits + gumbel) * log2e), 2 rows ----
  {
    const float4* c4 = (const float4*)ws;
    const float4* g40 = (const float4*)(g_alpha + (size_t)r0 * N_ORB);
    const float4* g41 = (const float4*)(g_alpha + (size_t)r1 * N_ORB);
#pragma unroll
    for (int q = 0; q < 4; ++q) {
      float4 c = c4[lane * 4 + q];
      float4 g0 = g40[lane * 4 + q];
      float4 g1 = g41[lane * 4 + q];
      w[4 * q + 0] = f32x2{__builtin_amdgcn_exp2f((c.x + g0.x) * LOG2E),
                           __builtin_amdgcn_exp2f((c.x + g1.x) * LOG2E)};
      w[4 * q + 1] = f32x2{__builtin_amdgcn_exp2f((c.y + g0.y) * LOG2E),
                           __builtin_amdgcn_exp2f((c.y + g1.y) * LOG2E)};
      w[4 * q + 2] = f32x2{__builtin_amdgcn_exp2f((c.z + g0.z) * LOG2E),
                           __builtin_amdgcn_exp2f((c.z + g1.z) * LOG2E)};
      w[4 * q + 3] = f32x2{__builtin_amdgcn_exp2f((c.w + g0.w) * LOG2E),
                           __builtin_amdgcn_exp2f((c.w + g1.w) * LOG2E)};
    }
  }
  run_chain2(w, kh);
  unsigned am0, am1;
  top32_mask2(kh, lane, am0, am1);

  // write alpha halves (hard config: exact 0/1)
  if (active) write_half(out + (size_t)row0 * (2 * N_ORB), am0, lane);
  if (have1) write_half(out + (size_t)(row0 + 1) * (2 * N_ORB), am1, lane);

  // ---- ctx = alpha_config @ Wc + bc, per row (LDS compact + fixed trip) ----
  compact_idx(am0, lane, &sidx[wave][0]);
  compact_idx(am1, lane, &sidx[wave][32]);
  const int vi0 = sidx[wave][lane & 31];
  const int vi1 = sidx[wave][32 + (lane & 31)];
  const float bcv = bc[lane & 31];
  float ctx0 = bcv, ctx1 = bcv;
#pragma unroll
  for (int r = 0; r < 32; ++r) {
    const int i0 = __builtin_amdgcn_readlane(vi0, r);  // uniform
    const int i1 = __builtin_amdgcn_readlane(vi1, r);
    ctx0 += Wc[i0 * 32 + (lane & 31)];
    ctx1 += Wc[i1 * 32 + (lane & 31)];
  }

  // ---- h1 = leaky(base_b@W1b[0:1024] + ctx@W1b[1024:1056] + b1b) ----
  f32x2 h1a, h1b_;
  {
    const float ia = b1b[lane] + ws[N_ORB + lane];
    const float ib = b1b[lane + 64] + ws[N_ORB + lane + 64];
    h1a = f32x2{ia, ia};
    h1b_ = f32x2{ib, ib};
  }
#pragma unroll 4
  for (int c = 0; c < 32; ++c) {
    const f32x2 cv = f32x2{rdlane(ctx0, c), rdlane(ctx1, c)};
    const float* wr = W1b + (size_t)(N_ORB + c) * 128;
    const float wa = wr[lane], wb = wr[lane + 64];
    h1a = __builtin_elementwise_fma(f32x2{wa, wa}, cv, h1a);
    h1b_ = __builtin_elementwise_fma(f32x2{wb, wb}, cv, h1b_);
  }
  h1a = f32x2{leaky(h1a.x), leaky(h1a.y)};
  h1b_ = f32x2{leaky(h1b_.x), leaky(h1b_.y)};

  // ---- h2 = leaky(h1 @ W2b + b2b): 4 partial accumulators (32-deep
  // chains instead of 128-deep) ----
  f32x2 h2p0, h2p1, h2p2, h2p3;
  {
    const float i2 = b2b[lane];
    h2p0 = f32x2{i2, i2};
    h2p1 = f32x2{0.0f, 0.0f};
    h2p2 = f32x2{0.0f, 0.0f};
    h2p3 = f32x2{0.0f, 0.0f};
  }
#pragma unroll 4
  for (int n = 0; n < 64; n += 4) {
    const f32x2 v0 = f32x2{rdlane(h1a.x, n + 0), rdlane(h1a.y, n + 0)};
    const f32x2 v1 = f32x2{rdlane(h1a.x, n + 1), rdlane(h1a.y, n + 1)};
    const f32x2 v2 = f32x2{rdlane(h1a.x, n + 2), rdlane(h1a.y, n + 2)};
    const f32x2 v3 = f32x2{rdlane(h1a.x, n + 3), rdlane(h1a.y, n + 3)};
    const float w0 = W2b[(n + 0) * 64 + lane];
    const float w1 = W2b[(n + 1) * 64 + lane];
    const float w2 = W2b[(n + 2) * 64 + lane];
    const float w3 = W2b[(n + 3) * 64 + lane];
    h2p0 = __builtin_elementwise_fma(f32x2{w0, w0}, v0, h2p0);
    h2p1 = __builtin_elementwise_fma(f32x2{w1, w1}, v1, h2p1);
    h2p2 = __builtin_elementwise_fma(f32x2{w2, w2}, v2, h2p2);
    h2p3 = __builtin_elementwise_fma(f32x2{w3, w3}, v3, h2p3);
  }
#pragma unroll 4
  for (int n = 0; n < 64; n += 4) {
    const f32x2 v0 = f32x2{rdlane(h1b_.x, n + 0), rdlane(h1b_.y, n + 0)};
    const f32x2 v1 = f32x2{rdlane(h1b_.x, n + 1), rdlane(h1b_.y, n + 1)};
    const f32x2 v2 = f32x2{rdlane(h1b_.x, n + 2), rdlane(h1b_.y, n + 2)};
    const f32x2 v3 = f32x2{rdlane(h1b_.x, n + 3), rdlane(h1b_.y, n + 3)};
    const float w0 = W2b[(n + 64 + 0) * 64 + lane];
    const float w1 = W2b[(n + 64 + 1) * 64 + lane];
    const float w2 = W2b[(n + 64 + 2) * 64 + lane];
    const float w3 = W2b[(n + 64 + 3) * 64 + lane];
    h2p0 = __builtin_elementwise_fma(f32x2{w0, w0}, v0, h2p0);
    h2p1 = __builtin_elementwise_fma(f32x2{w1, w1}, v1, h2p1);
    h2p2 = __builtin_elementwise_fma(f32x2{w2, w2}, v2, h2p2);
    h2p3 = __builtin_elementwise_fma(f32x2{w3, w3}, v3, h2p3);
  }
  f32x2 h2v = (h2p0 + h2p1) + (h2p2 + h2p3);
  h2v = f32x2{leaky(h2v.x), leaky(h2v.y)};

  // ---- beta logits: w[] = h2 @ W3b + b3b, with W3b LDS-staged in 8-row
  // tiles shared by the block's 4 waves. fma order identical to the
  // verified global-read version -> bit-exact. ----
  {
    const float4* b4 = (const float4*)b3b;
#pragma unroll
    for (int q = 0; q < 4; ++q) {
      float4 b = b4[lane * 4 + q];
      w[4 * q + 0] = f32x2{b.x, b.x};
      w[4 * q + 1] = f32x2{b.y, b.y};
      w[4 * q + 2] = f32x2{b.z, b.z};
      w[4 * q + 3] = f32x2{b.w, b.w};
    }
  }
  for (int t = 0; t < 8; ++t) {
    __syncthreads();  // previous tile fully consumed before overwrite
    {
      const float4* src = (const float4*)(W3b + (size_t)t * 8 * N_ORB);
      float4* dst = (float4*)w3s;
#pragma unroll
      for (int k = 0; k < 8; ++k) dst[tid + k * 256] = src[tid + k * 256];
    }
    __syncthreads();  // tile visible to all waves
#pragma unroll
    for (int ml = 0; ml < 8; ++ml) {
      const int m = t * 8 + ml;
      const f32x2 hm = f32x2{rdlane(h2v.x, m), rdlane(h2v.y, m)};
      const float4* w4 = (const float4*)(w3s + ml * N_ORB);
#pragma unroll
      for (int q = 0; q < 4; ++q) {
        float4 wv = w4[lane * 4 + q];
        w[4 * q + 0] = __builtin_elementwise_fma(f32x2{wv.x, wv.x}, hm, w[4 * q + 0]);
        w[4 * q + 1] = __builtin_elementwise_fma(f32x2{wv.y, wv.y}, hm, w[4 * q + 1]);
        w[4 * q + 2] = __builtin_elementwise_fma(f32x2{wv.z, wv.z}, hm, w[4 * q + 2]);
        w[4 * q + 3] = __builtin_elementwise_fma(f32x2{wv.w, wv.w}, hm, w[4 * q + 3]);
      }
    }
  }
  // + base_b + gumbel (prefetched) -> w = exp2(logits * log2e)
  {
    const float4* bb4 = (const float4*)bb;
#pragma unroll
    for (int q = 0; q < 4; ++q) {
      float4 b = bb4[lane * 4 + q];
      const float4 g0 = gb0[q];
      const float4 g1 = gb1[q];
      w[4 * q + 0] = f32x2{
          __builtin_amdgcn_exp2f((w[4 * q + 0].x + b.x + g0.x) * LOG2E),
          __builtin_amdgcn_exp2f((w[4 * q + 0].y + b.x + g1.x) * LOG2E)};
      w[4 * q + 1] = f32x2{
          __builtin_amdgcn_exp2f((w[4 * q + 1].x + b.y + g0.y) * LOG2E),
          __builtin_amdgcn_exp2f((w[4 * q + 1].y + b.y + g1.y) * LOG2E)};
      w[4 * q + 2] = f32x2{
          __builtin_amdgcn_exp2f((w[4 * q + 2].x + b.z + g0.z) * LOG2E),
          __builtin_amdgcn_exp2f((w[4 * q + 2].y + b.z + g1.z) * LOG2E)};
      w[4 * q + 3] = f32x2{
          __builtin_amdgcn_exp2f((w[4 * q + 3].x + b.w + g0.w) * LOG2E),
          __builtin_amdgcn_exp2f((w[4 * q + 3].y + b.w + g1.w) * LOG2E)};
    }
  }
  run_chain2(w, kh);
  unsigned bm0, bm1;
  top32_mask2(kh, lane, bm0, bm1);

  if (active) write_half(out + (size_t)row0 * (2 * N_ORB) + N_ORB, bm0, lane);
  if (have1)
    write_half(out + (size_t)(row0 + 1) * (2 * N_ORB) + N_ORB, bm1, lane);
}

extern "C" void kernel_launch(void* const* d_in, const int* in_sizes, int n_in,
                              void* d_out, int out_size, void* d_ws, size_t ws_size,
                              hipStream_t stream) {
  const float* ba  = (const float*)d_in[0];
  const float* W1a = (const float*)d_in[1];
  const float* b1a = (const float*)d_in[2];
  const float* W2a = (const float*)d_in[3];
  const float* b2a = (const float*)d_in[4];
  const float* W3a = (const float*)d_in[5];
  const float* b3a = (const float*)d_in[6];
  const float* bb  = (const float*)d_in[7];
  const float* Wc  = (const float*)d_in[8];
  const float* bc  = (const float*)d_in[9];
  const float* W1b = (const float*)d_in[10];
  const float* b1b = (const float*)d_in[11];
  const float* W2b = (const float*)d_in[12];
  const float* b2b = (const float*)d_in[13];
  const float* W3b = (const float*)d_in[14];
  const float* b3b = (const float*)d_in[15];
  const float* ga  = (const float*)d_in[16];
  const float* gbt = (const float*)d_in[17];
  const int B = in_sizes[16] / N_ORB;
  float* ws = (float*)d_ws;

  hipLaunchKernelGGL(pcfs_pre1, dim3(256), dim3(256), 0, stream,
                     ba, W1a, b1a, bb, W1b, ws);
  hipLaunchKernelGGL(pcfs_pre2a, dim3(1), dim3(64), 0, stream,
                     W2a, b2a, ws);
  hipLaunchKernelGGL(pcfs_pre2b, dim3(4), dim3(256), 0, stream,
                     ba, W3a, b3a, ws);
  const int pairs = (B + 1) / 2;
  hipLaunchKernelGGL(pcfs_sampler, dim3((pairs + 3) / 4), dim3(256), 0, stream,
                     ws, Wc, bc, W1b, b1b, W2b, b2b, W3b, b3b, bb,
                     ga, gbt, (float*)d_out, B);
}

// Round 9
// 265.970 us; speedup vs baseline: 1.2101x; 1.0108x over previous
//
#include <hip/hip_runtime.h>
#include <hip/hip_bf16.h>
#include <float.h>

#define N_ORB 1024
#define KSEL 32
#define LEAK 0.01f
#define LOG2E 1.4426950408889634f

typedef float f32x2 __attribute__((ext_vector_type(2)));
// NOTE: never write (f32x2)(a, b) — in C++ that's a comma-expr cast that
// SPLATS b. Use f32x2{a, b}.

__device__ __forceinline__ float leaky(float x) { return x >= 0.0f ? x : LEAK * x; }

// ---- packed-FP32 helpers (gfx90a+/gfx950 VOP3P, full-rate packed fp32).
// R6-verified: bit-exact (absmax 0), -3.5k VALU instr/wave, -20 us. ----
__device__ __forceinline__ f32x2 pk_add(f32x2 a, f32x2 b) {
  f32x2 d;
  asm("v_pk_add_f32 %0, %1, %2" : "=v"(d) : "v"(a), "v"(b));
  return d;
}
__device__ __forceinline__ f32x2 pk_mul(f32x2 a, f32x2 b) {
  f32x2 d;
  asm("v_pk_mul_f32 %0, %1, %2" : "=v"(d) : "v"(a), "v"(b));
  return d;
}
__device__ __forceinline__ f32x2 pk_fma(f32x2 a, f32x2 b, f32x2 c) {
  f32x2 d;
  asm("v_pk_fma_f32 %0, %1, %2, %3" : "=v"(d) : "v"(a), "v"(b), "v"(c));
  return d;
}
// VOP3P clamp bit == clamp result to [0,1] per half — exactly the verified
// min(max(om,0),1) semantics, in one instruction.
__device__ __forceinline__ f32x2 pk_fma_clamp(f32x2 a, f32x2 b, f32x2 c) {
  f32x2 d;
  asm("v_pk_fma_f32 %0, %1, %2, %3 clamp" : "=v"(d) : "v"(a), "v"(b), "v"(c));
  return d;
}

// ---- DPP helpers ----
template <int CTRL, int RM>
__device__ __forceinline__ int dpp0_i(int v) {  // masked-off rows contribute 0
  return __builtin_amdgcn_update_dpp(0, v, CTRL, RM, 0xF, true);
}
template <int CTRL>
__device__ __forceinline__ float dpp_zero(float v) {
  return __int_as_float(
      __builtin_amdgcn_update_dpp(0, __float_as_int(v), CTRL, 0xF, 0xF, true));
}
__device__ __forceinline__ float rdlane(float v, int l) {
  return __int_as_float(__builtin_amdgcn_readlane(__float_as_int(v), l));
}

// full 64-lane float sum, uniform result
__device__ __forceinline__ float wave_sum64_dpp(float v) {
  v += dpp_zero<0x111>(v);
  v += dpp_zero<0x112>(v);
  v += dpp_zero<0x114>(v);
  v += dpp_zero<0x118>(v);
  v += dpp_zero<0x142>(v);
  v += dpp_zero<0x143>(v);
  return rdlane(v, 63);
}
// full 64-lane int sum, uniform result
__device__ __forceinline__ int wave_isum64(int v) {
  v += dpp0_i<0x111, 0xF>(v);
  v += dpp0_i<0x112, 0xF>(v);
  v += dpp0_i<0x114, 0xF>(v);
  v += dpp0_i<0x118, 0xF>(v);
  v += dpp0_i<0x142, 0xF>(v);
  v += dpp0_i<0x143, 0xF>(v);
  return __builtin_amdgcn_readlane(v, 63);
}
// 64-lane inclusive prefix sum (int), per-lane result
__device__ __forceinline__ int wave_iscan64(int v) {
  v += dpp0_i<0x111, 0xF>(v);
  v += dpp0_i<0x112, 0xF>(v);
  v += dpp0_i<0x114, 0xF>(v);
  v += dpp0_i<0x118, 0xF>(v);
  v += dpp0_i<0x142, 0xA>(v);
  v += dpp0_i<0x143, 0xC>(v);
  return v;
}

// Successive-softmax chain for TWO rows packed in f32x2 (.x=row0,.y=row1),
// multiplicative form (w tracks exp(s)). Element j of a row = lane*16 + j.
// pk_fma_clamp == ref's 1e-20 floor at fp32 (khot deltas <= 1e-20, far below
// any top-32 boundary). fma(w, -rZ, 1) == fma(-w, rZ, 1) exactly (product is
// exact inside fma), so building rZn once per iteration is bit-identical.
__device__ void run_chain2(f32x2 w[16], f32x2 kh[16]) {
#pragma unroll
  for (int i = 0; i < 16; ++i) kh[i] = f32x2{0.0f, 0.0f};
  const f32x2 onev = f32x2{1.0f, 1.0f};
  for (int it = 0; it < KSEL; ++it) {
    f32x2 t0 = pk_add(w[0], w[1]), t1 = pk_add(w[2], w[3]);
    f32x2 t2 = pk_add(w[4], w[5]), t3 = pk_add(w[6], w[7]);
    f32x2 t4 = pk_add(w[8], w[9]), t5 = pk_add(w[10], w[11]);
    f32x2 t6 = pk_add(w[12], w[13]), t7 = pk_add(w[14], w[15]);
    t0 = pk_add(t0, t1); t2 = pk_add(t2, t3);
    t4 = pk_add(t4, t5); t6 = pk_add(t6, t7);
    t0 = pk_add(t0, t2); t4 = pk_add(t4, t6);
    t0 = pk_add(t0, t4);
    float Z0 = wave_sum64_dpp(t0.x);  // independent of Z1 -> interleaved issue
    float Z1 = wave_sum64_dpp(t0.y);
    Z0 = fmaxf(Z0, 1e-30f);
    Z1 = fmaxf(Z1, 1e-30f);
    float r0 = __builtin_amdgcn_rcpf(Z0);
    float r1 = __builtin_amdgcn_rcpf(Z1);
    float rZ0 = __builtin_fmaf(__builtin_fmaf(-Z0, r0, 1.0f), r0, r0);
    float rZ1 = __builtin_fmaf(__builtin_fmaf(-Z1, r1, 1.0f), r1, r1);
    const f32x2 rZ = f32x2{rZ0, rZ1};
    const f32x2 rZn = f32x2{-rZ0, -rZ1};
#pragma unroll
    for (int i = 0; i < 16; ++i) {
      kh[i] = pk_fma(w[i], rZ, kh[i]);
      f32x2 om = pk_fma_clamp(w[i], rZn, onev);  // clamp [0,1]
      w[i] = pk_mul(w[i], om);
    }
  }
}

// Tie path for one row (cold). jax stable tie semantics: all >T, then ==T
// in ascending global index ((lane<<4)|slot).
__device__ unsigned tie_mask16(const f32x2 kh[16], bool comp_y, unsigned T,
                               int lane) {
  unsigned gt = 0, eq = 0;
#pragma unroll
  for (int i = 0; i < 16; ++i) {
    const unsigned u = __float_as_uint(comp_y ? kh[i].y : kh[i].x);
    gt |= (u > T ? 1u : 0u) << i;
    eq |= (u == T ? 1u : 0u) << i;
  }
  const int n_gt = wave_isum64(__popc(gt));
  const int m = 32 - n_gt;  // uniform, >= 1 by search invariant
  const int pe = __popc(eq);
  const int be = wave_iscan64(pe) - pe;
  int need = m - be;
  need = need < 0 ? 0 : (need > pe ? pe : need);
  unsigned tk = 0;
  unsigned em = eq;
  for (int guard = 0; guard < 16; ++guard) {
    if (!__any(need > 0)) break;
    if (need > 0) {
      const int bpos = __ffs(em) - 1;
      tk |= 1u << bpos;
      em &= em - 1;
      --need;
    }
  }
  return gt | tk;
}

// Top-32 for both packed rows: joint binary search on the uint views
// (khot >= 0 -> order-isomorphic), ballot+popcll counting, early exit when
// both rows exact. Invariant (r6/r7, field-validated): tie path always
// completes exactly 32.
__device__ void top32_mask2(const f32x2 kh[16], int lane, unsigned& m0,
                            unsigned& m1) {
  unsigned lo0 = 0, lo1 = 0;
  bool ex0 = false, ex1 = false;
  for (int b = 30; b >= 0; --b) {
    const unsigned c0v = lo0 | (1u << b);
    const unsigned c1v = lo1 | (1u << b);
    int c0 = 0, c1 = 0;
#pragma unroll
    for (int i = 0; i < 16; ++i) {
      c0 += __popcll(__ballot(__float_as_uint(kh[i].x) >= c0v));
      c1 += __popcll(__ballot(__float_as_uint(kh[i].y) >= c1v));
    }
    if (!ex0 && c0 >= 32) { lo0 = c0v; ex0 = (c0 == 32); }
    if (!ex1 && c1 >= 32) { lo1 = c1v; ex1 = (c1 == 32); }
    if (ex0 && ex1) break;
  }

  if (ex0) {
    unsigned mk = 0;
#pragma unroll
    for (int i = 0; i < 16; ++i)
      mk |= (__float_as_uint(kh[i].x) >= lo0 ? 1u : 0u) << i;
    m0 = mk;
  } else {
    m0 = tie_mask16(kh, false, lo0, lane);
  }
  if (ex1) {
    unsigned mk = 0;
#pragma unroll
    for (int i = 0; i < 16; ++i)
      mk |= (__float_as_uint(kh[i].y) >= lo1 ? 1u : 0u) << i;
    m1 = mk;
  } else {
    m1 = tie_mask16(kh, true, lo1, lane);
  }
}

// Compact the 32 selected global indices into dst[0..31], ascending order.
__device__ __forceinline__ void compact_idx(unsigned mask, int lane,
                                            int* __restrict__ dst) {
  const int pe = __popc(mask);
  int base = wave_iscan64(pe) - pe;
  unsigned m = mask;
  while (m) {
    const int s = __ffs(m) - 1;
    m &= m - 1;
    dst[base++] = (lane << 4) | s;
  }
}

__device__ __forceinline__ void write_half(float* __restrict__ dst,
                                           unsigned mask, int lane) {
  float4* o4 = (float4*)dst;
#pragma unroll
  for (int q = 0; q < 4; ++q) {
    float4 o;
    o.x = ((mask >> (4 * q + 0)) & 1) ? 1.0f : 0.0f;
    o.y = ((mask >> (4 * q + 1)) & 1) ? 1.0f : 0.0f;
    o.z = ((mask >> (4 * q + 2)) & 1) ? 1.0f : 0.0f;
    o.w = ((mask >> (4 * q + 3)) & 1) ? 1.0f : 0.0f;
    o4[lane * 4 + q] = o;
  }
}

// ws layout (floats): [0,1024) alpha const logits; [1024,1152) beta base
// dots; [1152,1280) h1a; [1280,1344) h2a.

// ---- precompute, stage 1 (grid 256): the two length-1024 dot layers ----
extern "C" __global__ void pcfs_pre1(const float* __restrict__ ba,
                                     const float* __restrict__ W1a,
                                     const float* __restrict__ b1a,
                                     const float* __restrict__ bb,
                                     const float* __restrict__ W1b,
                                     float* __restrict__ ws) {
  const int b = blockIdx.x;
  const int t = threadIdx.x;
  float acc = 0.0f;
  if (b < 128) {
#pragma unroll
    for (int j = t; j < N_ORB; j += 256) acc += ba[j] * W1a[j * 128 + b];
  } else {
    const int n = b - 128;
#pragma unroll
    for (int j = t; j < N_ORB; j += 256) acc += bb[j] * W1b[j * 128 + n];
  }
  __shared__ float red[4];
  float wsum = wave_sum64_dpp(acc);
  if ((t & 63) == 0) red[t >> 6] = wsum;
  __syncthreads();
  if (t == 0) {
    float tot = red[0] + red[1] + red[2] + red[3];
    if (b < 128)
      ws[1152 + b] = leaky(tot + b1a[b]);
    else
      ws[N_ORB + (b - 128)] = tot;
  }
}

// ---- precompute, stage 2a (1 block x 64): h2 = leaky(h1 @ W2a + b2a) ----
extern "C" __global__ void pcfs_pre2a(const float* __restrict__ W2a,
                                      const float* __restrict__ b2a,
                                      float* __restrict__ ws) {
  const int t = threadIdx.x;  // 64
  float acc = b2a[t];
#pragma unroll 8
  for (int n = 0; n < 128; ++n) acc = __builtin_fmaf(ws[1152 + n], W2a[n * 64 + t], acc);
  ws[1280 + t] = leaky(acc);
}

// ---- precompute, stage 2b (grid 4 x 256): alpha logits = h2 @ W3a + b3a
// + base_a, coalesced row-major W3a reads ----
extern "C" __global__ void pcfs_pre2b(const float* __restrict__ ba,
                                      const float* __restrict__ W3a,
                                      const float* __restrict__ b3a,
                                      float* __restrict__ ws) {
  __shared__ float h2s[64];
  const int t = threadIdx.x;
  const int o = blockIdx.x * 256 + t;
  if (t < 64) h2s[t] = ws[1280 + t];
  __syncthreads();
  float acc = b3a[o] + ba[o];
#pragma unroll 8
  for (int m = 0; m < 64; ++m) acc = __builtin_fmaf(h2s[m], W3a[m * N_ORB + o], acc);
  ws[o] = acc;
}

// One wave per PAIR of batch rows (.x=row0, .y=row1 in every f32x2).
// R8: W3b LDS-staged in 8x 32KB tiles (verified -8 us) but the tile read
// pattern (lane*64B stride) was a heavy bank conflict: SQ_LDS_BANK_CONFLICT
// 1.26e7 = ~12 extra cy on every ds_read_b128 (~15% of wall in LDS
// serialization). R9: bijective slot swizzle SWZ(f)=((f&7)<<5)|(f>>3)
// applied to BOTH staging write and read -> every wave64 b128 access hits
// each bank-group exactly 8x (the hardware minimum). Pure layout change,
// bit-exact.
extern "C" __global__ void __launch_bounds__(256, 4) pcfs_sampler(
    const float* __restrict__ ws, const float* __restrict__ Wc,
    const float* __restrict__ bc, const float* __restrict__ W1b,
    const float* __restrict__ b1b, const float* __restrict__ W2b,
    const float* __restrict__ b2b, const float* __restrict__ W3b,
    const float* __restrict__ b3b, const float* __restrict__ bb,
    const float* __restrict__ g_alpha, const float* __restrict__ g_beta,
    float* __restrict__ out, int B) {
  __shared__ int sidx[4][64];        // per-wave: [0..31]=row0, [32..63]=row1
  __shared__ float w3s[8 * N_ORB];   // 32 KB: one 8-row tile of W3b
  const int tid = threadIdx.x;
  const int wave = tid >> 6;
  const int lane = tid & 63;
  const int pair = blockIdx.x * 4 + wave;
  const int row0 = pair * 2;
  // No early return: all threads must reach the tile barriers. Inactive
  // waves compute on clamped rows and skip the output writes.
  const bool active = (row0 < B);
  const bool have1 = active && (row0 + 1 < B);
  const int r0 = active ? row0 : 0;
  const int r1 = have1 ? row0 + 1 : r0;

  // ---- prefetch g_beta into registers NOW: these HBM loads drain ~10k
  // cycles later (beta exp2 stage), fully hidden behind the alpha phase ----
  float4 gb0[4], gb1[4];
  {
    const float4* g40 = (const float4*)(g_beta + (size_t)r0 * N_ORB);
    const float4* g41 = (const float4*)(g_beta + (size_t)r1 * N_ORB);
#pragma unroll
    for (int q = 0; q < 4; ++q) {
      gb0[q] = g40[lane * 4 + q];
      gb1[q] = g41[lane * 4 + q];
    }
  }

  f32x2 w[16], kh[16];

  // ---- alpha chains: w = exp2((const_logits + gumbel) * log2e), 2 rows ----
  {
    const float4* c4 = (const float4*)ws;
    const float4* g40 = (const float4*)(g_alpha + (size_t)r0 * N_ORB);
    const float4* g41 = (const float4*)(g_alpha + (size_t)r1 * N_ORB);
#pragma unroll
    for (int q = 0; q < 4; ++q) {
      float4 c = c4[lane * 4 + q];
      float4 g0 = g40[lane * 4 + q];
      float4 g1 = g41[lane * 4 + q];
      w[4 * q + 0] = f32x2{__builtin_amdgcn_exp2f((c.x + g0.x) * LOG2E),
                           __builtin_amdgcn_exp2f((c.x + g1.x) * LOG2E)};
      w[4 * q + 1] = f32x2{__builtin_amdgcn_exp2f((c.y + g0.y) * LOG2E),
                           __builtin_amdgcn_exp2f((c.y + g1.y) * LOG2E)};
      w[4 * q + 2] = f32x2{__builtin_amdgcn_exp2f((c.z + g0.z) * LOG2E),
                           __builtin_amdgcn_exp2f((c.z + g1.z) * LOG2E)};
      w[4 * q + 3] = f32x2{__builtin_amdgcn_exp2f((c.w + g0.w) * LOG2E),
                           __builtin_amdgcn_exp2f((c.w + g1.w) * LOG2E)};
    }
  }
  run_chain2(w, kh);
  unsigned am0, am1;
  top32_mask2(kh, lane, am0, am1);

  // write alpha halves (hard config: exact 0/1)
  if (active) write_half(out + (size_t)row0 * (2 * N_ORB), am0, lane);
  if (have1) write_half(out + (size_t)(row0 + 1) * (2 * N_ORB), am1, lane);

  // ---- ctx = alpha_config @ Wc + bc, per row (LDS compact + fixed trip) ----
  compact_idx(am0, lane, &sidx[wave][0]);
  compact_idx(am1, lane, &sidx[wave][32]);
  const int vi0 = sidx[wave][lane & 31];
  const int vi1 = sidx[wave][32 + (lane & 31)];
  const float bcv = bc[lane & 31];
  float ctx0 = bcv, ctx1 = bcv;
#pragma unroll
  for (int r = 0; r < 32; ++r) {
    const int i0 = __builtin_amdgcn_readlane(vi0, r);  // uniform
    const int i1 = __builtin_amdgcn_readlane(vi1, r);
    ctx0 += Wc[i0 * 32 + (lane & 31)];
    ctx1 += Wc[i1 * 32 + (lane & 31)];
  }

  // ---- h1 = leaky(base_b@W1b[0:1024] + ctx@W1b[1024:1056] + b1b) ----
  f32x2 h1a, h1b_;
  {
    const float ia = b1b[lane] + ws[N_ORB + lane];
    const float ib = b1b[lane + 64] + ws[N_ORB + lane + 64];
    h1a = f32x2{ia, ia};
    h1b_ = f32x2{ib, ib};
  }
#pragma unroll 4
  for (int c = 0; c < 32; ++c) {
    const f32x2 cv = f32x2{rdlane(ctx0, c), rdlane(ctx1, c)};
    const float* wr = W1b + (size_t)(N_ORB + c) * 128;
    const float wa = wr[lane], wb = wr[lane + 64];
    h1a = __builtin_elementwise_fma(f32x2{wa, wa}, cv, h1a);
    h1b_ = __builtin_elementwise_fma(f32x2{wb, wb}, cv, h1b_);
  }
  h1a = f32x2{leaky(h1a.x), leaky(h1a.y)};
  h1b_ = f32x2{leaky(h1b_.x), leaky(h1b_.y)};

  // ---- h2 = leaky(h1 @ W2b + b2b): 4 partial accumulators (32-deep
  // chains instead of 128-deep) ----
  f32x2 h2p0, h2p1, h2p2, h2p3;
  {
    const float i2 = b2b[lane];
    h2p0 = f32x2{i2, i2};
    h2p1 = f32x2{0.0f, 0.0f};
    h2p2 = f32x2{0.0f, 0.0f};
    h2p3 = f32x2{0.0f, 0.0f};
  }
#pragma unroll 4
  for (int n = 0; n < 64; n += 4) {
    const f32x2 v0 = f32x2{rdlane(h1a.x, n + 0), rdlane(h1a.y, n + 0)};
    const f32x2 v1 = f32x2{rdlane(h1a.x, n + 1), rdlane(h1a.y, n + 1)};
    const f32x2 v2 = f32x2{rdlane(h1a.x, n + 2), rdlane(h1a.y, n + 2)};
    const f32x2 v3 = f32x2{rdlane(h1a.x, n + 3), rdlane(h1a.y, n + 3)};
    const float w0 = W2b[(n + 0) * 64 + lane];
    const float w1 = W2b[(n + 1) * 64 + lane];
    const float w2 = W2b[(n + 2) * 64 + lane];
    const float w3 = W2b[(n + 3) * 64 + lane];
    h2p0 = __builtin_elementwise_fma(f32x2{w0, w0}, v0, h2p0);
    h2p1 = __builtin_elementwise_fma(f32x2{w1, w1}, v1, h2p1);
    h2p2 = __builtin_elementwise_fma(f32x2{w2, w2}, v2, h2p2);
    h2p3 = __builtin_elementwise_fma(f32x2{w3, w3}, v3, h2p3);
  }
#pragma unroll 4
  for (int n = 0; n < 64; n += 4) {
    const f32x2 v0 = f32x2{rdlane(h1b_.x, n + 0), rdlane(h1b_.y, n + 0)};
    const f32x2 v1 = f32x2{rdlane(h1b_.x, n + 1), rdlane(h1b_.y, n + 1)};
    const f32x2 v2 = f32x2{rdlane(h1b_.x, n + 2), rdlane(h1b_.y, n + 2)};
    const f32x2 v3 = f32x2{rdlane(h1b_.x, n + 3), rdlane(h1b_.y, n + 3)};
    const float w0 = W2b[(n + 64 + 0) * 64 + lane];
    const float w1 = W2b[(n + 64 + 1) * 64 + lane];
    const float w2 = W2b[(n + 64 + 2) * 64 + lane];
    const float w3 = W2b[(n + 64 + 3) * 64 + lane];
    h2p0 = __builtin_elementwise_fma(f32x2{w0, w0}, v0, h2p0);
    h2p1 = __builtin_elementwise_fma(f32x2{w1, w1}, v1, h2p1);
    h2p2 = __builtin_elementwise_fma(f32x2{w2, w2}, v2, h2p2);
    h2p3 = __builtin_elementwise_fma(f32x2{w3, w3}, v3, h2p3);
  }
  f32x2 h2v = (h2p0 + h2p1) + (h2p2 + h2p3);
  h2v = f32x2{leaky(h2v.x), leaky(h2v.y)};

  // ---- beta logits: w[] = h2 @ W3b + b3b, W3b LDS-staged in 8-row tiles,
  // slots swizzled SWZ(f)=((f&7)<<5)|(f>>3) on write AND read (conflict-free
  // wave64 b128: 8 lanes/bank-group = HW minimum). fma order identical to
  // the verified version -> bit-exact. ----
  {
    const float4* b4 = (const float4*)b3b;
#pragma unroll
    for (int q = 0; q < 4; ++q) {
      float4 b = b4[lane * 4 + q];
      w[4 * q + 0] = f32x2{b.x, b.x};
      w[4 * q + 1] = f32x2{b.y, b.y};
      w[4 * q + 2] = f32x2{b.z, b.z};
      w[4 * q + 3] = f32x2{b.w, b.w};
    }
  }
  // per-lane swizzled read base (float4 units within a row):
  // SWZ(lane*4+q) = ((lane&1)<<7) | (q<<5) | (lane>>1)
  const int swzrd = ((lane & 1) << 7) | (lane >> 1);
  // staging write slot for float4 j=tid of each row: SWZ(tid)
  const int swzwr = ((tid & 7) << 5) | (tid >> 3);
  for (int t = 0; t < 8; ++t) {
    __syncthreads();  // previous tile fully consumed before overwrite
    {
      const float4* src = (const float4*)(W3b + (size_t)t * 8 * N_ORB);
      float4* dst = (float4*)w3s;
#pragma unroll
      for (int k = 0; k < 8; ++k) dst[k * 256 + swzwr] = src[tid + k * 256];
    }
    __syncthreads();  // tile visible to all waves
#pragma unroll
    for (int ml = 0; ml < 8; ++ml) {
      const int m = t * 8 + ml;
      const f32x2 hm = f32x2{rdlane(h2v.x, m), rdlane(h2v.y, m)};
      const float4* w4 = (const float4*)(w3s + ml * N_ORB);
#pragma unroll
      for (int q = 0; q < 4; ++q) {
        float4 wv = w4[swzrd + (q << 5)];
        w[4 * q + 0] = __builtin_elementwise_fma(f32x2{wv.x, wv.x}, hm, w[4 * q + 0]);
        w[4 * q + 1] = __builtin_elementwise_fma(f32x2{wv.y, wv.y}, hm, w[4 * q + 1]);
        w[4 * q + 2] = __builtin_elementwise_fma(f32x2{wv.z, wv.z}, hm, w[4 * q + 2]);
        w[4 * q + 3] = __builtin_elementwise_fma(f32x2{wv.w, wv.w}, hm, w[4 * q + 3]);
      }
    }
  }
  // + base_b + gumbel (prefetched) -> w = exp2(logits * log2e)
  {
    const float4* bb4 = (const float4*)bb;
#pragma unroll
    for (int q = 0; q < 4; ++q) {
      float4 b = bb4[lane * 4 + q];
      const float4 g0 = gb0[q];
      const float4 g1 = gb1[q];
      w[4 * q + 0] = f32x2{
          __builtin_amdgcn_exp2f((w[4 * q + 0].x + b.x + g0.x) * LOG2E),
          __builtin_amdgcn_exp2f((w[4 * q + 0].y + b.x + g1.x) * LOG2E)};
      w[4 * q + 1] = f32x2{
          __builtin_amdgcn_exp2f((w[4 * q + 1].x + b.y + g0.y) * LOG2E),
          __builtin_amdgcn_exp2f((w[4 * q + 1].y + b.y + g1.y) * LOG2E)};
      w[4 * q + 2] = f32x2{
          __builtin_amdgcn_exp2f((w[4 * q + 2].x + b.z + g0.z) * LOG2E),
          __builtin_amdgcn_exp2f((w[4 * q + 2].y + b.z + g1.z) * LOG2E)};
      w[4 * q + 3] = f32x2{
          __builtin_amdgcn_exp2f((w[4 * q + 3].x + b.w + g0.w) * LOG2E),
          __builtin_amdgcn_exp2f((w[4 * q + 3].y + b.w + g1.w) * LOG2E)};
    }
  }
  run_chain2(w, kh);
  unsigned bm0, bm1;
  top32_mask2(kh, lane, bm0, bm1);

  if (active) write_half(out + (size_t)row0 * (2 * N_ORB) + N_ORB, bm0, lane);
  if (have1)
    write_half(out + (size_t)(row0 + 1) * (2 * N_ORB) + N_ORB, bm1, lane);
}

extern "C" void kernel_launch(void* const* d_in, const int* in_sizes, int n_in,
                              void* d_out, int out_size, void* d_ws, size_t ws_size,
                              hipStream_t stream) {
  const float* ba  = (const float*)d_in[0];
  const float* W1a = (const float*)d_in[1];
  const float* b1a = (const float*)d_in[2];
  const float* W2a = (const float*)d_in[3];
  const float* b2a = (const float*)d_in[4];
  const float* W3a = (const float*)d_in[5];
  const float* b3a = (const float*)d_in[6];
  const float* bb  = (const float*)d_in[7];
  const float* Wc  = (const float*)d_in[8];
  const float* bc  = (const float*)d_in[9];
  const float* W1b = (const float*)d_in[10];
  const float* b1b = (const float*)d_in[11];
  const float* W2b = (const float*)d_in[12];
  const float* b2b = (const float*)d_in[13];
  const float* W3b = (const float*)d_in[14];
  const float* b3b = (const float*)d_in[15];
  const float* ga  = (const float*)d_in[16];
  const float* gbt = (const float*)d_in[17];
  const int B = in_sizes[16] / N_ORB;
  float* ws = (float*)d_ws;

  hipLaunchKernelGGL(pcfs_pre1, dim3(256), dim3(256), 0, stream,
                     ba, W1a, b1a, bb, W1b, ws);
  hipLaunchKernelGGL(pcfs_pre2a, dim3(1), dim3(64), 0, stream,
                     W2a, b2a, ws);
  hipLaunchKernelGGL(pcfs_pre2b, dim3(4), dim3(256), 0, stream,
                     ba, W3a, b3a, ws);
  const int pairs = (B + 1) / 2;
  hipLaunchKernelGGL(pcfs_sampler, dim3((pairs + 3) / 4), dim3(256), 0, stream,
                     ws, Wc, bc, W1b, b1b, W2b, b2b, W3b, b3b, bb,
                     ga, gbt, (float*)d_out, B);
}

// Round 10
// 240.473 us; speedup vs baseline: 1.3384x; 1.1060x over previous
//
#include <hip/hip_runtime.h>
#include <hip/hip_bf16.h>
#include <float.h>

#define N_ORB 1024
#define KSEL 32
#define LEAK 0.01f

typedef float f32x2 __attribute__((ext_vector_type(2)));
// NOTE: never write (f32x2)(a, b) — comma-expr cast SPLATS b. Use f32x2{a,b}.

__device__ __forceinline__ float leaky(float x) { return x >= 0.0f ? x : LEAK * x; }

// R10: the successive-softmax chains are DELETED. The forward output is only
// the hard top-32 masks of khot, and khot order == score order (exact-math
// proof: a_t>b_t => a'-b' = (a-b)(1-(a+b)/Z) > 0 since a+b<Z strictly, so
// khot_a-khot_b = sum (a_t-b_t)*rZ_t > 0; exact score ties => khot ties =>
// ascending-index tie-break matches lax.top_k). Selection runs directly on
// monotone uint keys of scores = const_logits + gumbel.
__device__ __forceinline__ unsigned fkey(float f) {
  const unsigned u = __float_as_uint(f);
  return u ^ ((unsigned)((int)u >> 31) | 0x80000000u);
}

// ---- DPP helpers ----
template <int CTRL, int RM>
__device__ __forceinline__ int dpp0_i(int v) {  // masked-off rows contribute 0
  return __builtin_amdgcn_update_dpp(0, v, CTRL, RM, 0xF, true);
}
template <int CTRL>
__device__ __forceinline__ float dpp_zero(float v) {
  return __int_as_float(
      __builtin_amdgcn_update_dpp(0, __float_as_int(v), CTRL, 0xF, 0xF, true));
}
__device__ __forceinline__ float rdlane(float v, int l) {
  return __int_as_float(__builtin_amdgcn_readlane(__float_as_int(v), l));
}

// full 64-lane float sum, uniform result
__device__ __forceinline__ float wave_sum64_dpp(float v) {
  v += dpp_zero<0x111>(v);
  v += dpp_zero<0x112>(v);
  v += dpp_zero<0x114>(v);
  v += dpp_zero<0x118>(v);
  v += dpp_zero<0x142>(v);
  v += dpp_zero<0x143>(v);
  return rdlane(v, 63);
}
// full 64-lane int sum, uniform result
__device__ __forceinline__ int wave_isum64(int v) {
  v += dpp0_i<0x111, 0xF>(v);
  v += dpp0_i<0x112, 0xF>(v);
  v += dpp0_i<0x114, 0xF>(v);
  v += dpp0_i<0x118, 0xF>(v);
  v += dpp0_i<0x142, 0xF>(v);
  v += dpp0_i<0x143, 0xF>(v);
  return __builtin_amdgcn_readlane(v, 63);
}
// 64-lane inclusive prefix sum (int), per-lane result
__device__ __forceinline__ int wave_iscan64(int v) {
  v += dpp0_i<0x111, 0xF>(v);
  v += dpp0_i<0x112, 0xF>(v);
  v += dpp0_i<0x114, 0xF>(v);
  v += dpp0_i<0x118, 0xF>(v);
  v += dpp0_i<0x142, 0xA>(v);
  v += dpp0_i<0x143, 0xC>(v);
  return v;
}

// Tie path (cold). jax stable tie semantics: all >T, then ==T in ascending
// global index ((lane<<4)|slot). Operates on monotone uint keys.
__device__ unsigned tie_mask16u(const unsigned K[16], unsigned T, int lane) {
  unsigned gt = 0, eq = 0;
#pragma unroll
  for (int i = 0; i < 16; ++i) {
    gt |= (K[i] > T ? 1u : 0u) << i;
    eq |= (K[i] == T ? 1u : 0u) << i;
  }
  const int n_gt = wave_isum64(__popc(gt));
  const int m = 32 - n_gt;  // uniform, >= 1 by search invariant
  const int pe = __popc(eq);
  const int be = wave_iscan64(pe) - pe;
  int need = m - be;
  need = need < 0 ? 0 : (need > pe ? pe : need);
  unsigned tk = 0;
  unsigned em = eq;
  for (int guard = 0; guard < 16; ++guard) {
    if (!__any(need > 0)) break;
    if (need > 0) {
      const int bpos = __ffs(em) - 1;
      tk |= 1u << bpos;
      em &= em - 1;
      --need;
    }
  }
  return gt | tk;
}

// Top-32 for two rows on uint keys (bit 31 meaningful: sign-corrected keys),
// joint binary search, ballot+popcll counting, early exit when both exact.
__device__ void top32_mask2u(const unsigned K0[16], const unsigned K1[16],
                             int lane, unsigned& m0, unsigned& m1) {
  unsigned lo0 = 0, lo1 = 0;
  bool ex0 = false, ex1 = false;
  for (int b = 31; b >= 0; --b) {
    const unsigned c0v = lo0 | (1u << b);
    const unsigned c1v = lo1 | (1u << b);
    int c0 = 0, c1 = 0;
#pragma unroll
    for (int i = 0; i < 16; ++i) {
      c0 += __popcll(__ballot(K0[i] >= c0v));
      c1 += __popcll(__ballot(K1[i] >= c1v));
    }
    if (!ex0 && c0 >= 32) { lo0 = c0v; ex0 = (c0 == 32); }
    if (!ex1 && c1 >= 32) { lo1 = c1v; ex1 = (c1 == 32); }
    if (ex0 && ex1) break;
  }

  if (ex0) {
    unsigned mk = 0;
#pragma unroll
    for (int i = 0; i < 16; ++i) mk |= (K0[i] >= lo0 ? 1u : 0u) << i;
    m0 = mk;
  } else {
    m0 = tie_mask16u(K0, lo0, lane);
  }
  if (ex1) {
    unsigned mk = 0;
#pragma unroll
    for (int i = 0; i < 16; ++i) mk |= (K1[i] >= lo1 ? 1u : 0u) << i;
    m1 = mk;
  } else {
    m1 = tie_mask16u(K1, lo1, lane);
  }
}

// Compact the 32 selected global indices into dst[0..31], ascending order.
__device__ __forceinline__ void compact_idx(unsigned mask, int lane,
                                            int* __restrict__ dst) {
  const int pe = __popc(mask);
  int base = wave_iscan64(pe) - pe;
  unsigned m = mask;
  while (m) {
    const int s = __ffs(m) - 1;
    m &= m - 1;
    dst[base++] = (lane << 4) | s;
  }
}

__device__ __forceinline__ void write_half(float* __restrict__ dst,
                                           unsigned mask, int lane) {
  float4* o4 = (float4*)dst;
#pragma unroll
  for (int q = 0; q < 4; ++q) {
    float4 o;
    o.x = ((mask >> (4 * q + 0)) & 1) ? 1.0f : 0.0f;
    o.y = ((mask >> (4 * q + 1)) & 1) ? 1.0f : 0.0f;
    o.z = ((mask >> (4 * q + 2)) & 1) ? 1.0f : 0.0f;
    o.w = ((mask >> (4 * q + 3)) & 1) ? 1.0f : 0.0f;
    o4[lane * 4 + q] = o;
  }
}

// ws layout (floats): [0,1024) alpha const logits; [1024,1152) beta base
// dots; [1152,1280) h1a; [1280,1344) h2a.

// ---- precompute, stage 1 (grid 256): the two length-1024 dot layers ----
extern "C" __global__ void pcfs_pre1(const float* __restrict__ ba,
                                     const float* __restrict__ W1a,
                                     const float* __restrict__ b1a,
                                     const float* __restrict__ bb,
                                     const float* __restrict__ W1b,
                                     float* __restrict__ ws) {
  const int b = blockIdx.x;
  const int t = threadIdx.x;
  float acc = 0.0f;
  if (b < 128) {
#pragma unroll
    for (int j = t; j < N_ORB; j += 256) acc += ba[j] * W1a[j * 128 + b];
  } else {
    const int n = b - 128;
#pragma unroll
    for (int j = t; j < N_ORB; j += 256) acc += bb[j] * W1b[j * 128 + n];
  }
  __shared__ float red[4];
  float wsum = wave_sum64_dpp(acc);
  if ((t & 63) == 0) red[t >> 6] = wsum;
  __syncthreads();
  if (t == 0) {
    float tot = red[0] + red[1] + red[2] + red[3];
    if (b < 128)
      ws[1152 + b] = leaky(tot + b1a[b]);
    else
      ws[N_ORB + (b - 128)] = tot;
  }
}

// ---- precompute, stage 2a (1 block x 64): h2 = leaky(h1 @ W2a + b2a) ----
extern "C" __global__ void pcfs_pre2a(const float* __restrict__ W2a,
                                      const float* __restrict__ b2a,
                                      float* __restrict__ ws) {
  const int t = threadIdx.x;  // 64
  float acc = b2a[t];
#pragma unroll 8
  for (int n = 0; n < 128; ++n) acc = __builtin_fmaf(ws[1152 + n], W2a[n * 64 + t], acc);
  ws[1280 + t] = leaky(acc);
}

// ---- precompute, stage 2b (grid 4 x 256): alpha logits = h2 @ W3a + b3a
// + base_a, coalesced row-major W3a reads ----
extern "C" __global__ void pcfs_pre2b(const float* __restrict__ ba,
                                      const float* __restrict__ W3a,
                                      const float* __restrict__ b3a,
                                      float* __restrict__ ws) {
  __shared__ float h2s[64];
  const int t = threadIdx.x;
  const int o = blockIdx.x * 256 + t;
  if (t < 64) h2s[t] = ws[1280 + t];
  __syncthreads();
  float acc = b3a[o] + ba[o];
#pragma unroll 8
  for (int m = 0; m < 64; ++m) acc = __builtin_fmaf(h2s[m], W3a[m * N_ORB + o], acc);
  ws[o] = acc;
}

// One wave per PAIR of batch rows (.x=row0, .y=row1 in every f32x2).
// R10: chains/exp2/khot deleted (selection on score keys, see fkey note).
// W3b LDS staging + slot swizzle kept from R8/R9 (verified -8 us; conflicts
// hidden by TLP but staging removes L2 latency on the critical path).
extern "C" __global__ void __launch_bounds__(256, 4) pcfs_sampler(
    const float* __restrict__ ws, const float* __restrict__ Wc,
    const float* __restrict__ bc, const float* __restrict__ W1b,
    const float* __restrict__ b1b, const float* __restrict__ W2b,
    const float* __restrict__ b2b, const float* __restrict__ W3b,
    const float* __restrict__ b3b, const float* __restrict__ bb,
    const float* __restrict__ g_alpha, const float* __restrict__ g_beta,
    float* __restrict__ out, int B) {
  __shared__ int sidx[4][64];        // per-wave: [0..31]=row0, [32..63]=row1
  __shared__ float w3s[8 * N_ORB];   // 32 KB: one 8-row tile of W3b
  const int tid = threadIdx.x;
  const int wave = tid >> 6;
  const int lane = tid & 63;
  const int pair = blockIdx.x * 4 + wave;
  const int row0 = pair * 2;
  // No early return: all threads must reach the tile barriers. Inactive
  // waves compute on clamped rows and skip the output writes.
  const bool active = (row0 < B);
  const bool have1 = active && (row0 + 1 < B);
  const int r0 = active ? row0 : 0;
  const int r1 = have1 ? row0 + 1 : r0;

  // ---- prefetch g_beta into registers NOW: these HBM loads drain ~6k
  // cycles later (beta key stage), hidden behind alpha+MLP phases ----
  float4 gb0[4], gb1[4];
  {
    const float4* g40 = (const float4*)(g_beta + (size_t)r0 * N_ORB);
    const float4* g41 = (const float4*)(g_beta + (size_t)r1 * N_ORB);
#pragma unroll
    for (int q = 0; q < 4; ++q) {
      gb0[q] = g40[lane * 4 + q];
      gb1[q] = g41[lane * 4 + q];
    }
  }

  // ---- alpha selection: keys of scores = const_logits + gumbel ----
  unsigned ka0[16], ka1[16];
  {
    const float4* c4 = (const float4*)ws;
    const float4* g40 = (const float4*)(g_alpha + (size_t)r0 * N_ORB);
    const float4* g41 = (const float4*)(g_alpha + (size_t)r1 * N_ORB);
#pragma unroll
    for (int q = 0; q < 4; ++q) {
      float4 c = c4[lane * 4 + q];
      float4 g0 = g40[lane * 4 + q];
      float4 g1 = g41[lane * 4 + q];
      ka0[4 * q + 0] = fkey(c.x + g0.x); ka1[4 * q + 0] = fkey(c.x + g1.x);
      ka0[4 * q + 1] = fkey(c.y + g0.y); ka1[4 * q + 1] = fkey(c.y + g1.y);
      ka0[4 * q + 2] = fkey(c.z + g0.z); ka1[4 * q + 2] = fkey(c.z + g1.z);
      ka0[4 * q + 3] = fkey(c.w + g0.w); ka1[4 * q + 3] = fkey(c.w + g1.w);
    }
  }
  unsigned am0, am1;
  top32_mask2u(ka0, ka1, lane, am0, am1);

  // write alpha halves (hard config: exact 0/1)
  if (active) write_half(out + (size_t)row0 * (2 * N_ORB), am0, lane);
  if (have1) write_half(out + (size_t)(row0 + 1) * (2 * N_ORB), am1, lane);

  // ---- ctx = alpha_config @ Wc + bc, per row (LDS compact + fixed trip) ----
  compact_idx(am0, lane, &sidx[wave][0]);
  compact_idx(am1, lane, &sidx[wave][32]);
  const int vi0 = sidx[wave][lane & 31];
  const int vi1 = sidx[wave][32 + (lane & 31)];
  const float bcv = bc[lane & 31];
  float ctx0 = bcv, ctx1 = bcv;
#pragma unroll
  for (int r = 0; r < 32; ++r) {
    const int i0 = __builtin_amdgcn_readlane(vi0, r);  // uniform
    const int i1 = __builtin_amdgcn_readlane(vi1, r);
    ctx0 += Wc[i0 * 32 + (lane & 31)];
    ctx1 += Wc[i1 * 32 + (lane & 31)];
  }

  // ---- h1 = leaky(base_b@W1b[0:1024] + ctx@W1b[1024:1056] + b1b) ----
  f32x2 h1a, h1b_;
  {
    const float ia = b1b[lane] + ws[N_ORB + lane];
    const float ib = b1b[lane + 64] + ws[N_ORB + lane + 64];
    h1a = f32x2{ia, ia};
    h1b_ = f32x2{ib, ib};
  }
#pragma unroll 4
  for (int c = 0; c < 32; ++c) {
    const f32x2 cv = f32x2{rdlane(ctx0, c), rdlane(ctx1, c)};
    const float* wr = W1b + (size_t)(N_ORB + c) * 128;
    const float wa = wr[lane], wb = wr[lane + 64];
    h1a = __builtin_elementwise_fma(f32x2{wa, wa}, cv, h1a);
    h1b_ = __builtin_elementwise_fma(f32x2{wb, wb}, cv, h1b_);
  }
  h1a = f32x2{leaky(h1a.x), leaky(h1a.y)};
  h1b_ = f32x2{leaky(h1b_.x), leaky(h1b_.y)};

  // ---- h2 = leaky(h1 @ W2b + b2b): 4 partial accumulators ----
  f32x2 h2p0, h2p1, h2p2, h2p3;
  {
    const float i2 = b2b[lane];
    h2p0 = f32x2{i2, i2};
    h2p1 = f32x2{0.0f, 0.0f};
    h2p2 = f32x2{0.0f, 0.0f};
    h2p3 = f32x2{0.0f, 0.0f};
  }
#pragma unroll 4
  for (int n = 0; n < 64; n += 4) {
    const f32x2 v0 = f32x2{rdlane(h1a.x, n + 0), rdlane(h1a.y, n + 0)};
    const f32x2 v1 = f32x2{rdlane(h1a.x, n + 1), rdlane(h1a.y, n + 1)};
    const f32x2 v2 = f32x2{rdlane(h1a.x, n + 2), rdlane(h1a.y, n + 2)};
    const f32x2 v3 = f32x2{rdlane(h1a.x, n + 3), rdlane(h1a.y, n + 3)};
    const float w0 = W2b[(n + 0) * 64 + lane];
    const float w1 = W2b[(n + 1) * 64 + lane];
    const float w2 = W2b[(n + 2) * 64 + lane];
    const float w3 = W2b[(n + 3) * 64 + lane];
    h2p0 = __builtin_elementwise_fma(f32x2{w0, w0}, v0, h2p0);
    h2p1 = __builtin_elementwise_fma(f32x2{w1, w1}, v1, h2p1);
    h2p2 = __builtin_elementwise_fma(f32x2{w2, w2}, v2, h2p2);
    h2p3 = __builtin_elementwise_fma(f32x2{w3, w3}, v3, h2p3);
  }
#pragma unroll 4
  for (int n = 0; n < 64; n += 4) {
    const f32x2 v0 = f32x2{rdlane(h1b_.x, n + 0), rdlane(h1b_.y, n + 0)};
    const f32x2 v1 = f32x2{rdlane(h1b_.x, n + 1), rdlane(h1b_.y, n + 1)};
    const f32x2 v2 = f32x2{rdlane(h1b_.x, n + 2), rdlane(h1b_.y, n + 2)};
    const f32x2 v3 = f32x2{rdlane(h1b_.x, n + 3), rdlane(h1b_.y, n + 3)};
    const float w0 = W2b[(n + 64 + 0) * 64 + lane];
    const float w1 = W2b[(n + 64 + 1) * 64 + lane];
    const float w2 = W2b[(n + 64 + 2) * 64 + lane];
    const float w3 = W2b[(n + 64 + 3) * 64 + lane];
    h2p0 = __builtin_elementwise_fma(f32x2{w0, w0}, v0, h2p0);
    h2p1 = __builtin_elementwise_fma(f32x2{w1, w1}, v1, h2p1);
    h2p2 = __builtin_elementwise_fma(f32x2{w2, w2}, v2, h2p2);
    h2p3 = __builtin_elementwise_fma(f32x2{w3, w3}, v3, h2p3);
  }
  f32x2 h2v = (h2p0 + h2p1) + (h2p2 + h2p3);
  h2v = f32x2{leaky(h2v.x), leaky(h2v.y)};

  // ---- beta logits: w[] = h2 @ W3b + b3b, W3b LDS-staged in 8-row tiles,
  // slots swizzled SWZ(f)=((f&7)<<5)|(f>>3) on write AND read ----
  f32x2 w[16];
  {
    const float4* b4 = (const float4*)b3b;
#pragma unroll
    for (int q = 0; q < 4; ++q) {
      float4 b = b4[lane * 4 + q];
      w[4 * q + 0] = f32x2{b.x, b.x};
      w[4 * q + 1] = f32x2{b.y, b.y};
      w[4 * q + 2] = f32x2{b.z, b.z};
      w[4 * q + 3] = f32x2{b.w, b.w};
    }
  }
  const int swzrd = ((lane & 1) << 7) | (lane >> 1);
  const int swzwr = ((tid & 7) << 5) | (tid >> 3);
  for (int t = 0; t < 8; ++t) {
    __syncthreads();  // previous tile fully consumed before overwrite
    {
      const float4* src = (const float4*)(W3b + (size_t)t * 8 * N_ORB);
      float4* dst = (float4*)w3s;
#pragma unroll
      for (int k = 0; k < 8; ++k) dst[k * 256 + swzwr] = src[tid + k * 256];
    }
    __syncthreads();  // tile visible to all waves
#pragma unroll
    for (int ml = 0; ml < 8; ++ml) {
      const int m = t * 8 + ml;
      const f32x2 hm = f32x2{rdlane(h2v.x, m), rdlane(h2v.y, m)};
      const float4* w4 = (const float4*)(w3s + ml * N_ORB);
#pragma unroll
      for (int q = 0; q < 4; ++q) {
        float4 wv = w4[swzrd + (q << 5)];
        w[4 * q + 0] = __builtin_elementwise_fma(f32x2{wv.x, wv.x}, hm, w[4 * q + 0]);
        w[4 * q + 1] = __builtin_elementwise_fma(f32x2{wv.y, wv.y}, hm, w[4 * q + 1]);
        w[4 * q + 2] = __builtin_elementwise_fma(f32x2{wv.z, wv.z}, hm, w[4 * q + 2]);
        w[4 * q + 3] = __builtin_elementwise_fma(f32x2{wv.w, wv.w}, hm, w[4 * q + 3]);
      }
    }
  }
  // + base_b + gumbel (prefetched) -> keys; selection only (no exp needed)
  unsigned kb0[16], kb1[16];
  {
    const float4* bb4 = (const float4*)bb;
#pragma unroll
    for (int q = 0; q < 4; ++q) {
      float4 b = bb4[lane * 4 + q];
      const float4 g0 = gb0[q];
      const float4 g1 = gb1[q];
      kb0[4 * q + 0] = fkey(w[4 * q + 0].x + b.x + g0.x);
      kb1[4 * q + 0] = fkey(w[4 * q + 0].y + b.x + g1.x);
      kb0[4 * q + 1] = fkey(w[4 * q + 1].x + b.y + g0.y);
      kb1[4 * q + 1] = fkey(w[4 * q + 1].y + b.y + g1.y);
      kb0[4 * q + 2] = fkey(w[4 * q + 2].x + b.z + g0.z);
      kb1[4 * q + 2] = fkey(w[4 * q + 2].y + b.z + g1.z);
      kb0[4 * q + 3] = fkey(w[4 * q + 3].x + b.w + g0.w);
      kb1[4 * q + 3] = fkey(w[4 * q + 3].y + b.w + g1.w);
    }
  }
  unsigned bm0, bm1;
  top32_mask2u(kb0, kb1, lane, bm0, bm1);

  if (active) write_half(out + (size_t)row0 * (2 * N_ORB) + N_ORB, bm0, lane);
  if (have1)
    write_half(out + (size_t)(row0 + 1) * (2 * N_ORB) + N_ORB, bm1, lane);
}

extern "C" void kernel_launch(void* const* d_in, const int* in_sizes, int n_in,
                              void* d_out, int out_size, void* d_ws, size_t ws_size,
                              hipStream_t stream) {
  const float* ba  = (const float*)d_in[0];
  const float* W1a = (const float*)d_in[1];
  const float* b1a = (const float*)d_in[2];
  const float* W2a = (const float*)d_in[3];
  const float* b2a = (const float*)d_in[4];
  const float* W3a = (const float*)d_in[5];
  const float* b3a = (const float*)d_in[6];
  const float* bb  = (const float*)d_in[7];
  const float* Wc  = (const float*)d_in[8];
  const float* bc  = (const float*)d_in[9];
  const float* W1b = (const float*)d_in[10];
  const float* b1b = (const float*)d_in[11];
  const float* W2b = (const float*)d_in[12];
  const float* b2b = (const float*)d_in[13];
  const float* W3b = (const float*)d_in[14];
  const float* b3b = (const float*)d_in[15];
  const float* ga  = (const float*)d_in[16];
  const float* gbt = (const float*)d_in[17];
  const int B = in_sizes[16] / N_ORB;
  float* ws = (float*)d_ws;

  hipLaunchKernelGGL(pcfs_pre1, dim3(256), dim3(256), 0, stream,
                     ba, W1a, b1a, bb, W1b, ws);
  hipLaunchKernelGGL(pcfs_pre2a, dim3(1), dim3(64), 0, stream,
                     W2a, b2a, ws);
  hipLaunchKernelGGL(pcfs_pre2b, dim3(4), dim3(256), 0, stream,
                     ba, W3a, b3a, ws);
  const int pairs = (B + 1) / 2;
  hipLaunchKernelGGL(pcfs_sampler, dim3((pairs + 3) / 4), dim3(256), 0, stream,
                     ws, Wc, bc, W1b, b1b, W2b, b2b, W3b, b3b, bb,
                     ga, gbt, (float*)d_out, B);
}

// Round 11
// 229.880 us; speedup vs baseline: 1.4001x; 1.0461x over previous
//
#include <hip/hip_runtime.h>
#include <hip/hip_bf16.h>
#include <float.h>

#define N_ORB 1024
#define KSEL 32
#define LEAK 0.01f

typedef float f32x2 __attribute__((ext_vector_type(2)));
// NOTE: never write (f32x2)(a, b) — comma-expr cast SPLATS b. Use f32x2{a,b}.

__device__ __forceinline__ float leaky(float x) { return x >= 0.0f ? x : LEAK * x; }

// R10-verified: top-32 of khot == top-32 of scores (order isomorphism proof in
// session log); selection runs on monotone uint keys of scores.
__device__ __forceinline__ unsigned fkey(float f) {
  const unsigned u = __float_as_uint(f);
  return u ^ ((unsigned)((int)u >> 31) | 0x80000000u);
}

// packed fp32 fma (VOP3P). Per-half = same IEEE fma -> bit-exact (R6-verified).
__device__ __forceinline__ f32x2 pk_fma(f32x2 a, f32x2 b, f32x2 c) {
  f32x2 d;
  asm("v_pk_fma_f32 %0, %1, %2, %3" : "=v"(d) : "v"(a), "v"(b), "v"(c));
  return d;
}

// ---- DPP helpers ----
template <int CTRL, int RM>
__device__ __forceinline__ int dpp0_i(int v) {  // masked-off rows contribute 0
  return __builtin_amdgcn_update_dpp(0, v, CTRL, RM, 0xF, true);
}
template <int CTRL>
__device__ __forceinline__ float dpp_zero(float v) {
  return __int_as_float(
      __builtin_amdgcn_update_dpp(0, __float_as_int(v), CTRL, 0xF, 0xF, true));
}
__device__ __forceinline__ float rdlane(float v, int l) {
  return __int_as_float(__builtin_amdgcn_readlane(__float_as_int(v), l));
}

// full 64-lane float sum, uniform result
__device__ __forceinline__ float wave_sum64_dpp(float v) {
  v += dpp_zero<0x111>(v);
  v += dpp_zero<0x112>(v);
  v += dpp_zero<0x114>(v);
  v += dpp_zero<0x118>(v);
  v += dpp_zero<0x142>(v);
  v += dpp_zero<0x143>(v);
  return rdlane(v, 63);
}
// full 64-lane int sum, uniform result
__device__ __forceinline__ int wave_isum64(int v) {
  v += dpp0_i<0x111, 0xF>(v);
  v += dpp0_i<0x112, 0xF>(v);
  v += dpp0_i<0x114, 0xF>(v);
  v += dpp0_i<0x118, 0xF>(v);
  v += dpp0_i<0x142, 0xF>(v);
  v += dpp0_i<0x143, 0xF>(v);
  return __builtin_amdgcn_readlane(v, 63);
}
// 64-lane inclusive prefix sum (int), per-lane result
__device__ __forceinline__ int wave_iscan64(int v) {
  v += dpp0_i<0x111, 0xF>(v);
  v += dpp0_i<0x112, 0xF>(v);
  v += dpp0_i<0x114, 0xF>(v);
  v += dpp0_i<0x118, 0xF>(v);
  v += dpp0_i<0x142, 0xA>(v);
  v += dpp0_i<0x143, 0xC>(v);
  return v;
}

// Tie path (cold). jax stable tie semantics: all >T, then ==T in ascending
// global index ((lane<<4)|slot). Operates on monotone uint keys.
__device__ unsigned tie_mask16u(const unsigned K[16], unsigned T, int lane) {
  unsigned gt = 0, eq = 0;
#pragma unroll
  for (int i = 0; i < 16; ++i) {
    gt |= (K[i] > T ? 1u : 0u) << i;
    eq |= (K[i] == T ? 1u : 0u) << i;
  }
  const int n_gt = wave_isum64(__popc(gt));
  const int m = 32 - n_gt;  // uniform, >= 1 by search invariant
  const int pe = __popc(eq);
  const int be = wave_iscan64(pe) - pe;
  int need = m - be;
  need = need < 0 ? 0 : (need > pe ? pe : need);
  unsigned tk = 0;
  unsigned em = eq;
  for (int guard = 0; guard < 16; ++guard) {
    if (!__any(need > 0)) break;
    if (need > 0) {
      const int bpos = __ffs(em) - 1;
      tk |= 1u << bpos;
      em &= em - 1;
      --need;
    }
  }
  return gt | tk;
}

// Top-32 for two rows on uint keys, joint binary search from bit 31,
// ballot+popcll counting, early exit when both exact.
__device__ void top32_mask2u(const unsigned K0[16], const unsigned K1[16],
                             int lane, unsigned& m0, unsigned& m1) {
  unsigned lo0 = 0, lo1 = 0;
  bool ex0 = false, ex1 = false;
  for (int b = 31; b >= 0; --b) {
    const unsigned c0v = lo0 | (1u << b);
    const unsigned c1v = lo1 | (1u << b);
    int c0 = 0, c1 = 0;
#pragma unroll
    for (int i = 0; i < 16; ++i) {
      c0 += __popcll(__ballot(K0[i] >= c0v));
      c1 += __popcll(__ballot(K1[i] >= c1v));
    }
    if (!ex0 && c0 >= 32) { lo0 = c0v; ex0 = (c0 == 32); }
    if (!ex1 && c1 >= 32) { lo1 = c1v; ex1 = (c1 == 32); }
    if (ex0 && ex1) break;
  }

  if (ex0) {
    unsigned mk = 0;
#pragma unroll
    for (int i = 0; i < 16; ++i) mk |= (K0[i] >= lo0 ? 1u : 0u) << i;
    m0 = mk;
  } else {
    m0 = tie_mask16u(K0, lo0, lane);
  }
  if (ex1) {
    unsigned mk = 0;
#pragma unroll
    for (int i = 0; i < 16; ++i) mk |= (K1[i] >= lo1 ? 1u : 0u) << i;
    m1 = mk;
  } else {
    m1 = tie_mask16u(K1, lo1, lane);
  }
}

// Compact the 32 selected global indices into dst[0..31], ascending order.
__device__ __forceinline__ void compact_idx(unsigned mask, int lane,
                                            int* __restrict__ dst) {
  const int pe = __popc(mask);
  int base = wave_iscan64(pe) - pe;
  unsigned m = mask;
  while (m) {
    const int s = __ffs(m) - 1;
    m &= m - 1;
    dst[base++] = (lane << 4) | s;
  }
}

__device__ __forceinline__ void write_half(float* __restrict__ dst,
                                           unsigned mask, int lane) {
  float4* o4 = (float4*)dst;
#pragma unroll
  for (int q = 0; q < 4; ++q) {
    float4 o;
    o.x = ((mask >> (4 * q + 0)) & 1) ? 1.0f : 0.0f;
    o.y = ((mask >> (4 * q + 1)) & 1) ? 1.0f : 0.0f;
    o.z = ((mask >> (4 * q + 2)) & 1) ? 1.0f : 0.0f;
    o.w = ((mask >> (4 * q + 3)) & 1) ? 1.0f : 0.0f;
    o4[lane * 4 + q] = o;
  }
}

// ws layout (floats): [0,1024) alpha const logits; [1024,1152) beta base
// dots; [1152,1280) h1a; [1280,1344) h2a.

// ---- precompute, stage 1 (grid 256): the two length-1024 dot layers ----
extern "C" __global__ void pcfs_pre1(const float* __restrict__ ba,
                                     const float* __restrict__ W1a,
                                     const float* __restrict__ b1a,
                                     const float* __restrict__ bb,
                                     const float* __restrict__ W1b,
                                     float* __restrict__ ws) {
  const int b = blockIdx.x;
  const int t = threadIdx.x;
  float acc = 0.0f;
  if (b < 128) {
#pragma unroll
    for (int j = t; j < N_ORB; j += 256) acc += ba[j] * W1a[j * 128 + b];
  } else {
    const int n = b - 128;
#pragma unroll
    for (int j = t; j < N_ORB; j += 256) acc += bb[j] * W1b[j * 128 + n];
  }
  __shared__ float red[4];
  float wsum = wave_sum64_dpp(acc);
  if ((t & 63) == 0) red[t >> 6] = wsum;
  __syncthreads();
  if (t == 0) {
    float tot = red[0] + red[1] + red[2] + red[3];
    if (b < 128)
      ws[1152 + b] = leaky(tot + b1a[b]);
    else
      ws[N_ORB + (b - 128)] = tot;
  }
}

// ---- precompute, stage 2a (1 block x 64): h2 = leaky(h1 @ W2a + b2a) ----
extern "C" __global__ void pcfs_pre2a(const float* __restrict__ W2a,
                                      const float* __restrict__ b2a,
                                      float* __restrict__ ws) {
  const int t = threadIdx.x;  // 64
  float acc = b2a[t];
#pragma unroll 8
  for (int n = 0; n < 128; ++n) acc = __builtin_fmaf(ws[1152 + n], W2a[n * 64 + t], acc);
  ws[1280 + t] = leaky(acc);
}

// ---- precompute, stage 2b (grid 4 x 256): alpha logits = h2 @ W3a + b3a
// + base_a, coalesced row-major W3a reads ----
extern "C" __global__ void pcfs_pre2b(const float* __restrict__ ba,
                                      const float* __restrict__ W3a,
                                      const float* __restrict__ b3a,
                                      float* __restrict__ ws) {
  __shared__ float h2s[64];
  const int t = threadIdx.x;
  const int o = blockIdx.x * 256 + t;
  if (t < 64) h2s[t] = ws[1280 + t];
  __syncthreads();
  float acc = b3a[o] + ba[o];
#pragma unroll 8
  for (int m = 0; m < 64; ++m) acc = __builtin_fmaf(h2s[m], W3a[m * N_ORB + o], acc);
  ws[o] = acc;
}

// One wave per PAIR of batch rows.
// R11: cooperative column-split W3b matmul. R10 counters: VALUBusy 27%,
// LDS pipe ~50us/CU (16 waves x 256 ds_read_b128 + 74k conflict cy) = the
// stall. Now wave w computes column quarter [256w,256w+256) of ALL 8 block
// rows, reading only its 64KB of W3b from L2 (64 coalesced float4 loads,
// no staging, no per-tile barriers); h2 shared via 2KB LDS + readlane;
// logits redistributed via 32KB LDS (1 write + 1 read per element).
// Bit-exact: each logit = b3b[col] + sum_{m=0..63 asc} fma(W3b[m][col],
// h2[row][m], acc) — identical op sequence, only the computing lane moved.
extern "C" __global__ void __launch_bounds__(256, 4) pcfs_sampler(
    const float* __restrict__ ws, const float* __restrict__ Wc,
    const float* __restrict__ bc, const float* __restrict__ W1b,
    const float* __restrict__ b1b, const float* __restrict__ W2b,
    const float* __restrict__ b2b, const float* __restrict__ W3b,
    const float* __restrict__ b3b, const float* __restrict__ bb,
    const float* __restrict__ g_alpha, const float* __restrict__ g_beta,
    float* __restrict__ out, int B) {
  __shared__ int sidx[4][64];       // per-wave: [0..31]=row0, [32..63]=row1
  __shared__ float lgt[8 * N_ORB];  // 32 KB: block's 8 rows of beta logits
  __shared__ f32x2 h2sh[4 * 64];    // 2 KB: h2 exchange (pair per wave)
  const int tid = threadIdx.x;
  const int wave = tid >> 6;
  const int lane = tid & 63;
  const int pair = blockIdx.x * 4 + wave;
  const int row0 = pair * 2;
  // No early return: all threads reach the barriers. Inactive waves compute
  // on clamped rows and skip output writes.
  const bool active = (row0 < B);
  const bool have1 = active && (row0 + 1 < B);
  const int r0 = active ? row0 : 0;
  const int r1 = have1 ? row0 + 1 : r0;

  // ---- prefetch g_beta into registers: drains during alpha+MLP phases ----
  float4 gb0[4], gb1[4];
  {
    const float4* g40 = (const float4*)(g_beta + (size_t)r0 * N_ORB);
    const float4* g41 = (const float4*)(g_beta + (size_t)r1 * N_ORB);
#pragma unroll
    for (int q = 0; q < 4; ++q) {
      gb0[q] = g40[lane * 4 + q];
      gb1[q] = g41[lane * 4 + q];
    }
  }

  // ---- alpha selection: keys of scores = const_logits + gumbel ----
  unsigned ka0[16], ka1[16];
  {
    const float4* c4 = (const float4*)ws;
    const float4* g40 = (const float4*)(g_alpha + (size_t)r0 * N_ORB);
    const float4* g41 = (const float4*)(g_alpha + (size_t)r1 * N_ORB);
#pragma unroll
    for (int q = 0; q < 4; ++q) {
      float4 c = c4[lane * 4 + q];
      float4 g0 = g40[lane * 4 + q];
      float4 g1 = g41[lane * 4 + q];
      ka0[4 * q + 0] = fkey(c.x + g0.x); ka1[4 * q + 0] = fkey(c.x + g1.x);
      ka0[4 * q + 1] = fkey(c.y + g0.y); ka1[4 * q + 1] = fkey(c.y + g1.y);
      ka0[4 * q + 2] = fkey(c.z + g0.z); ka1[4 * q + 2] = fkey(c.z + g1.z);
      ka0[4 * q + 3] = fkey(c.w + g0.w); ka1[4 * q + 3] = fkey(c.w + g1.w);
    }
  }
  unsigned am0, am1;
  top32_mask2u(ka0, ka1, lane, am0, am1);

  // write alpha halves (hard config: exact 0/1)
  if (active) write_half(out + (size_t)row0 * (2 * N_ORB), am0, lane);
  if (have1) write_half(out + (size_t)(row0 + 1) * (2 * N_ORB), am1, lane);

  // ---- ctx = alpha_config @ Wc + bc, per row (LDS compact + fixed trip) ----
  compact_idx(am0, lane, &sidx[wave][0]);
  compact_idx(am1, lane, &sidx[wave][32]);
  const int vi0 = sidx[wave][lane & 31];
  const int vi1 = sidx[wave][32 + (lane & 31)];
  const float bcv = bc[lane & 31];
  float ctx0 = bcv, ctx1 = bcv;
#pragma unroll
  for (int r = 0; r < 32; ++r) {
    const int i0 = __builtin_amdgcn_readlane(vi0, r);  // uniform
    const int i1 = __builtin_amdgcn_readlane(vi1, r);
    ctx0 += Wc[i0 * 32 + (lane & 31)];
    ctx1 += Wc[i1 * 32 + (lane & 31)];
  }

  // ---- h1 = leaky(base_b@W1b[0:1024] + ctx@W1b[1024:1056] + b1b) ----
  f32x2 h1a, h1b_;
  {
    const float ia = b1b[lane] + ws[N_ORB + lane];
    const float ib = b1b[lane + 64] + ws[N_ORB + lane + 64];
    h1a = f32x2{ia, ia};
    h1b_ = f32x2{ib, ib};
  }
#pragma unroll 4
  for (int c = 0; c < 32; ++c) {
    const f32x2 cv = f32x2{rdlane(ctx0, c), rdlane(ctx1, c)};
    const float* wr = W1b + (size_t)(N_ORB + c) * 128;
    const float wa = wr[lane], wb = wr[lane + 64];
    h1a = __builtin_elementwise_fma(f32x2{wa, wa}, cv, h1a);
    h1b_ = __builtin_elementwise_fma(f32x2{wb, wb}, cv, h1b_);
  }
  h1a = f32x2{leaky(h1a.x), leaky(h1a.y)};
  h1b_ = f32x2{leaky(h1b_.x), leaky(h1b_.y)};

  // ---- h2 = leaky(h1 @ W2b + b2b): 4 partial accumulators ----
  f32x2 h2p0, h2p1, h2p2, h2p3;
  {
    const float i2 = b2b[lane];
    h2p0 = f32x2{i2, i2};
    h2p1 = f32x2{0.0f, 0.0f};
    h2p2 = f32x2{0.0f, 0.0f};
    h2p3 = f32x2{0.0f, 0.0f};
  }
#pragma unroll 4
  for (int n = 0; n < 64; n += 4) {
    const f32x2 v0 = f32x2{rdlane(h1a.x, n + 0), rdlane(h1a.y, n + 0)};
    const f32x2 v1 = f32x2{rdlane(h1a.x, n + 1), rdlane(h1a.y, n + 1)};
    const f32x2 v2 = f32x2{rdlane(h1a.x, n + 2), rdlane(h1a.y, n + 2)};
    const f32x2 v3 = f32x2{rdlane(h1a.x, n + 3), rdlane(h1a.y, n + 3)};
    const float w0 = W2b[(n + 0) * 64 + lane];
    const float w1 = W2b[(n + 1) * 64 + lane];
    const float w2 = W2b[(n + 2) * 64 + lane];
    const float w3 = W2b[(n + 3) * 64 + lane];
    h2p0 = __builtin_elementwise_fma(f32x2{w0, w0}, v0, h2p0);
    h2p1 = __builtin_elementwise_fma(f32x2{w1, w1}, v1, h2p1);
    h2p2 = __builtin_elementwise_fma(f32x2{w2, w2}, v2, h2p2);
    h2p3 = __builtin_elementwise_fma(f32x2{w3, w3}, v3, h2p3);
  }
#pragma unroll 4
  for (int n = 0; n < 64; n += 4) {
    const f32x2 v0 = f32x2{rdlane(h1b_.x, n + 0), rdlane(h1b_.y, n + 0)};
    const f32x2 v1 = f32x2{rdlane(h1b_.x, n + 1), rdlane(h1b_.y, n + 1)};
    const f32x2 v2 = f32x2{rdlane(h1b_.x, n + 2), rdlane(h1b_.y, n + 2)};
    const f32x2 v3 = f32x2{rdlane(h1b_.x, n + 3), rdlane(h1b_.y, n + 3)};
    const float w0 = W2b[(n + 64 + 0) * 64 + lane];
    const float w1 = W2b[(n + 64 + 1) * 64 + lane];
    const float w2 = W2b[(n + 64 + 2) * 64 + lane];
    const float w3 = W2b[(n + 64 + 3) * 64 + lane];
    h2p0 = __builtin_elementwise_fma(f32x2{w0, w0}, v0, h2p0);
    h2p1 = __builtin_elementwise_fma(f32x2{w1, w1}, v1, h2p1);
    h2p2 = __builtin_elementwise_fma(f32x2{w2, w2}, v2, h2p2);
    h2p3 = __builtin_elementwise_fma(f32x2{w3, w3}, v3, h2p3);
  }
  f32x2 h2v = (h2p0 + h2p1) + (h2p2 + h2p3);
  h2v = f32x2{leaky(h2v.x), leaky(h2v.y)};

  // ---- share h2 across the block's 4 waves ----
  h2sh[wave * 64 + lane] = h2v;
  __syncthreads();
  f32x2 hh0 = h2sh[0 * 64 + lane];
  f32x2 hh1 = h2sh[1 * 64 + lane];
  f32x2 hh2 = h2sh[2 * 64 + lane];
  f32x2 hh3 = h2sh[3 * 64 + lane];

  // ---- cooperative beta matmul: this wave owns columns
  // [wave*256, wave*256+256); lane owns 4 cols (one float4) for all 8 rows.
  // acc[rp][c]: row-pair rp (rows 2rp,2rp+1), col c.
  const int cbase = wave * 64 + lane;  // float4 index within a 1024-col row
  f32x2 acc[4][4];
  {
    const float4 b3v = ((const float4*)b3b)[cbase];
#pragma unroll
    for (int rp = 0; rp < 4; ++rp) {
      acc[rp][0] = f32x2{b3v.x, b3v.x};
      acc[rp][1] = f32x2{b3v.y, b3v.y};
      acc[rp][2] = f32x2{b3v.z, b3v.z};
      acc[rp][3] = f32x2{b3v.w, b3v.w};
    }
  }
  {
    const float4* w34 = (const float4*)W3b;
#pragma unroll 4
    for (int m = 0; m < 64; ++m) {
      const float4 wv = w34[(m << 8) + cbase];
      const f32x2 h0 = f32x2{rdlane(hh0.x, m), rdlane(hh0.y, m)};
      const f32x2 h1 = f32x2{rdlane(hh1.x, m), rdlane(hh1.y, m)};
      const f32x2 h2_ = f32x2{rdlane(hh2.x, m), rdlane(hh2.y, m)};
      const f32x2 h3 = f32x2{rdlane(hh3.x, m), rdlane(hh3.y, m)};
      acc[0][0] = pk_fma(f32x2{wv.x, wv.x}, h0, acc[0][0]);
      acc[0][1] = pk_fma(f32x2{wv.y, wv.y}, h0, acc[0][1]);
      acc[0][2] = pk_fma(f32x2{wv.z, wv.z}, h0, acc[0][2]);
      acc[0][3] = pk_fma(f32x2{wv.w, wv.w}, h0, acc[0][3]);
      acc[1][0] = pk_fma(f32x2{wv.x, wv.x}, h1, acc[1][0]);
      acc[1][1] = pk_fma(f32x2{wv.y, wv.y}, h1, acc[1][1]);
      acc[1][2] = pk_fma(f32x2{wv.z, wv.z}, h1, acc[1][2]);
      acc[1][3] = pk_fma(f32x2{wv.w, wv.w}, h1, acc[1][3]);
      acc[2][0] = pk_fma(f32x2{wv.x, wv.x}, h2_, acc[2][0]);
      acc[2][1] = pk_fma(f32x2{wv.y, wv.y}, h2_, acc[2][1]);
      acc[2][2] = pk_fma(f32x2{wv.z, wv.z}, h2_, acc[2][2]);
      acc[2][3] = pk_fma(f32x2{wv.w, wv.w}, h2_, acc[2][3]);
      acc[3][0] = pk_fma(f32x2{wv.x, wv.x}, h3, acc[3][0]);
      acc[3][1] = pk_fma(f32x2{wv.y, wv.y}, h3, acc[3][1]);
      acc[3][2] = pk_fma(f32x2{wv.z, wv.z}, h3, acc[3][2]);
      acc[3][3] = pk_fma(f32x2{wv.w, wv.w}, h3, acc[3][3]);
    }
  }
  // redistribute logits: row-major [8][1024] in LDS, contiguous b128 writes
#pragma unroll
  for (int rp = 0; rp < 4; ++rp) {
    float4 ex, ey;
    ex.x = acc[rp][0].x; ex.y = acc[rp][1].x; ex.z = acc[rp][2].x; ex.w = acc[rp][3].x;
    ey.x = acc[rp][0].y; ey.y = acc[rp][1].y; ey.z = acc[rp][2].y; ey.w = acc[rp][3].y;
    ((float4*)(lgt + (2 * rp) * N_ORB))[cbase] = ex;
    ((float4*)(lgt + (2 * rp + 1) * N_ORB))[cbase] = ey;
  }
  __syncthreads();

  // readback own rows in the lane->cols lane*16+j layout
  f32x2 w[16];
  {
    const float4* lr0 = (const float4*)(lgt + (2 * wave) * N_ORB);
    const float4* lr1 = (const float4*)(lgt + (2 * wave + 1) * N_ORB);
#pragma unroll
    for (int q = 0; q < 4; ++q) {
      const float4 a = lr0[lane * 4 + q];
      const float4 b = lr1[lane * 4 + q];
      w[4 * q + 0] = f32x2{a.x, b.x};
      w[4 * q + 1] = f32x2{a.y, b.y};
      w[4 * q + 2] = f32x2{a.z, b.z};
      w[4 * q + 3] = f32x2{a.w, b.w};
    }
  }
  // + base_b + gumbel (prefetched) -> keys; selection only
  unsigned kb0[16], kb1[16];
  {
    const float4* bb4 = (const float4*)bb;
#pragma unroll
    for (int q = 0; q < 4; ++q) {
      float4 b = bb4[lane * 4 + q];
      const float4 g0 = gb0[q];
      const float4 g1 = gb1[q];
      kb0[4 * q + 0] = fkey(w[4 * q + 0].x + b.x + g0.x);
      kb1[4 * q + 0] = fkey(w[4 * q + 0].y + b.x + g1.x);
      kb0[4 * q + 1] = fkey(w[4 * q + 1].x + b.y + g0.y);
      kb1[4 * q + 1] = fkey(w[4 * q + 1].y + b.y + g1.y);
      kb0[4 * q + 2] = fkey(w[4 * q + 2].x + b.z + g0.z);
      kb1[4 * q + 2] = fkey(w[4 * q + 2].y + b.z + g1.z);
      kb0[4 * q + 3] = fkey(w[4 * q + 3].x + b.w + g0.w);
      kb1[4 * q + 3] = fkey(w[4 * q + 3].y + b.w + g1.w);
    }
  }
  unsigned bm0, bm1;
  top32_mask2u(kb0, kb1, lane, bm0, bm1);

  if (active) write_half(out + (size_t)row0 * (2 * N_ORB) + N_ORB, bm0, lane);
  if (have1)
    write_half(out + (size_t)(row0 + 1) * (2 * N_ORB) + N_ORB, bm1, lane);
}

extern "C" void kernel_launch(void* const* d_in, const int* in_sizes, int n_in,
                              void* d_out, int out_size, void* d_ws, size_t ws_size,
                              hipStream_t stream) {
  const float* ba  = (const float*)d_in[0];
  const float* W1a = (const float*)d_in[1];
  const float* b1a = (const float*)d_in[2];
  const float* W2a = (const float*)d_in[3];
  const float* b2a = (const float*)d_in[4];
  const float* W3a = (const float*)d_in[5];
  const float* b3a = (const float*)d_in[6];
  const float* bb  = (const float*)d_in[7];
  const float* Wc  = (const float*)d_in[8];
  const float* bc  = (const float*)d_in[9];
  const float* W1b = (const float*)d_in[10];
  const float* b1b = (const float*)d_in[11];
  const float* W2b = (const float*)d_in[12];
  const float* b2b = (const float*)d_in[13];
  const float* W3b = (const float*)d_in[14];
  const float* b3b = (const float*)d_in[15];
  const float* ga  = (const float*)d_in[16];
  const float* gbt = (const float*)d_in[17];
  const int B = in_sizes[16] / N_ORB;
  float* ws = (float*)d_ws;

  hipLaunchKernelGGL(pcfs_pre1, dim3(256), dim3(256), 0, stream,
                     ba, W1a, b1a, bb, W1b, ws);
  hipLaunchKernelGGL(pcfs_pre2a, dim3(1), dim3(64), 0, stream,
                     W2a, b2a, ws);
  hipLaunchKernelGGL(pcfs_pre2b, dim3(4), dim3(256), 0, stream,
                     ba, W3a, b3a, ws);
  const int pairs = (B + 1) / 2;
  hipLaunchKernelGGL(pcfs_sampler, dim3((pairs + 3) / 4), dim3(256), 0, stream,
                     ws, Wc, bc, W1b, b1b, W2b, b2b, W3b, b3b, bb,
                     ga, gbt, (float*)d_out, B);
}